// Round 1
// baseline (4001.702 us; speedup 1.0000x reference)
//
#include <hip/hip_runtime.h>
#include <hip/hip_bf16.h>
#include <math.h>

#define D_MODEL 1024
#define SEQ     1024
#define NHEADS  16
#define NKVH    4
#define HDIM    64
#define NEXP    64
#define TOPK    6
#define HEXP    512
#define EPS     1e-5f

// ---------------- rmsnorm over D=1024 (256 thr, 4 elems/thread) ----------------
__global__ __launch_bounds__(256) void rmsnorm_k(const float* __restrict__ x,
    const float* __restrict__ w, float* __restrict__ out) {
  int t = blockIdx.x;
  const float4* xr = (const float4*)(x + (size_t)t * D_MODEL);
  float4 v = xr[threadIdx.x];
  float ss = v.x*v.x + v.y*v.y + v.z*v.z + v.w*v.w;
  for (int off = 32; off; off >>= 1) ss += __shfl_xor(ss, off);
  __shared__ float red[4];
  if ((threadIdx.x & 63) == 0) red[threadIdx.x >> 6] = ss;
  __syncthreads();
  float tot = red[0] + red[1] + red[2] + red[3];
  float inv = rsqrtf(tot * (1.f / D_MODEL) + EPS);
  float4 wv = ((const float4*)w)[threadIdx.x];
  float4 o;
  o.x = v.x * inv * wv.x; o.y = v.y * inv * wv.y;
  o.z = v.z * inv * wv.z; o.w = v.w * inv * wv.w;
  ((float4*)(out + (size_t)t * D_MODEL))[threadIdx.x] = o;
}

// ---------------- generic f32 GEMM: C[M,N] = A[M,K]@B[K,N] (+resid) ----------------
// BM=64,BN=64,BK=16, 256 threads, 4x4 per thread. M = grid.y*64 implicit.
__global__ __launch_bounds__(256) void gemm64_k(const float* __restrict__ A,
    const float* __restrict__ B, float* __restrict__ C, float* __restrict__ C2,
    const float* __restrict__ resid, int N, int K) {
  __shared__ float As[16][64];
  __shared__ float Bs[16][64];
  int tid = threadIdx.x;
  int bm = blockIdx.y << 6, bn = blockIdx.x << 6;
  int tm = (tid >> 4) << 2, tn = (tid & 15) << 2;
  int am = tid >> 2, ak = (tid & 3) << 2;
  int bk = tid >> 4, bn4 = (tid & 15) << 2;
  float acc[4][4] = {};
  const float* Aptr = A + (size_t)(bm + am) * K + ak;
  const float* Bptr = B + (size_t)bk * N + bn + bn4;
  for (int k0 = 0; k0 < K; k0 += 16) {
    float4 av = *(const float4*)(Aptr + k0);
    float4 bv = *(const float4*)(Bptr + (size_t)k0 * N);
    As[ak + 0][am] = av.x; As[ak + 1][am] = av.y;
    As[ak + 2][am] = av.z; As[ak + 3][am] = av.w;
    *(float4*)&Bs[bk][bn4] = bv;
    __syncthreads();
#pragma unroll
    for (int kk = 0; kk < 16; kk++) {
      float4 a = *(const float4*)&As[kk][tm];
      float4 b = *(const float4*)&Bs[kk][tn];
      acc[0][0]+=a.x*b.x; acc[0][1]+=a.x*b.y; acc[0][2]+=a.x*b.z; acc[0][3]+=a.x*b.w;
      acc[1][0]+=a.y*b.x; acc[1][1]+=a.y*b.y; acc[1][2]+=a.y*b.z; acc[1][3]+=a.y*b.w;
      acc[2][0]+=a.z*b.x; acc[2][1]+=a.z*b.y; acc[2][2]+=a.z*b.z; acc[2][3]+=a.z*b.w;
      acc[3][0]+=a.w*b.x; acc[3][1]+=a.w*b.y; acc[3][2]+=a.w*b.z; acc[3][3]+=a.w*b.w;
    }
    __syncthreads();
  }
#pragma unroll
  for (int i = 0; i < 4; i++) {
    size_t rowoff = (size_t)(bm + tm + i) * N + bn + tn;
    float4 o = make_float4(acc[i][0], acc[i][1], acc[i][2], acc[i][3]);
    if (resid) {
      float4 r = *(const float4*)(resid + rowoff);
      o.x += r.x; o.y += r.y; o.z += r.z; o.w += r.w;
    }
    *(float4*)(C + rowoff) = o;
    if (C2) *(float4*)(C2 + rowoff) = o;
  }
}

// ---------------- per-head rmsnorm + RoPE on q (16 heads) and k (4 heads) ----------------
__global__ __launch_bounds__(64) void qknorm_rope_k(float* __restrict__ qb,
    float* __restrict__ kb, const float* __restrict__ qw, const float* __restrict__ kw,
    const float* __restrict__ fcos, const float* __restrict__ fsin) {
  int t = blockIdx.x, hid = blockIdx.y, lane = threadIdx.x;
  float* p; const float* w;
  if (hid < NHEADS) { p = qb + (size_t)t * (NHEADS*HDIM) + hid * HDIM; w = qw; }
  else              { p = kb + (size_t)t * (NKVH*HDIM) + (hid - NHEADS) * HDIM; w = kw; }
  float v = p[lane];
  float ss = v * v;
  for (int off = 32; off; off >>= 1) ss += __shfl_xor(ss, off);
  float vn = v * rsqrtf(ss * (1.f / HDIM) + EPS) * w[lane];
  int pi = lane >> 1;
  float c = fcos[t * (HDIM/2) + pi], s = fsin[t * (HDIM/2) + pi];
  float other = __shfl_xor(vn, 1);
  float o = (lane & 1) ? (other * s + vn * c) : (vn * c - other * s);
  p[lane] = o;
}

// ---------------- causal flash attention, f32, GQA 4:1 ----------------
// block = 256 thr (4 waves), handles head h and 16 q-rows; wave handles 4 rows, lane = dim.
__global__ __launch_bounds__(256) void attn_k(const float* __restrict__ qb,
    const float* __restrict__ kb, const float* __restrict__ vb, float* __restrict__ ob) {
  int h = blockIdx.y;
  int qbase = blockIdx.x * 16;
  int kvh = h >> 2;
  int tid = threadIdx.x, wv_ = tid >> 6, lane = tid & 63;
  __shared__ float Kt[64][65];   // Kt[d][k]
  __shared__ float Vs[64][64];   // Vs[k][d]
  float qreg[4], mm[4], ll[4], acc[4];
  int rows[4];
#pragma unroll
  for (int r = 0; r < 4; r++) {
    rows[r] = qbase + wv_ * 4 + r;
    qreg[r] = qb[(size_t)rows[r] * (NHEADS*HDIM) + h * HDIM + lane];
    mm[r] = -1e30f; ll[r] = 0.f; acc[r] = 0.f;
  }
  int ntiles = qbase / 64 + 1;
  for (int ti = 0; ti < ntiles; ti++) {
    int ts = ti * 64;
#pragma unroll
    for (int i = 0; i < 16; i++) {
      int idx = tid + i * 256;
      int kk = idx >> 6, dd = idx & 63;
      size_t src = (size_t)(ts + kk) * (NKVH*HDIM) + kvh * HDIM + dd;
      Kt[dd][kk] = kb[src];
      Vs[kk][dd] = vb[src];
    }
    __syncthreads();
    float sc[4] = {0.f, 0.f, 0.f, 0.f};
#pragma unroll
    for (int d = 0; d < 64; d++) {
      float kd = Kt[d][lane];
      sc[0] += __shfl(qreg[0], d) * kd;
      sc[1] += __shfl(qreg[1], d) * kd;
      sc[2] += __shfl(qreg[2], d) * kd;
      sc[3] += __shfl(qreg[3], d) * kd;
    }
    float pp[4];
#pragma unroll
    for (int r = 0; r < 4; r++) {
      float s = (ts + lane <= rows[r]) ? sc[r] * 0.125f : -1e30f;
      float tmax = s;
      for (int off = 32; off; off >>= 1) tmax = fmaxf(tmax, __shfl_xor(tmax, off));
      float mn = fmaxf(mm[r], tmax);
      float p = __expf(s - mn);
      float psum = p;
      for (int off = 32; off; off >>= 1) psum += __shfl_xor(psum, off);
      float alpha = __expf(mm[r] - mn);
      ll[r] = ll[r] * alpha + psum;
      acc[r] *= alpha;
      mm[r] = mn;
      pp[r] = p;
    }
#pragma unroll
    for (int k = 0; k < 64; k++) {
      float vk = Vs[k][lane];
      acc[0] += __shfl(pp[0], k) * vk;
      acc[1] += __shfl(pp[1], k) * vk;
      acc[2] += __shfl(pp[2], k) * vk;
      acc[3] += __shfl(pp[3], k) * vk;
    }
    __syncthreads();
  }
#pragma unroll
  for (int r = 0; r < 4; r++)
    ob[(size_t)rows[r] * (NHEADS*HDIM) + h * HDIM + lane] = acc[r] / ll[r];
}

// ---------------- gate: logits -> softmax -> top-6 (low-index tie-break) ----------------
__global__ __launch_bounds__(64) void gate_topk_k(const float* __restrict__ z,
    const float* __restrict__ gw, int* __restrict__ sel, float* __restrict__ topw,
    int* __restrict__ counts) {
  int t = blockIdx.x, lane = threadIdx.x;
  const float* zr = z + (size_t)t * D_MODEL;
  float acc = 0.f;
  for (int d = 0; d < D_MODEL; d += 4) {
    float4 zv = *(const float4*)(zr + d);
    acc += zv.x * gw[(size_t)(d + 0) * NEXP + lane];
    acc += zv.y * gw[(size_t)(d + 1) * NEXP + lane];
    acc += zv.z * gw[(size_t)(d + 2) * NEXP + lane];
    acc += zv.w * gw[(size_t)(d + 3) * NEXP + lane];
  }
  float m = acc;
  for (int off = 32; off; off >>= 1) m = fmaxf(m, __shfl_xor(m, off));
  float p = __expf(acc - m);
  float s = p;
  for (int off = 32; off; off >>= 1) s += __shfl_xor(s, off);
  p /= s;
  float rem = p, wsum = 0.f;
  float wv[TOPK]; int wi[TOPK];
  for (int i = 0; i < TOPK; i++) {
    float v = rem; int idx = lane;
    for (int off = 32; off; off >>= 1) {
      float v2 = __shfl_xor(v, off);
      int i2 = __shfl_xor(idx, off);
      if (v2 > v || (v2 == v && i2 < idx)) { v = v2; idx = i2; }
    }
    wv[i] = v; wi[i] = idx; wsum += v;
    if (lane == idx) rem = -1.f;
  }
  if (lane < TOPK) {
    sel[t * TOPK + lane] = wi[lane];
    topw[t * TOPK + lane] = wv[lane] / wsum;
  }
  if (lane == 0)
    for (int i = 0; i < TOPK; i++) atomicAdd(&counts[wi[i]], 1);
}

// ---------------- exclusive scan of 64 counts -> offsets & cursor ----------------
__global__ void scan_k(const int* __restrict__ counts, int* __restrict__ offs,
                       int* __restrict__ cursor, int* __restrict__ shcnt,
                       int* __restrict__ shoff) {
  int lane = threadIdx.x;
  int c = counts[lane];
  int x = c;
  for (int off = 1; off < 64; off <<= 1) {
    int y = __shfl_up(x, off);
    if (lane >= off) x += y;
  }
  offs[lane] = x - c;
  cursor[lane] = x - c;
  if (lane == 0) { shcnt[0] = SEQ; shoff[0] = 0; }
}

__global__ void iota_k(int* p) {
  int i = blockIdx.x * 256 + threadIdx.x;
  p[i] = i;
}

__global__ void scatter_k(const int* __restrict__ sel, const float* __restrict__ topw,
    int* __restrict__ cursor, int* __restrict__ tok, float* __restrict__ wt) {
  int t = blockIdx.x * 256 + threadIdx.x;
  if (t >= SEQ) return;
  for (int i = 0; i < TOPK; i++) {
    int e = sel[t * TOPK + i];
    int pos = atomicAdd(&cursor[e], 1);
    tok[pos] = t;
    wt[pos] = topw[t * TOPK + i];
  }
}

// ---------------- MoE phase A: g = silu(Z@w1) * (Z@w3) * wt  (gathered rows) ----------------
// BM=32 (tokens), BN=64, BK=16; grid = (HE/64, n_experts); loops M-tiles per expert.
__global__ __launch_bounds__(256) void moe_up_k(const float* __restrict__ z,
    const float* __restrict__ w1, const float* __restrict__ w3, size_t wstride,
    float* __restrict__ g, const int* __restrict__ tok_list,
    const float* __restrict__ wt_list, const int* __restrict__ counts,
    const int* __restrict__ offs) {
  int e = blockIdx.y;
  int cnt = counts[e];
  if (cnt == 0) return;
  int off = offs[e];
  int bn = blockIdx.x << 6;
  const float* w1p = w1 + (size_t)e * wstride;
  const float* w3p = w3 + (size_t)e * wstride;
  __shared__ float As[16][32];
  __shared__ float B1s[16][64];
  __shared__ float B3s[16][64];
  int tid = threadIdx.x;
  int tm = (tid >> 4) << 1, tn = (tid & 15) << 2;
  int am = tid >> 3, ak = (tid & 7) << 1;
  int bk = tid >> 4, bn4 = (tid & 15) << 2;
  for (int mt = 0; mt < cnt; mt += 32) {
    int row = mt + am;
    int tok = tok_list[off + (row < cnt ? row : 0)];
    const float* zr = z + (size_t)tok * D_MODEL + ak;
    float acc1[2][4] = {}, acc3[2][4] = {};
    for (int k0 = 0; k0 < D_MODEL; k0 += 16) {
      float2 av = *(const float2*)(zr + k0);
      As[ak][am] = av.x; As[ak + 1][am] = av.y;
      *(float4*)&B1s[bk][bn4] = *(const float4*)(w1p + (size_t)(k0 + bk) * HEXP + bn + bn4);
      *(float4*)&B3s[bk][bn4] = *(const float4*)(w3p + (size_t)(k0 + bk) * HEXP + bn + bn4);
      __syncthreads();
#pragma unroll
      for (int kk = 0; kk < 16; kk++) {
        float a0 = As[kk][tm], a1 = As[kk][tm + 1];
        float4 b1 = *(const float4*)&B1s[kk][tn];
        float4 b3 = *(const float4*)&B3s[kk][tn];
        acc1[0][0]+=a0*b1.x; acc1[0][1]+=a0*b1.y; acc1[0][2]+=a0*b1.z; acc1[0][3]+=a0*b1.w;
        acc1[1][0]+=a1*b1.x; acc1[1][1]+=a1*b1.y; acc1[1][2]+=a1*b1.z; acc1[1][3]+=a1*b1.w;
        acc3[0][0]+=a0*b3.x; acc3[0][1]+=a0*b3.y; acc3[0][2]+=a0*b3.z; acc3[0][3]+=a0*b3.w;
        acc3[1][0]+=a1*b3.x; acc3[1][1]+=a1*b3.y; acc3[1][2]+=a1*b3.z; acc3[1][3]+=a1*b3.w;
      }
      __syncthreads();
    }
#pragma unroll
    for (int i = 0; i < 2; i++) {
      int r = mt + tm + i;
      if (r < cnt) {
        float wt = wt_list ? wt_list[off + r] : 1.0f;
        float* gp = g + (size_t)(off + r) * HEXP + bn + tn;
#pragma unroll
        for (int j = 0; j < 4; j++) {
          float h1 = acc1[i][j], h3 = acc3[i][j];
          float sg = 1.f / (1.f + __expf(-h1));
          gp[j] = h1 * sg * h3 * wt;
        }
      }
    }
  }
}

// ---------------- MoE phase B: out[tok] += g @ w2  (atomicAdd scatter) ----------------
__global__ __launch_bounds__(256) void moe_down_k(const float* __restrict__ g,
    const float* __restrict__ w2, size_t wstride, float* __restrict__ out,
    const int* __restrict__ tok_list, const int* __restrict__ counts,
    const int* __restrict__ offs) {
  int e = blockIdx.y;
  int cnt = counts[e];
  if (cnt == 0) return;
  int off = offs[e];
  int bn = blockIdx.x << 6;
  const float* w2p = w2 + (size_t)e * wstride;
  __shared__ float As[16][32];
  __shared__ float Bs[16][64];
  int tid = threadIdx.x;
  int tm = (tid >> 4) << 1, tn = (tid & 15) << 2;
  int am = tid >> 3, ak = (tid & 7) << 1;
  int bk = tid >> 4, bn4 = (tid & 15) << 2;
  for (int mt = 0; mt < cnt; mt += 32) {
    int row = mt + am;
    int arow = off + (row < cnt ? row : 0);
    const float* gr = g + (size_t)arow * HEXP + ak;
    float acc[2][4] = {};
    for (int k0 = 0; k0 < HEXP; k0 += 16) {
      float2 av = *(const float2*)(gr + k0);
      As[ak][am] = av.x; As[ak + 1][am] = av.y;
      *(float4*)&Bs[bk][bn4] = *(const float4*)(w2p + (size_t)(k0 + bk) * D_MODEL + bn + bn4);
      __syncthreads();
#pragma unroll
      for (int kk = 0; kk < 16; kk++) {
        float a0 = As[kk][tm], a1 = As[kk][tm + 1];
        float4 b = *(const float4*)&Bs[kk][tn];
        acc[0][0]+=a0*b.x; acc[0][1]+=a0*b.y; acc[0][2]+=a0*b.z; acc[0][3]+=a0*b.w;
        acc[1][0]+=a1*b.x; acc[1][1]+=a1*b.y; acc[1][2]+=a1*b.z; acc[1][3]+=a1*b.w;
      }
      __syncthreads();
    }
#pragma unroll
    for (int i = 0; i < 2; i++) {
      int r = mt + tm + i;
      if (r < cnt) {
        int tok = tok_list[off + r];
        float* op = out + (size_t)tok * D_MODEL + bn + tn;
        atomicAdd(&op[0], acc[i][0]);
        atomicAdd(&op[1], acc[i][1]);
        atomicAdd(&op[2], acc[i][2]);
        atomicAdd(&op[3], acc[i][3]);
      }
    }
  }
}

// ---------------- host ----------------
extern "C" void kernel_launch(void* const* d_in, const int* in_sizes, int n_in,
                              void* d_out, int out_size, void* d_ws, size_t ws_size,
                              hipStream_t stream) {
  const float* x     = (const float*)d_in[0];
  const float* fcos  = (const float*)d_in[1];
  const float* fsin  = (const float*)d_in[2];
  const float* anw   = (const float*)d_in[3];
  const float* fnw   = (const float*)d_in[4];
  const float* wq    = (const float*)d_in[5];
  const float* wk    = (const float*)d_in[6];
  const float* wvv   = (const float*)d_in[7];
  const float* wo    = (const float*)d_in[8];
  const float* qnw   = (const float*)d_in[9];
  const float* knw   = (const float*)d_in[10];
  const float* gatew = (const float*)d_in[11];
  const float* w1e   = (const float*)d_in[12];
  const float* w3e   = (const float*)d_in[13];
  const float* w2e   = (const float*)d_in[14];
  const float* sw1   = (const float*)d_in[15];
  const float* sw3   = (const float*)d_in[16];
  const float* sw2   = (const float*)d_in[17];
  float* out = (float*)d_out;

  char* ws = (char*)d_ws;
  const size_t MB = 1ull << 20;
  float* hx    = (float*)(ws);            // 4MB, reused as attention output buffer
  float* h     = (float*)(ws + 4*MB);     // 4MB residual stream after attention
  float* z     = (float*)(ws + 8*MB);     // 4MB ffn-norm output
  float* qbuf  = (float*)(ws + 12*MB);    // 4MB
  float* kbuf  = (float*)(ws + 16*MB);    // 1MB
  float* vbuf  = (float*)(ws + 17*MB);    // 1MB
  float* gbuf  = (float*)(ws + 12*MB);    // 12.6MB, overlaps q/k/v (dead by then)
  float* s_act = (float*)(ws + 25*MB);    // 2MB shared-expert activation
  char*  misc  = ws + 27*MB;
  int*   sel      = (int*)(misc);
  float* topw     = (float*)(misc + 24576);
  int*   counts   = (int*)(misc + 49152);
  int*   offs     = (int*)(misc + 49152 + 256);
  int*   cursor   = (int*)(misc + 49152 + 512);
  int*   shcnt    = (int*)(misc + 49152 + 768);
  int*   shoff    = (int*)(misc + 49152 + 1024);
  int*   tok_list = (int*)(misc + 49152 + 1280);
  float* wt_list  = (float*)(misc + 49152 + 1280 + 24576);
  int*   id_list  = (int*)(misc + 49152 + 1280 + 49152);

  // 1. attn rmsnorm
  rmsnorm_k<<<SEQ, 256, 0, stream>>>(x, anw, hx);
  // 2. QKV projections
  gemm64_k<<<dim3(16, 16), 256, 0, stream>>>(hx, wq, qbuf, nullptr, nullptr, 1024, 1024);
  gemm64_k<<<dim3(4, 16),  256, 0, stream>>>(hx, wk, kbuf, nullptr, nullptr, 256, 1024);
  gemm64_k<<<dim3(4, 16),  256, 0, stream>>>(hx, wvv, vbuf, nullptr, nullptr, 256, 1024);
  // 3. per-head q/k rmsnorm + rope
  qknorm_rope_k<<<dim3(SEQ, NHEADS + NKVH), 64, 0, stream>>>(qbuf, kbuf, qnw, knw, fcos, fsin);
  // 4. causal flash attention -> hx (reused as o)
  attn_k<<<dim3(SEQ / 16, NHEADS), 256, 0, stream>>>(qbuf, kbuf, vbuf, hx);
  // 5. o @ wo + x -> h (and initialize d_out = h)
  gemm64_k<<<dim3(16, 16), 256, 0, stream>>>(hx, wo, h, out, x, 1024, 1024);
  // 6. ffn rmsnorm
  rmsnorm_k<<<SEQ, 256, 0, stream>>>(h, fnw, z);
  // 7. gate + top-k
  hipMemsetAsync(counts, 0, 256, stream);
  gate_topk_k<<<SEQ, 64, 0, stream>>>(z, gatew, sel, topw, counts);
  scan_k<<<1, 64, 0, stream>>>(counts, offs, cursor, shcnt, shoff);
  iota_k<<<SEQ / 256, 256, 0, stream>>>(id_list);
  scatter_k<<<SEQ / 256, 256, 0, stream>>>(sel, topw, cursor, tok_list, wt_list);
  // 8. MoE phase A (experts, then shared expert with identity list)
  moe_up_k<<<dim3(HEXP / 64, NEXP), 256, 0, stream>>>(z, w1e, w3e,
      (size_t)D_MODEL * HEXP, gbuf, tok_list, wt_list, counts, offs);
  moe_up_k<<<dim3(HEXP / 64, 1), 256, 0, stream>>>(z, sw1, sw3,
      0, s_act, id_list, nullptr, shcnt, shoff);
  // 9. MoE phase B: out += g @ w2 (scatter), out += s_act @ sw2
  moe_down_k<<<dim3(D_MODEL / 64, NEXP), 256, 0, stream>>>(gbuf, w2e,
      (size_t)HEXP * D_MODEL, out, tok_list, counts, offs);
  moe_down_k<<<dim3(D_MODEL / 64, 1), 256, 0, stream>>>(s_act, sw2,
      0, out, id_list, shcnt, shoff);
  (void)in_sizes; (void)n_in; (void)out_size; (void)ws_size;
}

// Round 3
// 1231.546 us; speedup vs baseline: 3.2493x; 3.2493x over previous
//
#include <hip/hip_runtime.h>
#include <hip/hip_bf16.h>
#include <math.h>

#define D_MODEL 1024
#define SEQ     1024
#define NHEADS  16
#define NKVH    4
#define HDIM    64
#define NEXP    64
#define TOPK    6
#define HEXP    512
#define EPS     1e-5f

typedef __attribute__((ext_vector_type(8))) short bf16x8;
typedef __attribute__((ext_vector_type(4))) float f32x4;

struct bfrag2 { bf16x8 hi, lo; };

__device__ __forceinline__ unsigned rne1(float a) {
  union { float f; unsigned u; } x; x.f = a;
  return (x.u + 0x7fffu + ((x.u >> 16) & 1u)) >> 16;
}
__device__ __forceinline__ float frombf(unsigned h) {
  union { float f; unsigned u; } x; x.u = h << 16; return x.f;
}
// pack two floats into one dword of bf16 hi parts and one dword of bf16 lo parts
__device__ __forceinline__ void split_pack(float a, float b, unsigned& hi, unsigned& lo) {
  unsigned ha = rne1(a), hb = rne1(b);
  hi = ha | (hb << 16);
  lo = rne1(a - frombf(ha)) | (rne1(b - frombf(hb)) << 16);
}

__device__ __forceinline__ f32x4 mfma16(bf16x8 a, bf16x8 b, f32x4 c) {
  return __builtin_amdgcn_mfma_f32_16x16x32_bf16(a, b, c, 0, 0, 0);
}
// split-precision accumulate: acc += (ah+al)*(bh+bl) minus lo*lo
__device__ __forceinline__ f32x4 mfma_sp(bf16x8 ah, bf16x8 al, const bfrag2& b, f32x4 c) {
  c = mfma16(ah, b.hi, c);
  c = mfma16(ah, b.lo, c);
  c = mfma16(al, b.hi, c);
  return c;
}

// B fragment from global f32: lane col = (lane&15) baked into p, k = (lane>>4)*8 + e.
__device__ __forceinline__ bfrag2 load_bfrag2(const float* __restrict__ p, int ld) {
  float f0 = p[0];
  float f1 = p[(size_t)ld];
  float f2 = p[(size_t)ld * 2];
  float f3 = p[(size_t)ld * 3];
  float f4 = p[(size_t)ld * 4];
  float f5 = p[(size_t)ld * 5];
  float f6 = p[(size_t)ld * 6];
  float f7 = p[(size_t)ld * 7];
  union { bf16x8 v; unsigned u[4]; } H, L;
  split_pack(f0, f1, H.u[0], L.u[0]);
  split_pack(f2, f3, H.u[1], L.u[1]);
  split_pack(f4, f5, H.u[2], L.u[2]);
  split_pack(f6, f7, H.u[3], L.u[3]);
  bfrag2 r; r.hi = H.v; r.lo = L.v; return r;
}

// ---------------- rmsnorm over D=1024 ----------------
__global__ __launch_bounds__(256) void rmsnorm_k(const float* __restrict__ x,
    const float* __restrict__ w, float* __restrict__ out) {
  int t = blockIdx.x;
  const float4* xr = (const float4*)(x + (size_t)t * D_MODEL);
  float4 v = xr[threadIdx.x];
  float ss = v.x*v.x + v.y*v.y + v.z*v.z + v.w*v.w;
  for (int off = 32; off; off >>= 1) ss += __shfl_xor(ss, off);
  __shared__ float red[4];
  if ((threadIdx.x & 63) == 0) red[threadIdx.x >> 6] = ss;
  __syncthreads();
  float tot = red[0] + red[1] + red[2] + red[3];
  float inv = rsqrtf(tot * (1.f / D_MODEL) + EPS);
  float4 wv = ((const float4*)w)[threadIdx.x];
  float4 o;
  o.x = v.x * inv * wv.x; o.y = v.y * inv * wv.y;
  o.z = v.z * inv * wv.z; o.w = v.w * inv * wv.w;
  ((float4*)(out + (size_t)t * D_MODEL))[threadIdx.x] = o;
}

// ---------------- dense split-bf16 MFMA GEMM (+resid, dual-store) ----------------
// BM=16, BN=128, 4 waves. grid = (N/128, M/16).
__global__ __launch_bounds__(256) void mfma_gemm_k(const float* __restrict__ A,
    const float* __restrict__ B, float* __restrict__ C, float* __restrict__ C2,
    const float* __restrict__ resid, int N, int K) {
  __shared__ short Ah[16][40];
  __shared__ short Al[16][40];
  int bm = blockIdx.y << 4, bn = blockIdx.x << 7;
  int tid = threadIdx.x, wv = tid >> 6, lane = tid & 63;
  int m_ = tid >> 4, k_ = (tid & 15) << 1;
  int arow = lane & 15, akb = (lane >> 4) << 3;
  int c0 = bn + wv * 32 + arow;
  const float* ar = A + (size_t)(bm + m_) * K + k_;
  f32x4 acc0 = {0.f,0.f,0.f,0.f}, acc1 = {0.f,0.f,0.f,0.f};
  for (int k0 = 0; k0 < K; k0 += 32) {
    float2 a2 = *(const float2*)(ar + k0);
    unsigned hi, lo; split_pack(a2.x, a2.y, hi, lo);
    *(unsigned*)&Ah[m_][k_] = hi;
    *(unsigned*)&Al[m_][k_] = lo;
    __syncthreads();
    bf16x8 ah = *(const bf16x8*)&Ah[arow][akb];
    bf16x8 al = *(const bf16x8*)&Al[arow][akb];
    const float* bp = B + (size_t)(k0 + akb) * N + c0;
    acc0 = mfma_sp(ah, al, load_bfrag2(bp, N), acc0);
    acc1 = mfma_sp(ah, al, load_bfrag2(bp + 16, N), acc1);
    __syncthreads();
  }
  int r0 = (lane >> 4) << 2;
#pragma unroll
  for (int ri = 0; ri < 4; ri++) {
    int row = bm + r0 + ri;
    size_t o0 = (size_t)row * N + c0;
    float v0 = acc0[ri], v1 = acc1[ri];
    if (resid) { v0 += resid[o0]; v1 += resid[o0 + 16]; }
    C[o0] = v0; C[o0 + 16] = v1;
    if (C2) { C2[o0] = v0; C2[o0 + 16] = v1; }
  }
}

// ---------------- per-head rmsnorm + RoPE ----------------
__global__ __launch_bounds__(64) void qknorm_rope_k(float* __restrict__ qb,
    float* __restrict__ kb, const float* __restrict__ qw, const float* __restrict__ kw,
    const float* __restrict__ fcos, const float* __restrict__ fsin) {
  int t = blockIdx.x, hid = blockIdx.y, lane = threadIdx.x;
  float* p; const float* w;
  if (hid < NHEADS) { p = qb + (size_t)t * (NHEADS*HDIM) + hid * HDIM; w = qw; }
  else              { p = kb + (size_t)t * (NKVH*HDIM) + (hid - NHEADS) * HDIM; w = kw; }
  float v = p[lane];
  float ss = v * v;
  for (int off = 32; off; off >>= 1) ss += __shfl_xor(ss, off);
  float vn = v * rsqrtf(ss * (1.f / HDIM) + EPS) * w[lane];
  int pi = lane >> 1;
  float c = fcos[t * (HDIM/2) + pi], s = fsin[t * (HDIM/2) + pi];
  float other = __shfl_xor(vn, 1);
  float o = (lane & 1) ? (other * s + vn * c) : (vn * c - other * s);
  p[lane] = o;
}

// ---------------- causal flash attention, f32, GQA 4:1 ----------------
__global__ __launch_bounds__(256) void attn_k(const float* __restrict__ qb,
    const float* __restrict__ kb, const float* __restrict__ vb, float* __restrict__ ob) {
  int h = blockIdx.y;
  int qbase = blockIdx.x * 16;
  int kvh = h >> 2;
  int tid = threadIdx.x, wv_ = tid >> 6, lane = tid & 63;
  __shared__ float Kt[64][65];
  __shared__ float Vs[64][64];
  float qreg[4], mm[4], ll[4], acc[4];
  int rows[4];
#pragma unroll
  for (int r = 0; r < 4; r++) {
    rows[r] = qbase + wv_ * 4 + r;
    qreg[r] = qb[(size_t)rows[r] * (NHEADS*HDIM) + h * HDIM + lane];
    mm[r] = -1e30f; ll[r] = 0.f; acc[r] = 0.f;
  }
  int ntiles = qbase / 64 + 1;
  for (int ti = 0; ti < ntiles; ti++) {
    int ts = ti * 64;
#pragma unroll
    for (int i = 0; i < 16; i++) {
      int idx = tid + i * 256;
      int kk = idx >> 6, dd = idx & 63;
      size_t src = (size_t)(ts + kk) * (NKVH*HDIM) + kvh * HDIM + dd;
      Kt[dd][kk] = kb[src];
      Vs[kk][dd] = vb[src];
    }
    __syncthreads();
    float sc[4] = {0.f, 0.f, 0.f, 0.f};
#pragma unroll
    for (int d = 0; d < 64; d++) {
      float kd = Kt[d][lane];
      sc[0] += __shfl(qreg[0], d) * kd;
      sc[1] += __shfl(qreg[1], d) * kd;
      sc[2] += __shfl(qreg[2], d) * kd;
      sc[3] += __shfl(qreg[3], d) * kd;
    }
    float pp[4];
#pragma unroll
    for (int r = 0; r < 4; r++) {
      float s = (ts + lane <= rows[r]) ? sc[r] * 0.125f : -1e30f;
      float tmax = s;
      for (int off = 32; off; off >>= 1) tmax = fmaxf(tmax, __shfl_xor(tmax, off));
      float mn = fmaxf(mm[r], tmax);
      float p = __expf(s - mn);
      float psum = p;
      for (int off = 32; off; off >>= 1) psum += __shfl_xor(psum, off);
      float alpha = __expf(mm[r] - mn);
      ll[r] = ll[r] * alpha + psum;
      acc[r] *= alpha;
      mm[r] = mn;
      pp[r] = p;
    }
#pragma unroll
    for (int k = 0; k < 64; k++) {
      float vk = Vs[k][lane];
      acc[0] += __shfl(pp[0], k) * vk;
      acc[1] += __shfl(pp[1], k) * vk;
      acc[2] += __shfl(pp[2], k) * vk;
      acc[3] += __shfl(pp[3], k) * vk;
    }
    __syncthreads();
  }
#pragma unroll
  for (int r = 0; r < 4; r++)
    ob[(size_t)rows[r] * (NHEADS*HDIM) + h * HDIM + lane] = acc[r] / ll[r];
}

// ---------------- gate: softmax -> top-6 (low-index tie-break) ----------------
__global__ __launch_bounds__(64) void gate_topk_k(const float* __restrict__ z,
    const float* __restrict__ gw, int* __restrict__ sel, float* __restrict__ topw,
    int* __restrict__ counts) {
  int t = blockIdx.x, lane = threadIdx.x;
  const float* zr = z + (size_t)t * D_MODEL;
  float acc = 0.f;
  for (int d = 0; d < D_MODEL; d += 4) {
    float4 zv = *(const float4*)(zr + d);
    acc += zv.x * gw[(size_t)(d + 0) * NEXP + lane];
    acc += zv.y * gw[(size_t)(d + 1) * NEXP + lane];
    acc += zv.z * gw[(size_t)(d + 2) * NEXP + lane];
    acc += zv.w * gw[(size_t)(d + 3) * NEXP + lane];
  }
  float m = acc;
  for (int off = 32; off; off >>= 1) m = fmaxf(m, __shfl_xor(m, off));
  float p = __expf(acc - m);
  float s = p;
  for (int off = 32; off; off >>= 1) s += __shfl_xor(s, off);
  p /= s;
  float rem = p, wsum = 0.f;
  float wvv[TOPK]; int wi[TOPK];
  for (int i = 0; i < TOPK; i++) {
    float v = rem; int idx = lane;
    for (int off = 32; off; off >>= 1) {
      float v2 = __shfl_xor(v, off);
      int i2 = __shfl_xor(idx, off);
      if (v2 > v || (v2 == v && i2 < idx)) { v = v2; idx = i2; }
    }
    wvv[i] = v; wi[i] = idx; wsum += v;
    if (lane == idx) rem = -1.f;
  }
  if (lane < TOPK) {
    sel[t * TOPK + lane] = wi[lane];
    topw[t * TOPK + lane] = wvv[lane] / wsum;
  }
  if (lane == 0)
    for (int i = 0; i < TOPK; i++) atomicAdd(&counts[wi[i]], 1);
}

__global__ void scan_k(const int* __restrict__ counts, int* __restrict__ offs,
                       int* __restrict__ cursor, int* __restrict__ shcnt,
                       int* __restrict__ shoff) {
  int lane = threadIdx.x;
  int c = counts[lane];
  int x = c;
  for (int off = 1; off < 64; off <<= 1) {
    int y = __shfl_up(x, off);
    if (lane >= off) x += y;
  }
  offs[lane] = x - c;
  cursor[lane] = x - c;
  if (lane == 0) { shcnt[0] = SEQ; shoff[0] = 0; }
}

__global__ void iota_k(int* p) {
  int i = blockIdx.x * 256 + threadIdx.x;
  p[i] = i;
}

__global__ void scatter_k(const int* __restrict__ sel, const float* __restrict__ topw,
    int* __restrict__ cursor, int* __restrict__ tok, float* __restrict__ wt) {
  int t = blockIdx.x * 256 + threadIdx.x;
  if (t >= SEQ) return;
  for (int i = 0; i < TOPK; i++) {
    int e = sel[t * TOPK + i];
    int pos = atomicAdd(&cursor[e], 1);
    tok[pos] = t;
    wt[pos] = topw[t * TOPK + i];
  }
}

// ---------------- MoE phase A (split-bf16 MFMA): g = silu(Z@w1)*(Z@w3)*wt ----------
// BM=16 tokens, BN=128 cols. grid = (HE/128, n_experts, z_split).
__global__ __launch_bounds__(256) void moe_up_mfma(const float* __restrict__ z,
    const float* __restrict__ w1, const float* __restrict__ w3, size_t wstride,
    float* __restrict__ g, const int* __restrict__ tok_list,
    const float* __restrict__ wt_list, const int* __restrict__ counts,
    const int* __restrict__ offs) {
  int e = blockIdx.y;
  int cnt = counts[e]; if (cnt == 0) return;
  int off = offs[e];
  const float* w1p = w1 + (size_t)e * wstride;
  const float* w3p = w3 + (size_t)e * wstride;
  __shared__ short Ah[16][40];
  __shared__ short Al[16][40];
  __shared__ int toks[16];
  int bn = blockIdx.x << 7;
  int tid = threadIdx.x, wv = tid >> 6, lane = tid & 63;
  int m_ = tid >> 4, k_ = (tid & 15) << 1;
  int arow = lane & 15, akb = (lane >> 4) << 3;
  int c0 = bn + wv * 32 + arow;
  for (int mt = blockIdx.z << 4; mt < cnt; mt += (int)(gridDim.z << 4)) {
    if (tid < 16) { int r = mt + tid; toks[tid] = tok_list[off + (r < cnt ? r : cnt - 1)]; }
    __syncthreads();
    const float* zr = z + (size_t)toks[m_] * D_MODEL + k_;
    f32x4 acc10 = {0.f,0.f,0.f,0.f}, acc11 = {0.f,0.f,0.f,0.f};
    f32x4 acc30 = {0.f,0.f,0.f,0.f}, acc31 = {0.f,0.f,0.f,0.f};
    for (int k0 = 0; k0 < D_MODEL; k0 += 32) {
      float2 a2 = *(const float2*)(zr + k0);
      unsigned hi, lo; split_pack(a2.x, a2.y, hi, lo);
      *(unsigned*)&Ah[m_][k_] = hi;
      *(unsigned*)&Al[m_][k_] = lo;
      __syncthreads();
      bf16x8 ah = *(const bf16x8*)&Ah[arow][akb];
      bf16x8 al = *(const bf16x8*)&Al[arow][akb];
      const float* b1 = w1p + (size_t)(k0 + akb) * HEXP + c0;
      const float* b3 = w3p + (size_t)(k0 + akb) * HEXP + c0;
      acc10 = mfma_sp(ah, al, load_bfrag2(b1, HEXP), acc10);
      acc30 = mfma_sp(ah, al, load_bfrag2(b3, HEXP), acc30);
      acc11 = mfma_sp(ah, al, load_bfrag2(b1 + 16, HEXP), acc11);
      acc31 = mfma_sp(ah, al, load_bfrag2(b3 + 16, HEXP), acc31);
      __syncthreads();
    }
    int r0 = (lane >> 4) << 2;
#pragma unroll
    for (int ri = 0; ri < 4; ri++) {
      int gr = mt + r0 + ri;
      if (gr < cnt) {
        float wt = wt_list ? wt_list[off + gr] : 1.0f;
        float* gp = g + (size_t)(off + gr) * HEXP + c0;
        float h1 = acc10[ri], h3 = acc30[ri];
        gp[0]  = h1 / (1.f + __expf(-h1)) * h3 * wt;
        h1 = acc11[ri]; h3 = acc31[ri];
        gp[16] = h1 / (1.f + __expf(-h1)) * h3 * wt;
      }
    }
  }
}

// ---------------- MoE phase B (split-bf16 MFMA): out[tok] += g @ w2 ----------------
__global__ __launch_bounds__(256) void moe_down_mfma(const float* __restrict__ g,
    const float* __restrict__ w2, size_t wstride, float* __restrict__ out,
    const int* __restrict__ tok_list, const int* __restrict__ counts,
    const int* __restrict__ offs) {
  int e = blockIdx.y;
  int cnt = counts[e]; if (cnt == 0) return;
  int off = offs[e];
  const float* w2p = w2 + (size_t)e * wstride;
  __shared__ short Ah[16][40];
  __shared__ short Al[16][40];
  int bn = blockIdx.x << 7;
  int tid = threadIdx.x, wv = tid >> 6, lane = tid & 63;
  int m_ = tid >> 4, k_ = (tid & 15) << 1;
  int arow = lane & 15, akb = (lane >> 4) << 3;
  int c0 = bn + wv * 32 + arow;
  for (int mt = blockIdx.z << 4; mt < cnt; mt += (int)(gridDim.z << 4)) {
    int ar_ = mt + m_; if (ar_ >= cnt) ar_ = cnt - 1;
    const float* gr_ = g + (size_t)(off + ar_) * HEXP + k_;
    f32x4 acc0 = {0.f,0.f,0.f,0.f}, acc1 = {0.f,0.f,0.f,0.f};
    for (int k0 = 0; k0 < HEXP; k0 += 32) {
      float2 a2 = *(const float2*)(gr_ + k0);
      unsigned hi, lo; split_pack(a2.x, a2.y, hi, lo);
      *(unsigned*)&Ah[m_][k_] = hi;
      *(unsigned*)&Al[m_][k_] = lo;
      __syncthreads();
      bf16x8 ah = *(const bf16x8*)&Ah[arow][akb];
      bf16x8 al = *(const bf16x8*)&Al[arow][akb];
      const float* bp = w2p + (size_t)(k0 + akb) * D_MODEL + c0;
      acc0 = mfma_sp(ah, al, load_bfrag2(bp, D_MODEL), acc0);
      acc1 = mfma_sp(ah, al, load_bfrag2(bp + 16, D_MODEL), acc1);
      __syncthreads();
    }
    int r0 = (lane >> 4) << 2;
#pragma unroll
    for (int ri = 0; ri < 4; ri++) {
      int gr2 = mt + r0 + ri;
      if (gr2 < cnt) {
        int tok = tok_list[off + gr2];
        float* op = out + (size_t)tok * D_MODEL + c0;
        atomicAdd(op, acc0[ri]);
        atomicAdd(op + 16, acc1[ri]);
      }
    }
  }
}

// ---------------- host ----------------
extern "C" void kernel_launch(void* const* d_in, const int* in_sizes, int n_in,
                              void* d_out, int out_size, void* d_ws, size_t ws_size,
                              hipStream_t stream) {
  const float* x     = (const float*)d_in[0];
  const float* fcos  = (const float*)d_in[1];
  const float* fsin  = (const float*)d_in[2];
  const float* anw   = (const float*)d_in[3];
  const float* fnw   = (const float*)d_in[4];
  const float* wq    = (const float*)d_in[5];
  const float* wk    = (const float*)d_in[6];
  const float* wvv   = (const float*)d_in[7];
  const float* wo    = (const float*)d_in[8];
  const float* qnw   = (const float*)d_in[9];
  const float* knw   = (const float*)d_in[10];
  const float* gatew = (const float*)d_in[11];
  const float* w1e   = (const float*)d_in[12];
  const float* w3e   = (const float*)d_in[13];
  const float* w2e   = (const float*)d_in[14];
  const float* sw1   = (const float*)d_in[15];
  const float* sw3   = (const float*)d_in[16];
  const float* sw2   = (const float*)d_in[17];
  float* out = (float*)d_out;

  char* ws = (char*)d_ws;
  const size_t MB = 1ull << 20;
  float* hx    = (float*)(ws);            // 4MB (attn-norm out, then attn out)
  float* h     = (float*)(ws + 4*MB);     // 4MB residual after attention
  float* z     = (float*)(ws + 8*MB);     // 4MB ffn-norm out
  float* qbuf  = (float*)(ws + 12*MB);    // 4MB
  float* kbuf  = (float*)(ws + 16*MB);    // 1MB
  float* vbuf  = (float*)(ws + 17*MB);    // 1MB
  float* gbuf  = (float*)(ws + 12*MB);    // 12.6MB, overlaps q/k/v (dead by then)
  float* s_act = (float*)(ws + 25*MB);    // 2MB shared-expert activation
  char*  misc  = ws + 27*MB;
  int*   sel      = (int*)(misc);
  float* topw     = (float*)(misc + 24576);
  int*   counts   = (int*)(misc + 49152);
  int*   offs     = (int*)(misc + 49152 + 256);
  int*   cursor   = (int*)(misc + 49152 + 512);
  int*   shcnt    = (int*)(misc + 49152 + 768);
  int*   shoff    = (int*)(misc + 49152 + 1024);
  int*   tok_list = (int*)(misc + 49152 + 1280);
  float* wt_list  = (float*)(misc + 49152 + 1280 + 24576);
  int*   id_list  = (int*)(misc + 49152 + 1280 + 49152);

  // 1. attn rmsnorm
  rmsnorm_k<<<SEQ, 256, 0, stream>>>(x, anw, hx);
  // 2. QKV projections (split-bf16 MFMA)
  mfma_gemm_k<<<dim3(8, 64), 256, 0, stream>>>(hx, wq, qbuf, nullptr, nullptr, 1024, 1024);
  mfma_gemm_k<<<dim3(2, 64), 256, 0, stream>>>(hx, wk, kbuf, nullptr, nullptr, 256, 1024);
  mfma_gemm_k<<<dim3(2, 64), 256, 0, stream>>>(hx, wvv, vbuf, nullptr, nullptr, 256, 1024);
  // 3. q/k rmsnorm + rope
  qknorm_rope_k<<<dim3(SEQ, NHEADS + NKVH), 64, 0, stream>>>(qbuf, kbuf, qnw, knw, fcos, fsin);
  // 4. causal flash attention -> hx
  attn_k<<<dim3(SEQ / 16, NHEADS), 256, 0, stream>>>(qbuf, kbuf, vbuf, hx);
  // 5. o @ wo + x -> h (and d_out = h)
  mfma_gemm_k<<<dim3(8, 64), 256, 0, stream>>>(hx, wo, h, out, x, 1024, 1024);
  // 6. ffn rmsnorm
  rmsnorm_k<<<SEQ, 256, 0, stream>>>(h, fnw, z);
  // 7. gate + top-k + bucketing
  hipMemsetAsync(counts, 0, 256, stream);
  gate_topk_k<<<SEQ, 64, 0, stream>>>(z, gatew, sel, topw, counts);
  scan_k<<<1, 64, 0, stream>>>(counts, offs, cursor, shcnt, shoff);
  iota_k<<<SEQ / 256, 256, 0, stream>>>(id_list);
  scatter_k<<<SEQ / 256, 256, 0, stream>>>(sel, topw, cursor, tok_list, wt_list);
  // 8. MoE phase A: experts then shared expert (dense over all tokens)
  moe_up_mfma<<<dim3(HEXP / 128, NEXP, 2), 256, 0, stream>>>(z, w1e, w3e,
      (size_t)D_MODEL * HEXP, gbuf, tok_list, wt_list, counts, offs);
  moe_up_mfma<<<dim3(HEXP / 128, 1, 64), 256, 0, stream>>>(z, sw1, sw3,
      0, s_act, id_list, nullptr, shcnt, shoff);
  // 9. MoE phase B: out += g @ w2 (scatter), out += s_act @ sw2
  moe_down_mfma<<<dim3(D_MODEL / 128, NEXP, 2), 256, 0, stream>>>(gbuf, w2e,
      (size_t)HEXP * D_MODEL, out, tok_list, counts, offs);
  moe_down_mfma<<<dim3(D_MODEL / 128, 1, 64), 256, 0, stream>>>(s_act, sw2,
      0, out, id_list, shcnt, shoff);
  (void)in_sizes; (void)n_in; (void)out_size; (void)ws_size;
}

// Round 4
// 673.919 us; speedup vs baseline: 5.9380x; 1.8274x over previous
//
#include <hip/hip_runtime.h>
#include <hip/hip_bf16.h>
#include <math.h>

#define D_MODEL 1024
#define SEQ     1024
#define NHEADS  16
#define NKVH    4
#define HDIM    64
#define NEXP    64
#define TOPK    6
#define HEXP    512
#define EPS     1e-5f

typedef __attribute__((ext_vector_type(8))) short bf16x8;
typedef __attribute__((ext_vector_type(4))) float f32x4;

struct bfrag2 { bf16x8 hi, lo; };

__device__ __forceinline__ unsigned rne1(float a) {
  union { float f; unsigned u; } x; x.f = a;
  return (x.u + 0x7fffu + ((x.u >> 16) & 1u)) >> 16;
}
__device__ __forceinline__ float frombf(unsigned h) {
  union { float f; unsigned u; } x; x.u = h << 16; return x.f;
}
__device__ __forceinline__ void split_pack(float a, float b, unsigned& hi, unsigned& lo) {
  unsigned ha = rne1(a), hb = rne1(b);
  hi = ha | (hb << 16);
  lo = rne1(a - frombf(ha)) | (rne1(b - frombf(hb)) << 16);
}
__device__ __forceinline__ unsigned pk2bf(float a, float b) {
  return rne1(a) | (rne1(b) << 16);
}

__device__ __forceinline__ f32x4 mfma16(bf16x8 a, bf16x8 b, f32x4 c) {
  return __builtin_amdgcn_mfma_f32_16x16x32_bf16(a, b, c, 0, 0, 0);
}
__device__ __forceinline__ f32x4 mfma_sp(bf16x8 ah, bf16x8 al, const bfrag2& b, f32x4 c) {
  c = mfma16(ah, b.hi, c);
  c = mfma16(ah, b.lo, c);
  c = mfma16(al, b.hi, c);
  return c;
}

// B fragment from global f32: col baked into p (lane&15), k = (lane>>4)*8 + j.
__device__ __forceinline__ bfrag2 load_bfrag2(const float* __restrict__ p, int ld) {
  float f0 = p[0];
  float f1 = p[(size_t)ld];
  float f2 = p[(size_t)ld * 2];
  float f3 = p[(size_t)ld * 3];
  float f4 = p[(size_t)ld * 4];
  float f5 = p[(size_t)ld * 5];
  float f6 = p[(size_t)ld * 6];
  float f7 = p[(size_t)ld * 7];
  union { bf16x8 v; unsigned u[4]; } H, L;
  split_pack(f0, f1, H.u[0], L.u[0]);
  split_pack(f2, f3, H.u[1], L.u[1]);
  split_pack(f4, f5, H.u[2], L.u[2]);
  split_pack(f6, f7, H.u[3], L.u[3]);
  bfrag2 r; r.hi = H.v; r.lo = L.v; return r;
}

// ---------------- rmsnorm over D=1024 ----------------
__global__ __launch_bounds__(256) void rmsnorm_k(const float* __restrict__ x,
    const float* __restrict__ w, float* __restrict__ out) {
  int t = blockIdx.x;
  const float4* xr = (const float4*)(x + (size_t)t * D_MODEL);
  float4 v = xr[threadIdx.x];
  float ss = v.x*v.x + v.y*v.y + v.z*v.z + v.w*v.w;
  for (int off = 32; off; off >>= 1) ss += __shfl_xor(ss, off);
  __shared__ float red[4];
  if ((threadIdx.x & 63) == 0) red[threadIdx.x >> 6] = ss;
  __syncthreads();
  float tot = red[0] + red[1] + red[2] + red[3];
  float inv = rsqrtf(tot * (1.f / D_MODEL) + EPS);
  float4 wv = ((const float4*)w)[threadIdx.x];
  float4 o;
  o.x = v.x * inv * wv.x; o.y = v.y * inv * wv.y;
  o.z = v.z * inv * wv.z; o.w = v.w * inv * wv.w;
  ((float4*)(out + (size_t)t * D_MODEL))[threadIdx.x] = o;
}

// ---------------- dense split-bf16 MFMA GEMM (+resid, dual-store) ----------------
__global__ __launch_bounds__(256) void mfma_gemm_k(const float* __restrict__ A,
    const float* __restrict__ B, float* __restrict__ C, float* __restrict__ C2,
    const float* __restrict__ resid, int N, int K) {
  __shared__ short Ah[16][40];
  __shared__ short Al[16][40];
  int bm = blockIdx.y << 4, bn = blockIdx.x << 7;
  int tid = threadIdx.x, wv = tid >> 6, lane = tid & 63;
  int m_ = tid >> 4, k_ = (tid & 15) << 1;
  int arow = lane & 15, akb = (lane >> 4) << 3;
  int c0 = bn + wv * 32 + arow;
  const float* ar = A + (size_t)(bm + m_) * K + k_;
  f32x4 acc0 = {0.f,0.f,0.f,0.f}, acc1 = {0.f,0.f,0.f,0.f};
  for (int k0 = 0; k0 < K; k0 += 32) {
    float2 a2 = *(const float2*)(ar + k0);
    unsigned hi, lo; split_pack(a2.x, a2.y, hi, lo);
    *(unsigned*)&Ah[m_][k_] = hi;
    *(unsigned*)&Al[m_][k_] = lo;
    __syncthreads();
    bf16x8 ah = *(const bf16x8*)&Ah[arow][akb];
    bf16x8 al = *(const bf16x8*)&Al[arow][akb];
    const float* bp = B + (size_t)(k0 + akb) * N + c0;
    acc0 = mfma_sp(ah, al, load_bfrag2(bp, N), acc0);
    acc1 = mfma_sp(ah, al, load_bfrag2(bp + 16, N), acc1);
    __syncthreads();
  }
  int r0 = (lane >> 4) << 2;
#pragma unroll
  for (int ri = 0; ri < 4; ri++) {
    int row = bm + r0 + ri;
    size_t o0 = (size_t)row * N + c0;
    float v0 = acc0[ri], v1 = acc1[ri];
    if (resid) { v0 += resid[o0]; v1 += resid[o0 + 16]; }
    C[o0] = v0; C[o0 + 16] = v1;
    if (C2) { C2[o0] = v0; C2[o0 + 16] = v1; }
  }
}

// ---------------- per-head rmsnorm + RoPE ----------------
__global__ __launch_bounds__(64) void qknorm_rope_k(float* __restrict__ qb,
    float* __restrict__ kb, const float* __restrict__ qw, const float* __restrict__ kw,
    const float* __restrict__ fcos, const float* __restrict__ fsin) {
  int t = blockIdx.x, hid = blockIdx.y, lane = threadIdx.x;
  float* p; const float* w;
  if (hid < NHEADS) { p = qb + (size_t)t * (NHEADS*HDIM) + hid * HDIM; w = qw; }
  else              { p = kb + (size_t)t * (NKVH*HDIM) + (hid - NHEADS) * HDIM; w = kw; }
  float v = p[lane];
  float ss = v * v;
  for (int off = 32; off; off >>= 1) ss += __shfl_xor(ss, off);
  float vn = v * rsqrtf(ss * (1.f / HDIM) + EPS) * w[lane];
  int pi = lane >> 1;
  float c = fcos[t * (HDIM/2) + pi], s = fsin[t * (HDIM/2) + pi];
  float other = __shfl_xor(vn, 1);
  float o = (lane & 1) ? (other * s + vn * c) : (vn * c - other * s);
  p[lane] = o;
}

// ---------------- causal flash attention, bf16 MFMA, GQA 4:1 ----------------
// block = 256 thr (4 waves); block handles 1 head x 64 q-rows; wave owns 16 rows.
__global__ __launch_bounds__(256) void attn_mfma(const float* __restrict__ qb,
    const float* __restrict__ kb, const float* __restrict__ vb, float* __restrict__ ob) {
  int h = blockIdx.y;
  int qbase = blockIdx.x << 6;
  int kvh = h >> 2;
  int tid = threadIdx.x, wv = tid >> 6, lane = tid & 63;
  __shared__ short Kt[64][72];      // [key][d]
  __shared__ short Vt[64][72];      // [d][key]  (transposed)
  __shared__ short Pl[4][16][72];   // per-wave P tile [row][key]
  int arow = lane & 15;
  int akb = (lane >> 4) << 3;
  int kg = lane >> 4;
  int qrow_base = qbase + wv * 16;
  // Q A-fragments (2 k-chunks), bf16, held in registers
  bf16x8 qf[2];
  {
    const float* qp = qb + (size_t)(qrow_base + arow) * (NHEADS*HDIM) + h * HDIM;
#pragma unroll
    for (int c = 0; c < 2; c++) {
      int d0 = akb + c * 32;
      union { bf16x8 v; unsigned u[4]; } r;
#pragma unroll
      for (int j = 0; j < 4; j++) r.u[j] = pk2bf(qp[d0 + 2*j], qp[d0 + 2*j + 1]);
      qf[c] = r.v;
    }
  }
  f32x4 accO[4];
  float m_[4], l_[4];
#pragma unroll
  for (int n = 0; n < 4; n++) { accO[n] = (f32x4){0.f,0.f,0.f,0.f}; m_[n] = -1e30f; l_[n] = 0.f; }
  int ntiles = (qbase >> 6) + 1;
  for (int ti = 0; ti < ntiles; ti++) {
    int ts = ti << 6;
    // stage K [key][d] and V transposed [d][key] as bf16
#pragma unroll
    for (int i = 0; i < 16; i++) {
      int flat = tid + i * 256;
      int kk = flat >> 6, dd = flat & 63;
      size_t src = (size_t)(ts + kk) * (NKVH*HDIM) + kvh * HDIM + dd;
      Kt[kk][dd] = (short)rne1(kb[src]);
      Vt[dd][kk] = (short)rne1(vb[src]);
    }
    __syncthreads();
    // S = Q K^T : 4 key-subtiles x 2 k-chunks
    f32x4 accS[4];
#pragma unroll
    for (int n = 0; n < 4; n++) accS[n] = (f32x4){0.f,0.f,0.f,0.f};
#pragma unroll
    for (int c = 0; c < 2; c++) {
#pragma unroll
      for (int n = 0; n < 4; n++) {
        bf16x8 bf = *(const bf16x8*)&Kt[n*16 + arow][c*32 + akb];
        accS[n] = mfma16(qf[c], bf, accS[n]);
      }
    }
    // online softmax (rows kg*4+ri, keys n*16+arow)
    float alpha[4];
#pragma unroll
    for (int ri = 0; ri < 4; ri++) {
      int qrow = qrow_base + kg*4 + ri;
      float mx = -1e30f;
#pragma unroll
      for (int n = 0; n < 4; n++) {
        int key = ts + n*16 + arow;
        float s = (key <= qrow) ? accS[n][ri] * 0.125f : -1e30f;
        accS[n][ri] = s;
        mx = fmaxf(mx, s);
      }
      for (int off = 1; off < 16; off <<= 1) mx = fmaxf(mx, __shfl_xor(mx, off));
      float mn = fmaxf(m_[ri], mx);
      float a = __expf(m_[ri] - mn);
      float sum = 0.f;
#pragma unroll
      for (int n = 0; n < 4; n++) {
        float p = __expf(accS[n][ri] - mn);
        accS[n][ri] = p;
        sum += p;
      }
      for (int off = 1; off < 16; off <<= 1) sum += __shfl_xor(sum, off);
      l_[ri] = l_[ri] * a + sum;
      m_[ri] = mn;
      alpha[ri] = a;
#pragma unroll
      for (int n = 0; n < 4; n++) accO[n][ri] *= a;
    }
    // P -> per-wave LDS (bf16)
#pragma unroll
    for (int ri = 0; ri < 4; ri++)
#pragma unroll
      for (int n = 0; n < 4; n++)
        Pl[wv][kg*4 + ri][n*16 + arow] = (short)rne1(accS[n][ri]);
    // O += P V : A = P from LDS, B = Vt contiguous
#pragma unroll
    for (int c = 0; c < 2; c++) {
      bf16x8 pf = *(const bf16x8*)&Pl[wv][arow][c*32 + akb];
#pragma unroll
      for (int n = 0; n < 4; n++) {
        bf16x8 vf = *(const bf16x8*)&Vt[n*16 + arow][c*32 + akb];
        accO[n] = mfma16(pf, vf, accO[n]);
      }
    }
    __syncthreads();
  }
#pragma unroll
  for (int ri = 0; ri < 4; ri++) {
    int qrow = qrow_base + kg*4 + ri;
    float inv = 1.f / l_[ri];
#pragma unroll
    for (int n = 0; n < 4; n++)
      ob[(size_t)qrow * (NHEADS*HDIM) + h * HDIM + n*16 + arow] = accO[n][ri] * inv;
  }
}

// ---------------- gate: softmax -> top-6 (low-index tie-break) ----------------
__global__ __launch_bounds__(64) void gate_topk_k(const float* __restrict__ z,
    const float* __restrict__ gw, int* __restrict__ sel, float* __restrict__ topw,
    int* __restrict__ counts) {
  int t = blockIdx.x, lane = threadIdx.x;
  const float* zr = z + (size_t)t * D_MODEL;
  float acc = 0.f;
  for (int d = 0; d < D_MODEL; d += 4) {
    float4 zv = *(const float4*)(zr + d);
    acc += zv.x * gw[(size_t)(d + 0) * NEXP + lane];
    acc += zv.y * gw[(size_t)(d + 1) * NEXP + lane];
    acc += zv.z * gw[(size_t)(d + 2) * NEXP + lane];
    acc += zv.w * gw[(size_t)(d + 3) * NEXP + lane];
  }
  float m = acc;
  for (int off = 32; off; off >>= 1) m = fmaxf(m, __shfl_xor(m, off));
  float p = __expf(acc - m);
  float s = p;
  for (int off = 32; off; off >>= 1) s += __shfl_xor(s, off);
  p /= s;
  float rem = p, wsum = 0.f;
  float wvv[TOPK]; int wi[TOPK];
  for (int i = 0; i < TOPK; i++) {
    float v = rem; int idx = lane;
    for (int off = 32; off; off >>= 1) {
      float v2 = __shfl_xor(v, off);
      int i2 = __shfl_xor(idx, off);
      if (v2 > v || (v2 == v && i2 < idx)) { v = v2; idx = i2; }
    }
    wvv[i] = v; wi[i] = idx; wsum += v;
    if (lane == idx) rem = -1.f;
  }
  if (lane < TOPK) {
    sel[t * TOPK + lane] = wi[lane];
    topw[t * TOPK + lane] = wvv[lane] / wsum;
  }
  if (lane == 0)
    for (int i = 0; i < TOPK; i++) atomicAdd(&counts[wi[i]], 1);
}

__global__ void scan_k(const int* __restrict__ counts, int* __restrict__ offs,
                       int* __restrict__ cursor, int* __restrict__ shcnt,
                       int* __restrict__ shoff) {
  int lane = threadIdx.x;
  int c = counts[lane];
  int x = c;
  for (int off = 1; off < 64; off <<= 1) {
    int y = __shfl_up(x, off);
    if (lane >= off) x += y;
  }
  offs[lane] = x - c;
  cursor[lane] = x - c;
  if (lane == 0) { shcnt[0] = SEQ; shoff[0] = 0; }
}

__global__ void iota_k(int* p) {
  int i = blockIdx.x * 256 + threadIdx.x;
  p[i] = i;
}

__global__ void scatter_k(const int* __restrict__ sel, const float* __restrict__ topw,
    int* __restrict__ cursor, int* __restrict__ tok, float* __restrict__ wt) {
  int t = blockIdx.x * 256 + threadIdx.x;
  if (t >= SEQ) return;
  for (int i = 0; i < TOPK; i++) {
    int e = sel[t * TOPK + i];
    int pos = atomicAdd(&cursor[e], 1);
    tok[pos] = t;
    wt[pos] = topw[t * TOPK + i];
  }
}

// ---------------- MoE phase A (split-bf16 MFMA, BM=128): g = silu(Z@w1)*(Z@w3)*wt --
// grid = (HEXP/64, n_experts, zsplit); 256 thr; wave covers 16 cols x 128 rows.
__global__ __launch_bounds__(256) void moe_up2(const float* __restrict__ z,
    const float* __restrict__ w1, const float* __restrict__ w3, size_t wstride,
    float* __restrict__ g, const int* __restrict__ tok_list,
    const float* __restrict__ wt_list, const int* __restrict__ counts,
    const int* __restrict__ offs) {
  int e = blockIdx.y;
  int cnt = counts[e]; if (cnt == 0) return;
  int off = offs[e];
  const float* w1p = w1 + (size_t)e * wstride;
  const float* w3p = w3 + (size_t)e * wstride;
  __shared__ short Ah[128][40];
  __shared__ short Al[128][40];
  __shared__ int toks[128];
  int tid = threadIdx.x, wv = tid >> 6, lane = tid & 63;
  int arow = lane & 15, akb = (lane >> 4) << 3, kg = lane >> 4;
  int c0 = (blockIdx.x << 6) + wv * 16 + arow;
  for (int mt = blockIdx.z << 7; mt < cnt; mt += (int)(gridDim.z << 7)) {
    if (tid < 128) { int r = mt + tid; toks[tid] = tok_list[off + (r < cnt ? r : cnt - 1)]; }
    __syncthreads();
    f32x4 a1[8], a3[8];
#pragma unroll
    for (int f = 0; f < 8; f++) { a1[f] = (f32x4){0.f,0.f,0.f,0.f}; a3[f] = (f32x4){0.f,0.f,0.f,0.f}; }
    for (int k0 = 0; k0 < D_MODEL; k0 += 32) {
#pragma unroll
      for (int i = 0; i < 8; i++) {
        int idx = tid + i * 256;
        int row = idx >> 4, kk = (idx & 15) << 1;
        const float* zp = z + (size_t)toks[row] * D_MODEL + k0 + kk;
        unsigned hi, lo; split_pack(zp[0], zp[1], hi, lo);
        *(unsigned*)&Ah[row][kk] = hi;
        *(unsigned*)&Al[row][kk] = lo;
      }
      __syncthreads();
      bfrag2 b1 = load_bfrag2(w1p + (size_t)(k0 + akb) * HEXP + c0, HEXP);
      bfrag2 b3 = load_bfrag2(w3p + (size_t)(k0 + akb) * HEXP + c0, HEXP);
#pragma unroll
      for (int f = 0; f < 8; f++) {
        bf16x8 ah = *(const bf16x8*)&Ah[f*16 + arow][akb];
        bf16x8 al = *(const bf16x8*)&Al[f*16 + arow][akb];
        a1[f] = mfma_sp(ah, al, b1, a1[f]);
        a3[f] = mfma_sp(ah, al, b3, a3[f]);
      }
      __syncthreads();
    }
#pragma unroll
    for (int f = 0; f < 8; f++)
#pragma unroll
      for (int ri = 0; ri < 4; ri++) {
        int r = mt + f*16 + kg*4 + ri;
        if (r < cnt) {
          float wt = wt_list ? wt_list[off + r] : 1.0f;
          float h1 = a1[f][ri], h3 = a3[f][ri];
          g[(size_t)(off + r) * HEXP + c0] = h1 / (1.f + __expf(-h1)) * h3 * wt;
        }
      }
    __syncthreads();
  }
}

// ---------------- MoE phase B (split-bf16 MFMA, BM=128): out[tok] += g @ w2 --------
// grid = (D_MODEL/128, n_experts, zsplit); wave covers 32 cols (2 frags) x 128 rows.
__global__ __launch_bounds__(256) void moe_down2(const float* __restrict__ g,
    const float* __restrict__ w2, size_t wstride, float* __restrict__ out,
    const int* __restrict__ tok_list, const int* __restrict__ counts,
    const int* __restrict__ offs) {
  int e = blockIdx.y;
  int cnt = counts[e]; if (cnt == 0) return;
  int off = offs[e];
  const float* w2p = w2 + (size_t)e * wstride;
  __shared__ short Ah[128][40];
  __shared__ short Al[128][40];
  int tid = threadIdx.x, wv = tid >> 6, lane = tid & 63;
  int arow = lane & 15, akb = (lane >> 4) << 3, kg = lane >> 4;
  int c0 = (blockIdx.x << 7) + wv * 32 + arow;
  for (int mt = blockIdx.z << 7; mt < cnt; mt += (int)(gridDim.z << 7)) {
    f32x4 ac0[8], ac1[8];
#pragma unroll
    for (int f = 0; f < 8; f++) { ac0[f] = (f32x4){0.f,0.f,0.f,0.f}; ac1[f] = (f32x4){0.f,0.f,0.f,0.f}; }
    for (int k0 = 0; k0 < HEXP; k0 += 32) {
#pragma unroll
      for (int i = 0; i < 8; i++) {
        int idx = tid + i * 256;
        int row = idx >> 4, kk = (idx & 15) << 1;
        int ar_ = mt + row; if (ar_ >= cnt) ar_ = cnt - 1;
        const float* gp = g + (size_t)(off + ar_) * HEXP + k0 + kk;
        unsigned hi, lo; split_pack(gp[0], gp[1], hi, lo);
        *(unsigned*)&Ah[row][kk] = hi;
        *(unsigned*)&Al[row][kk] = lo;
      }
      __syncthreads();
      bfrag2 b0 = load_bfrag2(w2p + (size_t)(k0 + akb) * D_MODEL + c0, D_MODEL);
      bfrag2 b1 = load_bfrag2(w2p + (size_t)(k0 + akb) * D_MODEL + c0 + 16, D_MODEL);
#pragma unroll
      for (int f = 0; f < 8; f++) {
        bf16x8 ah = *(const bf16x8*)&Ah[f*16 + arow][akb];
        bf16x8 al = *(const bf16x8*)&Al[f*16 + arow][akb];
        ac0[f] = mfma_sp(ah, al, b0, ac0[f]);
        ac1[f] = mfma_sp(ah, al, b1, ac1[f]);
      }
      __syncthreads();
    }
#pragma unroll
    for (int f = 0; f < 8; f++)
#pragma unroll
      for (int ri = 0; ri < 4; ri++) {
        int r = mt + f*16 + kg*4 + ri;
        if (r < cnt) {
          int tok = tok_list[off + r];
          float* op = out + (size_t)tok * D_MODEL + c0;
          atomicAdd(op, ac0[f][ri]);
          atomicAdd(op + 16, ac1[f][ri]);
        }
      }
    __syncthreads();
  }
}

// ---------------- host ----------------
extern "C" void kernel_launch(void* const* d_in, const int* in_sizes, int n_in,
                              void* d_out, int out_size, void* d_ws, size_t ws_size,
                              hipStream_t stream) {
  const float* x     = (const float*)d_in[0];
  const float* fcos  = (const float*)d_in[1];
  const float* fsin  = (const float*)d_in[2];
  const float* anw   = (const float*)d_in[3];
  const float* fnw   = (const float*)d_in[4];
  const float* wq    = (const float*)d_in[5];
  const float* wk    = (const float*)d_in[6];
  const float* wvv   = (const float*)d_in[7];
  const float* wo    = (const float*)d_in[8];
  const float* qnw   = (const float*)d_in[9];
  const float* knw   = (const float*)d_in[10];
  const float* gatew = (const float*)d_in[11];
  const float* w1e   = (const float*)d_in[12];
  const float* w3e   = (const float*)d_in[13];
  const float* w2e   = (const float*)d_in[14];
  const float* sw1   = (const float*)d_in[15];
  const float* sw3   = (const float*)d_in[16];
  const float* sw2   = (const float*)d_in[17];
  float* out = (float*)d_out;

  char* ws = (char*)d_ws;
  const size_t MB = 1ull << 20;
  float* hx    = (float*)(ws);            // 4MB (attn-norm out, then attn out)
  float* h     = (float*)(ws + 4*MB);     // 4MB residual after attention
  float* z     = (float*)(ws + 8*MB);     // 4MB ffn-norm out
  float* qbuf  = (float*)(ws + 12*MB);    // 4MB
  float* kbuf  = (float*)(ws + 16*MB);    // 1MB
  float* vbuf  = (float*)(ws + 17*MB);    // 1MB
  float* gbuf  = (float*)(ws + 12*MB);    // 12.6MB, overlaps q/k/v (dead by then)
  float* s_act = (float*)(ws + 25*MB);    // 2MB shared-expert activation
  char*  misc  = ws + 27*MB;
  int*   sel      = (int*)(misc);
  float* topw     = (float*)(misc + 24576);
  int*   counts   = (int*)(misc + 49152);
  int*   offs     = (int*)(misc + 49152 + 256);
  int*   cursor   = (int*)(misc + 49152 + 512);
  int*   shcnt    = (int*)(misc + 49152 + 768);
  int*   shoff    = (int*)(misc + 49152 + 1024);
  int*   tok_list = (int*)(misc + 49152 + 1280);
  float* wt_list  = (float*)(misc + 49152 + 1280 + 24576);
  int*   id_list  = (int*)(misc + 49152 + 1280 + 49152);

  // 1. attn rmsnorm
  rmsnorm_k<<<SEQ, 256, 0, stream>>>(x, anw, hx);
  // 2. QKV projections (split-bf16 MFMA)
  mfma_gemm_k<<<dim3(8, 64), 256, 0, stream>>>(hx, wq, qbuf, nullptr, nullptr, 1024, 1024);
  mfma_gemm_k<<<dim3(2, 64), 256, 0, stream>>>(hx, wk, kbuf, nullptr, nullptr, 256, 1024);
  mfma_gemm_k<<<dim3(2, 64), 256, 0, stream>>>(hx, wvv, vbuf, nullptr, nullptr, 256, 1024);
  // 3. q/k rmsnorm + rope
  qknorm_rope_k<<<dim3(SEQ, NHEADS + NKVH), 64, 0, stream>>>(qbuf, kbuf, qnw, knw, fcos, fsin);
  // 4. causal flash attention (bf16 MFMA) -> hx
  attn_mfma<<<dim3(SEQ / 64, NHEADS), 256, 0, stream>>>(qbuf, kbuf, vbuf, hx);
  // 5. o @ wo + x -> h (and d_out = h)
  mfma_gemm_k<<<dim3(8, 64), 256, 0, stream>>>(hx, wo, h, out, x, 1024, 1024);
  // 6. ffn rmsnorm
  rmsnorm_k<<<SEQ, 256, 0, stream>>>(h, fnw, z);
  // 7. gate + top-k + bucketing
  hipMemsetAsync(counts, 0, 256, stream);
  gate_topk_k<<<SEQ, 64, 0, stream>>>(z, gatew, sel, topw, counts);
  scan_k<<<1, 64, 0, stream>>>(counts, offs, cursor, shcnt, shoff);
  iota_k<<<SEQ / 256, 256, 0, stream>>>(id_list);
  scatter_k<<<SEQ / 256, 256, 0, stream>>>(sel, topw, cursor, tok_list, wt_list);
  // 8. MoE phase A: experts (BM=128) then shared expert
  moe_up2<<<dim3(HEXP / 64, NEXP, 1), 256, 0, stream>>>(z, w1e, w3e,
      (size_t)D_MODEL * HEXP, gbuf, tok_list, wt_list, counts, offs);
  moe_up2<<<dim3(HEXP / 64, 1, 8), 256, 0, stream>>>(z, sw1, sw3,
      0, s_act, id_list, nullptr, shcnt, shoff);
  // 9. MoE phase B: out += g @ w2 (scatter), out += s_act @ sw2
  moe_down2<<<dim3(D_MODEL / 128, NEXP, 1), 256, 0, stream>>>(gbuf, w2e,
      (size_t)HEXP * D_MODEL, out, tok_list, counts, offs);
  moe_down2<<<dim3(D_MODEL / 128, 1, 8), 256, 0, stream>>>(s_act, sw2,
      0, out, id_list, shcnt, shoff);
  (void)in_sizes; (void)n_in; (void)out_size; (void)ws_size;
}

// Round 5
// 617.885 us; speedup vs baseline: 6.4764x; 1.0907x over previous
//
#include <hip/hip_runtime.h>
#include <hip/hip_bf16.h>
#include <math.h>

#define D_MODEL 1024
#define SEQ     1024
#define NHEADS  16
#define NKVH    4
#define HDIM    64
#define NEXP    64
#define TOPK    6
#define HEXP    512
#define EPS     1e-5f
#define MAXTILES 112

typedef __attribute__((ext_vector_type(8))) short bf16x8;
typedef __attribute__((ext_vector_type(4))) float f32x4;

struct bfrag2 { bf16x8 hi, lo; };

__device__ __forceinline__ unsigned rne1(float a) {
  union { float f; unsigned u; } x; x.f = a;
  return (x.u + 0x7fffu + ((x.u >> 16) & 1u)) >> 16;
}
__device__ __forceinline__ float frombf(unsigned h) {
  union { float f; unsigned u; } x; x.u = h << 16; return x.f;
}
__device__ __forceinline__ void split_pack(float a, float b, unsigned& hi, unsigned& lo) {
  unsigned ha = rne1(a), hb = rne1(b);
  hi = ha | (hb << 16);
  lo = rne1(a - frombf(ha)) | (rne1(b - frombf(hb)) << 16);
}
__device__ __forceinline__ unsigned pk2bf(float a, float b) {
  return rne1(a) | (rne1(b) << 16);
}

__device__ __forceinline__ f32x4 mfma16(bf16x8 a, bf16x8 b, f32x4 c) {
  return __builtin_amdgcn_mfma_f32_16x16x32_bf16(a, b, c, 0, 0, 0);
}
__device__ __forceinline__ f32x4 mfma_sp(bf16x8 ah, bf16x8 al, const bfrag2& b, f32x4 c) {
  c = mfma16(ah, b.hi, c);
  c = mfma16(ah, b.lo, c);
  c = mfma16(al, b.hi, c);
  return c;
}

// split-precision B fragment from global f32 (col baked into p, k = (lane>>4)*8+j)
__device__ __forceinline__ bfrag2 load_bfrag2(const float* __restrict__ p, int ld) {
  float f0 = p[0];
  float f1 = p[(size_t)ld];
  float f2 = p[(size_t)ld * 2];
  float f3 = p[(size_t)ld * 3];
  float f4 = p[(size_t)ld * 4];
  float f5 = p[(size_t)ld * 5];
  float f6 = p[(size_t)ld * 6];
  float f7 = p[(size_t)ld * 7];
  union { bf16x8 v; unsigned u[4]; } H, L;
  split_pack(f0, f1, H.u[0], L.u[0]);
  split_pack(f2, f3, H.u[1], L.u[1]);
  split_pack(f4, f5, H.u[2], L.u[2]);
  split_pack(f6, f7, H.u[3], L.u[3]);
  bfrag2 r; r.hi = H.v; r.lo = L.v; return r;
}

// plain bf16 B fragment from global f32
__device__ __forceinline__ bf16x8 load_bfrag(const float* __restrict__ p, int ld) {
  float f0 = p[0];
  float f1 = p[(size_t)ld];
  float f2 = p[(size_t)ld * 2];
  float f3 = p[(size_t)ld * 3];
  float f4 = p[(size_t)ld * 4];
  float f5 = p[(size_t)ld * 5];
  float f6 = p[(size_t)ld * 6];
  float f7 = p[(size_t)ld * 7];
  union { bf16x8 v; unsigned u[4]; } r;
  r.u[0] = pk2bf(f0, f1); r.u[1] = pk2bf(f2, f3);
  r.u[2] = pk2bf(f4, f5); r.u[3] = pk2bf(f6, f7);
  return r.v;
}

// ---------------- rmsnorm over D=1024 (+ optional bf16 copy) ----------------
__global__ __launch_bounds__(256) void rmsnorm_k(const float* __restrict__ x,
    const float* __restrict__ w, float* __restrict__ out, ushort* __restrict__ outb) {
  int t = blockIdx.x;
  const float4* xr = (const float4*)(x + (size_t)t * D_MODEL);
  float4 v = xr[threadIdx.x];
  float ss = v.x*v.x + v.y*v.y + v.z*v.z + v.w*v.w;
  for (int off = 32; off; off >>= 1) ss += __shfl_xor(ss, off);
  __shared__ float red[4];
  if ((threadIdx.x & 63) == 0) red[threadIdx.x >> 6] = ss;
  __syncthreads();
  float tot = red[0] + red[1] + red[2] + red[3];
  float inv = rsqrtf(tot * (1.f / D_MODEL) + EPS);
  float4 wv = ((const float4*)w)[threadIdx.x];
  float4 o;
  o.x = v.x * inv * wv.x; o.y = v.y * inv * wv.y;
  o.z = v.z * inv * wv.z; o.w = v.w * inv * wv.w;
  ((float4*)(out + (size_t)t * D_MODEL))[threadIdx.x] = o;
  if (outb) {
    uint2 b;
    b.x = pk2bf(o.x, o.y); b.y = pk2bf(o.z, o.w);
    *(uint2*)(outb + (size_t)t * D_MODEL + threadIdx.x * 4) = b;
  }
}

// ---------------- dense split-bf16 MFMA GEMM (+resid, dual-store) ----------------
__global__ __launch_bounds__(256) void mfma_gemm_k(const float* __restrict__ A,
    const float* __restrict__ B, float* __restrict__ C, float* __restrict__ C2,
    const float* __restrict__ resid, int N, int K) {
  __shared__ short Ah[16][40];
  __shared__ short Al[16][40];
  int bm = blockIdx.y << 4, bn = blockIdx.x << 7;
  int tid = threadIdx.x, wv = tid >> 6, lane = tid & 63;
  int m_ = tid >> 4, k_ = (tid & 15) << 1;
  int arow = lane & 15, akb = (lane >> 4) << 3;
  int c0 = bn + wv * 32 + arow;
  const float* ar = A + (size_t)(bm + m_) * K + k_;
  f32x4 acc0 = {0.f,0.f,0.f,0.f}, acc1 = {0.f,0.f,0.f,0.f};
  for (int k0 = 0; k0 < K; k0 += 32) {
    float2 a2 = *(const float2*)(ar + k0);
    unsigned hi, lo; split_pack(a2.x, a2.y, hi, lo);
    *(unsigned*)&Ah[m_][k_] = hi;
    *(unsigned*)&Al[m_][k_] = lo;
    __syncthreads();
    bf16x8 ah = *(const bf16x8*)&Ah[arow][akb];
    bf16x8 al = *(const bf16x8*)&Al[arow][akb];
    const float* bp = B + (size_t)(k0 + akb) * N + c0;
    acc0 = mfma_sp(ah, al, load_bfrag2(bp, N), acc0);
    acc1 = mfma_sp(ah, al, load_bfrag2(bp + 16, N), acc1);
    __syncthreads();
  }
  int r0 = (lane >> 4) << 2;
#pragma unroll
  for (int ri = 0; ri < 4; ri++) {
    int row = bm + r0 + ri;
    size_t o0 = (size_t)row * N + c0;
    float v0 = acc0[ri], v1 = acc1[ri];
    if (resid) { v0 += resid[o0]; v1 += resid[o0 + 16]; }
    C[o0] = v0; C[o0 + 16] = v1;
    if (C2) { C2[o0] = v0; C2[o0 + 16] = v1; }
  }
}

// ---------------- per-head rmsnorm + RoPE ----------------
__global__ __launch_bounds__(64) void qknorm_rope_k(float* __restrict__ qb,
    float* __restrict__ kb, const float* __restrict__ qw, const float* __restrict__ kw,
    const float* __restrict__ fcos, const float* __restrict__ fsin) {
  int t = blockIdx.x, hid = blockIdx.y, lane = threadIdx.x;
  float* p; const float* w;
  if (hid < NHEADS) { p = qb + (size_t)t * (NHEADS*HDIM) + hid * HDIM; w = qw; }
  else              { p = kb + (size_t)t * (NKVH*HDIM) + (hid - NHEADS) * HDIM; w = kw; }
  float v = p[lane];
  float ss = v * v;
  for (int off = 32; off; off >>= 1) ss += __shfl_xor(ss, off);
  float vn = v * rsqrtf(ss * (1.f / HDIM) + EPS) * w[lane];
  int pi = lane >> 1;
  float c = fcos[t * (HDIM/2) + pi], s = fsin[t * (HDIM/2) + pi];
  float other = __shfl_xor(vn, 1);
  float o = (lane & 1) ? (other * s + vn * c) : (vn * c - other * s);
  p[lane] = o;
}

// ---------------- causal flash attention, bf16 MFMA, GQA 4:1 ----------------
__global__ __launch_bounds__(256) void attn_mfma(const float* __restrict__ qb,
    const float* __restrict__ kb, const float* __restrict__ vb, float* __restrict__ ob) {
  int h = blockIdx.y;
  int qbase = blockIdx.x << 6;
  int kvh = h >> 2;
  int tid = threadIdx.x, wv = tid >> 6, lane = tid & 63;
  __shared__ short Kt[64][72];
  __shared__ short Vt[64][72];
  __shared__ short Pl[4][16][72];
  int arow = lane & 15;
  int akb = (lane >> 4) << 3;
  int kg = lane >> 4;
  int qrow_base = qbase + wv * 16;
  bf16x8 qf[2];
  {
    const float* qp = qb + (size_t)(qrow_base + arow) * (NHEADS*HDIM) + h * HDIM;
#pragma unroll
    for (int c = 0; c < 2; c++) {
      int d0 = akb + c * 32;
      union { bf16x8 v; unsigned u[4]; } r;
#pragma unroll
      for (int j = 0; j < 4; j++) r.u[j] = pk2bf(qp[d0 + 2*j], qp[d0 + 2*j + 1]);
      qf[c] = r.v;
    }
  }
  f32x4 accO[4];
  float m_[4], l_[4];
#pragma unroll
  for (int n = 0; n < 4; n++) { accO[n] = (f32x4){0.f,0.f,0.f,0.f}; m_[n] = -1e30f; l_[n] = 0.f; }
  int ntiles = (qbase >> 6) + 1;
  for (int ti = 0; ti < ntiles; ti++) {
    int ts = ti << 6;
#pragma unroll
    for (int i = 0; i < 16; i++) {
      int flat = tid + i * 256;
      int kk = flat >> 6, dd = flat & 63;
      size_t src = (size_t)(ts + kk) * (NKVH*HDIM) + kvh * HDIM + dd;
      Kt[kk][dd] = (short)rne1(kb[src]);
      Vt[dd][kk] = (short)rne1(vb[src]);
    }
    __syncthreads();
    f32x4 accS[4];
#pragma unroll
    for (int n = 0; n < 4; n++) accS[n] = (f32x4){0.f,0.f,0.f,0.f};
#pragma unroll
    for (int c = 0; c < 2; c++) {
#pragma unroll
      for (int n = 0; n < 4; n++) {
        bf16x8 bf = *(const bf16x8*)&Kt[n*16 + arow][c*32 + akb];
        accS[n] = mfma16(qf[c], bf, accS[n]);
      }
    }
#pragma unroll
    for (int ri = 0; ri < 4; ri++) {
      int qrow = qrow_base + kg*4 + ri;
      float mx = -1e30f;
#pragma unroll
      for (int n = 0; n < 4; n++) {
        int key = ts + n*16 + arow;
        float s = (key <= qrow) ? accS[n][ri] * 0.125f : -1e30f;
        accS[n][ri] = s;
        mx = fmaxf(mx, s);
      }
      for (int off = 1; off < 16; off <<= 1) mx = fmaxf(mx, __shfl_xor(mx, off));
      float mn = fmaxf(m_[ri], mx);
      float a = __expf(m_[ri] - mn);
      float sum = 0.f;
#pragma unroll
      for (int n = 0; n < 4; n++) {
        float p = __expf(accS[n][ri] - mn);
        accS[n][ri] = p;
        sum += p;
      }
      for (int off = 1; off < 16; off <<= 1) sum += __shfl_xor(sum, off);
      l_[ri] = l_[ri] * a + sum;
      m_[ri] = mn;
#pragma unroll
      for (int n = 0; n < 4; n++) accO[n][ri] *= a;
    }
#pragma unroll
    for (int ri = 0; ri < 4; ri++)
#pragma unroll
      for (int n = 0; n < 4; n++)
        Pl[wv][kg*4 + ri][n*16 + arow] = (short)rne1(accS[n][ri]);
#pragma unroll
    for (int c = 0; c < 2; c++) {
      bf16x8 pf = *(const bf16x8*)&Pl[wv][arow][c*32 + akb];
#pragma unroll
      for (int n = 0; n < 4; n++) {
        bf16x8 vf = *(const bf16x8*)&Vt[n*16 + arow][c*32 + akb];
        accO[n] = mfma16(pf, vf, accO[n]);
      }
    }
    __syncthreads();
  }
#pragma unroll
  for (int ri = 0; ri < 4; ri++) {
    int qrow = qrow_base + kg*4 + ri;
    float inv = 1.f / l_[ri];
#pragma unroll
    for (int n = 0; n < 4; n++)
      ob[(size_t)qrow * (NHEADS*HDIM) + h * HDIM + n*16 + arow] = accO[n][ri] * inv;
  }
}

// ---------------- gate: softmax -> top-6 (low-index tie-break) ----------------
__global__ __launch_bounds__(64) void gate_topk_k(const float* __restrict__ z,
    const float* __restrict__ gw, int* __restrict__ sel, float* __restrict__ topw,
    int* __restrict__ counts) {
  int t = blockIdx.x, lane = threadIdx.x;
  const float* zr = z + (size_t)t * D_MODEL;
  float acc = 0.f;
  for (int d = 0; d < D_MODEL; d += 4) {
    float4 zv = *(const float4*)(zr + d);
    acc += zv.x * gw[(size_t)(d + 0) * NEXP + lane];
    acc += zv.y * gw[(size_t)(d + 1) * NEXP + lane];
    acc += zv.z * gw[(size_t)(d + 2) * NEXP + lane];
    acc += zv.w * gw[(size_t)(d + 3) * NEXP + lane];
  }
  float m = acc;
  for (int off = 32; off; off >>= 1) m = fmaxf(m, __shfl_xor(m, off));
  float p = __expf(acc - m);
  float s = p;
  for (int off = 32; off; off >>= 1) s += __shfl_xor(s, off);
  p /= s;
  float rem = p, wsum = 0.f;
  float wvv[TOPK]; int wi[TOPK];
  for (int i = 0; i < TOPK; i++) {
    float v = rem; int idx = lane;
    for (int off = 32; off; off >>= 1) {
      float v2 = __shfl_xor(v, off);
      int i2 = __shfl_xor(idx, off);
      if (v2 > v || (v2 == v && i2 < idx)) { v = v2; idx = i2; }
    }
    wvv[i] = v; wi[i] = idx; wsum += v;
    if (lane == idx) rem = -1.f;
  }
  if (lane < TOPK) {
    sel[t * TOPK + lane] = wi[lane];
    topw[t * TOPK + lane] = wvv[lane] / wsum;
  }
  if (lane == 0)
    for (int i = 0; i < TOPK; i++) atomicAdd(&counts[wi[i]], 1);
}

// ---------------- scan + flattened (expert, mtile) work list ----------------
__global__ void scan_k(const int* __restrict__ counts, int* __restrict__ offs,
                       int* __restrict__ cursor, int* __restrict__ shcnt,
                       int* __restrict__ shoff, int* __restrict__ tile2e,
                       int* __restrict__ tile2mt, int* __restrict__ ntiles) {
  int lane = threadIdx.x;
  int c = counts[lane];
  int x = c;
  for (int off = 1; off < 64; off <<= 1) {
    int y = __shfl_up(x, off);
    if (lane >= off) x += y;
  }
  offs[lane] = x - c;
  cursor[lane] = x - c;
  int nt = (c + 127) >> 7;
  int y = nt;
  for (int off = 1; off < 64; off <<= 1) {
    int t2 = __shfl_up(y, off);
    if (lane >= off) y += t2;
  }
  int tbase = y - nt;
  for (int i = 0; i < nt; i++) { tile2e[tbase + i] = lane; tile2mt[tbase + i] = i; }
  if (lane == 63) ntiles[0] = y;
  if (lane == 0) { shcnt[0] = SEQ; shoff[0] = 0; }
}

__global__ void iota_k(int* p) {
  int i = blockIdx.x * 256 + threadIdx.x;
  p[i] = i;
}

__global__ void scatter_k(const int* __restrict__ sel, const float* __restrict__ topw,
    int* __restrict__ cursor, int* __restrict__ tok, float* __restrict__ wt) {
  int t = blockIdx.x * 256 + threadIdx.x;
  if (t >= SEQ) return;
  for (int i = 0; i < TOPK; i++) {
    int e = sel[t * TOPK + i];
    int pos = atomicAdd(&cursor[e], 1);
    tok[pos] = t;
    wt[pos] = topw[t * TOPK + i];
  }
}

// ---------------- MoE phase A (plain bf16, tile list): g = silu(Z@w1)*(Z@w3)*wt ----
// grid = (HEXP/64, ntile_slots); one 128-row tile x 64 cols per block.
__global__ __launch_bounds__(256) void moe_up3(const ushort* __restrict__ zb,
    const float* __restrict__ w1, const float* __restrict__ w3, size_t wstride,
    ushort* __restrict__ g, const int* __restrict__ tok_list,
    const float* __restrict__ wt_list, const int* __restrict__ counts,
    const int* __restrict__ offs, const int* __restrict__ tile2e,
    const int* __restrict__ tile2mt, const int* __restrict__ ntiles) {
  int e, mt;
  if (tile2e) {
    int gt = blockIdx.y;
    if (gt >= ntiles[0]) return;
    e = tile2e[gt]; mt = tile2mt[gt] << 7;
  } else { e = 0; mt = blockIdx.y << 7; }
  int cnt = counts[e];
  int off = offs[e];
  const float* w1p = w1 + (size_t)e * wstride;
  const float* w3p = w3 + (size_t)e * wstride;
  __shared__ ushort Ah[128][40];
  __shared__ int toks[128];
  int tid = threadIdx.x, wv = tid >> 6, lane = tid & 63;
  int arow = lane & 15, akb = (lane >> 4) << 3, kg = lane >> 4;
  int c0 = (blockIdx.x << 6) + wv * 16 + arow;
  if (tid < 128) {
    int r = mt + tid; if (r >= cnt) r = cnt - 1;
    toks[tid] = tok_list[off + r];
  }
  __syncthreads();
  f32x4 a1[8], a3[8];
#pragma unroll
  for (int f = 0; f < 8; f++) { a1[f] = (f32x4){0.f,0.f,0.f,0.f}; a3[f] = (f32x4){0.f,0.f,0.f,0.f}; }
  for (int k0 = 0; k0 < D_MODEL; k0 += 32) {
#pragma unroll
    for (int i = 0; i < 2; i++) {
      int flat = tid + i * 256;
      int row = flat >> 2, q = flat & 3;
      const ushort* zp = zb + (size_t)toks[row] * D_MODEL + k0 + q * 8;
      *(uint4*)&Ah[row][q * 8] = *(const uint4*)zp;
    }
    __syncthreads();
    bf16x8 b1 = load_bfrag(w1p + (size_t)(k0 + akb) * HEXP + c0, HEXP);
    bf16x8 b3 = load_bfrag(w3p + (size_t)(k0 + akb) * HEXP + c0, HEXP);
#pragma unroll
    for (int f = 0; f < 8; f++) {
      bf16x8 ah = *(const bf16x8*)&Ah[f*16 + arow][akb];
      a1[f] = mfma16(ah, b1, a1[f]);
      a3[f] = mfma16(ah, b3, a3[f]);
    }
    __syncthreads();
  }
#pragma unroll
  for (int f = 0; f < 8; f++)
#pragma unroll
    for (int ri = 0; ri < 4; ri++) {
      int r = mt + f*16 + kg*4 + ri;
      if (r < cnt) {
        float wt = wt_list ? wt_list[off + r] : 1.0f;
        float h1 = a1[f][ri], h3 = a3[f][ri];
        float gv = h1 / (1.f + __expf(-h1)) * h3 * wt;
        g[(size_t)(off + r) * HEXP + c0] = (ushort)rne1(gv);
      }
    }
}

// ---------------- MoE phase B (plain bf16, tile list): out[tok] += g @ w2 ----------
// grid = (D_MODEL/128, ntile_slots).
__global__ __launch_bounds__(256) void moe_down3(const ushort* __restrict__ g,
    const float* __restrict__ w2, size_t wstride, float* __restrict__ out,
    const int* __restrict__ tok_list, const int* __restrict__ counts,
    const int* __restrict__ offs, const int* __restrict__ tile2e,
    const int* __restrict__ tile2mt, const int* __restrict__ ntiles) {
  int e, mt;
  if (tile2e) {
    int gt = blockIdx.y;
    if (gt >= ntiles[0]) return;
    e = tile2e[gt]; mt = tile2mt[gt] << 7;
  } else { e = 0; mt = blockIdx.y << 7; }
  int cnt = counts[e];
  int off = offs[e];
  const float* w2p = w2 + (size_t)e * wstride;
  __shared__ ushort Ah[128][40];
  int tid = threadIdx.x, wv = tid >> 6, lane = tid & 63;
  int arow = lane & 15, akb = (lane >> 4) << 3, kg = lane >> 4;
  int c0 = (blockIdx.x << 7) + wv * 32 + arow;
  f32x4 ac0[8], ac1[8];
#pragma unroll
  for (int f = 0; f < 8; f++) { ac0[f] = (f32x4){0.f,0.f,0.f,0.f}; ac1[f] = (f32x4){0.f,0.f,0.f,0.f}; }
  for (int k0 = 0; k0 < HEXP; k0 += 32) {
#pragma unroll
    for (int i = 0; i < 2; i++) {
      int flat = tid + i * 256;
      int row = flat >> 2, q = flat & 3;
      int r = mt + row; if (r >= cnt) r = cnt - 1;
      const ushort* gp = g + (size_t)(off + r) * HEXP + k0 + q * 8;
      *(uint4*)&Ah[row][q * 8] = *(const uint4*)gp;
    }
    __syncthreads();
    bf16x8 b0 = load_bfrag(w2p + (size_t)(k0 + akb) * D_MODEL + c0, D_MODEL);
    bf16x8 b1 = load_bfrag(w2p + (size_t)(k0 + akb) * D_MODEL + c0 + 16, D_MODEL);
#pragma unroll
    for (int f = 0; f < 8; f++) {
      bf16x8 ah = *(const bf16x8*)&Ah[f*16 + arow][akb];
      ac0[f] = mfma16(ah, b0, ac0[f]);
      ac1[f] = mfma16(ah, b1, ac1[f]);
    }
    __syncthreads();
  }
#pragma unroll
  for (int f = 0; f < 8; f++)
#pragma unroll
    for (int ri = 0; ri < 4; ri++) {
      int r = mt + f*16 + kg*4 + ri;
      if (r < cnt) {
        int tok = tok_list[off + r];
        float* op = out + (size_t)tok * D_MODEL + c0;
        atomicAdd(op, ac0[f][ri]);
        atomicAdd(op + 16, ac1[f][ri]);
      }
    }
}

// ---------------- host ----------------
extern "C" void kernel_launch(void* const* d_in, const int* in_sizes, int n_in,
                              void* d_out, int out_size, void* d_ws, size_t ws_size,
                              hipStream_t stream) {
  const float* x     = (const float*)d_in[0];
  const float* fcos  = (const float*)d_in[1];
  const float* fsin  = (const float*)d_in[2];
  const float* anw   = (const float*)d_in[3];
  const float* fnw   = (const float*)d_in[4];
  const float* wq    = (const float*)d_in[5];
  const float* wk    = (const float*)d_in[6];
  const float* wvv   = (const float*)d_in[7];
  const float* wo    = (const float*)d_in[8];
  const float* qnw   = (const float*)d_in[9];
  const float* knw   = (const float*)d_in[10];
  const float* gatew = (const float*)d_in[11];
  const float* w1e   = (const float*)d_in[12];
  const float* w3e   = (const float*)d_in[13];
  const float* w2e   = (const float*)d_in[14];
  const float* sw1   = (const float*)d_in[15];
  const float* sw3   = (const float*)d_in[16];
  const float* sw2   = (const float*)d_in[17];
  float* out = (float*)d_out;

  char* ws = (char*)d_ws;
  const size_t MB = 1ull << 20;
  float*  hx    = (float*)(ws);             // 4MB (attn-norm out, then attn out)
  float*  h     = (float*)(ws + 4*MB);      // 4MB residual after attention
  float*  z     = (float*)(ws + 8*MB);      // 4MB ffn-norm out (f32, for gate)
  float*  qbuf  = (float*)(ws + 12*MB);     // 4MB   (dead after attention)
  float*  kbuf  = (float*)(ws + 16*MB);     // 1MB
  float*  vbuf  = (float*)(ws + 17*MB);     // 1MB
  ushort* zb    = (ushort*)(ws + 12*MB);    // 2MB bf16 z (overlaps dead qbuf)
  ushort* gb    = (ushort*)(ws + 14*MB);    // 6.3MB bf16 expert activations
  ushort* s_gb  = (ushort*)(ws + 20*MB + 512*1024); // 1MB shared-expert act
  char*   misc  = ws + 22*MB;
  int*   sel      = (int*)(misc);
  float* topw     = (float*)(misc + 24576);
  int*   counts   = (int*)(misc + 49152);
  int*   offs     = (int*)(misc + 49408);
  int*   cursor   = (int*)(misc + 49664);
  int*   shcnt    = (int*)(misc + 49920);
  int*   shoff    = (int*)(misc + 50176);
  int*   ntiles   = (int*)(misc + 50432);
  int*   tile2e   = (int*)(misc + 50688);
  int*   tile2mt  = (int*)(misc + 51200);
  int*   tok_list = (int*)(misc + 51712);
  float* wt_list  = (float*)(misc + 76288);
  int*   id_list  = (int*)(misc + 100864);

  // 1. attn rmsnorm
  rmsnorm_k<<<SEQ, 256, 0, stream>>>(x, anw, hx, nullptr);
  // 2. QKV projections (split-bf16 MFMA)
  mfma_gemm_k<<<dim3(8, 64), 256, 0, stream>>>(hx, wq, qbuf, nullptr, nullptr, 1024, 1024);
  mfma_gemm_k<<<dim3(2, 64), 256, 0, stream>>>(hx, wk, kbuf, nullptr, nullptr, 256, 1024);
  mfma_gemm_k<<<dim3(2, 64), 256, 0, stream>>>(hx, wvv, vbuf, nullptr, nullptr, 256, 1024);
  // 3. q/k rmsnorm + rope
  qknorm_rope_k<<<dim3(SEQ, NHEADS + NKVH), 64, 0, stream>>>(qbuf, kbuf, qnw, knw, fcos, fsin);
  // 4. causal flash attention (bf16 MFMA) -> hx
  attn_mfma<<<dim3(SEQ / 64, NHEADS), 256, 0, stream>>>(qbuf, kbuf, vbuf, hx);
  // 5. o @ wo + x -> h (and d_out = h)
  mfma_gemm_k<<<dim3(8, 64), 256, 0, stream>>>(hx, wo, h, out, x, 1024, 1024);
  // 6. ffn rmsnorm -> z (f32) + zb (bf16)
  rmsnorm_k<<<SEQ, 256, 0, stream>>>(h, fnw, z, zb);
  // 7. gate + top-k + bucketing + tile list
  hipMemsetAsync(counts, 0, 256, stream);
  gate_topk_k<<<SEQ, 64, 0, stream>>>(z, gatew, sel, topw, counts);
  scan_k<<<1, 64, 0, stream>>>(counts, offs, cursor, shcnt, shoff, tile2e, tile2mt, ntiles);
  iota_k<<<SEQ / 256, 256, 0, stream>>>(id_list);
  scatter_k<<<SEQ / 256, 256, 0, stream>>>(sel, topw, cursor, tok_list, wt_list);
  // 8. MoE phase A: experts (flattened tiles) then shared expert
  moe_up3<<<dim3(HEXP / 64, MAXTILES), 256, 0, stream>>>(zb, w1e, w3e,
      (size_t)D_MODEL * HEXP, gb, tok_list, wt_list, counts, offs, tile2e, tile2mt, ntiles);
  moe_up3<<<dim3(HEXP / 64, SEQ / 128), 256, 0, stream>>>(zb, sw1, sw3,
      0, s_gb, id_list, nullptr, shcnt, shoff, nullptr, nullptr, nullptr);
  // 9. MoE phase B: out += g @ w2 (scatter), out += s_gb @ sw2
  moe_down3<<<dim3(D_MODEL / 128, MAXTILES), 256, 0, stream>>>(gb, w2e,
      (size_t)HEXP * D_MODEL, out, tok_list, counts, offs, tile2e, tile2mt, ntiles);
  moe_down3<<<dim3(D_MODEL / 128, SEQ / 128), 256, 0, stream>>>(s_gb, sw2,
      0, out, id_list, shcnt, shoff, nullptr, nullptr, nullptr);
  (void)in_sizes; (void)n_in; (void)out_size; (void)ws_size;
}

// Round 6
// 425.219 us; speedup vs baseline: 9.4109x; 1.4531x over previous
//
#include <hip/hip_runtime.h>
#include <hip/hip_bf16.h>
#include <math.h>

#define D_MODEL 1024
#define SEQ     1024
#define NHEADS  16
#define NKVH    4
#define HDIM    64
#define NEXP    64
#define TOPK    6
#define HEXP    512
#define EPS     1e-5f
#define MAXTILES 120   // 112 expert tiles max + 8 shared-expert tiles

typedef __attribute__((ext_vector_type(8))) short bf16x8;
typedef __attribute__((ext_vector_type(4))) float f32x4;

struct bfrag2 { bf16x8 hi, lo; };
struct f32x8r { float v[8]; };

__device__ __forceinline__ unsigned rne1(float a) {
  union { float f; unsigned u; } x; x.f = a;
  return (x.u + 0x7fffu + ((x.u >> 16) & 1u)) >> 16;
}
__device__ __forceinline__ float frombf(unsigned h) {
  union { float f; unsigned u; } x; x.u = h << 16; return x.f;
}
__device__ __forceinline__ void split_pack(float a, float b, unsigned& hi, unsigned& lo) {
  unsigned ha = rne1(a), hb = rne1(b);
  hi = ha | (hb << 16);
  lo = rne1(a - frombf(ha)) | (rne1(b - frombf(hb)) << 16);
}
__device__ __forceinline__ unsigned pk2bf(float a, float b) {
  return rne1(a) | (rne1(b) << 16);
}

__device__ __forceinline__ f32x4 mfma16(bf16x8 a, bf16x8 b, f32x4 c) {
  return __builtin_amdgcn_mfma_f32_16x16x32_bf16(a, b, c, 0, 0, 0);
}
__device__ __forceinline__ f32x4 mfma_sp(bf16x8 ah, bf16x8 al, const bfrag2& b, f32x4 c) {
  c = mfma16(ah, b.hi, c);
  c = mfma16(ah, b.lo, c);
  c = mfma16(al, b.hi, c);
  return c;
}

// raw 8-float strided fetch (B fragment, conversion deferred)
__device__ __forceinline__ f32x8r loadraw8(const float* __restrict__ p, int ld) {
  f32x8r r;
#pragma unroll
  for (int i = 0; i < 8; i++) r.v[i] = p[(size_t)ld * i];
  return r;
}
__device__ __forceinline__ bf16x8 cvt_bf(const f32x8r& f) {
  union { bf16x8 v; unsigned u[4]; } r;
  r.u[0] = pk2bf(f.v[0], f.v[1]); r.u[1] = pk2bf(f.v[2], f.v[3]);
  r.u[2] = pk2bf(f.v[4], f.v[5]); r.u[3] = pk2bf(f.v[6], f.v[7]);
  return r.v;
}
__device__ __forceinline__ bfrag2 cvt_bf2(const f32x8r& f) {
  union { bf16x8 v; unsigned u[4]; } H, L;
  split_pack(f.v[0], f.v[1], H.u[0], L.u[0]);
  split_pack(f.v[2], f.v[3], H.u[1], L.u[1]);
  split_pack(f.v[4], f.v[5], H.u[2], L.u[2]);
  split_pack(f.v[6], f.v[7], H.u[3], L.u[3]);
  bfrag2 r; r.hi = H.v; r.lo = L.v; return r;
}

// ---------------- rmsnorm over D=1024 (+ optional bf16 copy) ----------------
__global__ __launch_bounds__(256) void rmsnorm_k(const float* __restrict__ x,
    const float* __restrict__ w, float* __restrict__ out, ushort* __restrict__ outb) {
  int t = blockIdx.x;
  const float4* xr = (const float4*)(x + (size_t)t * D_MODEL);
  float4 v = xr[threadIdx.x];
  float ss = v.x*v.x + v.y*v.y + v.z*v.z + v.w*v.w;
  for (int off = 32; off; off >>= 1) ss += __shfl_xor(ss, off);
  __shared__ float red[4];
  if ((threadIdx.x & 63) == 0) red[threadIdx.x >> 6] = ss;
  __syncthreads();
  float tot = red[0] + red[1] + red[2] + red[3];
  float inv = rsqrtf(tot * (1.f / D_MODEL) + EPS);
  float4 wv = ((const float4*)w)[threadIdx.x];
  float4 o;
  o.x = v.x * inv * wv.x; o.y = v.y * inv * wv.y;
  o.z = v.z * inv * wv.z; o.w = v.w * inv * wv.w;
  ((float4*)(out + (size_t)t * D_MODEL))[threadIdx.x] = o;
  if (outb) {
    uint2 b;
    b.x = pk2bf(o.x, o.y); b.y = pk2bf(o.z, o.w);
    *(uint2*)(outb + (size_t)t * D_MODEL + threadIdx.x * 4) = b;
  }
}

// ---------------- dense split-bf16 MFMA GEMM, pipelined (+resid, dual-store) -------
// BM=16, BN=128, 4 waves. grid = (N/128, M/16).
__global__ __launch_bounds__(256) void mfma_gemm_k(const float* __restrict__ A,
    const float* __restrict__ B, float* __restrict__ C, float* __restrict__ C2,
    const float* __restrict__ resid, int N, int K) {
  __shared__ short Ah[2][16][40];
  __shared__ short Al[2][16][40];
  int bm = blockIdx.y << 4, bn = blockIdx.x << 7;
  int tid = threadIdx.x, wv = tid >> 6, lane = tid & 63;
  int m_ = tid >> 4, k_ = (tid & 15) << 1;
  int arow = lane & 15, akb = (lane >> 4) << 3;
  int c0 = bn + wv * 32 + arow;
  const float* ar = A + (size_t)(bm + m_) * K + k_;
  // prologue: stage k0=0
  {
    float2 a2 = *(const float2*)ar;
    unsigned hi, lo; split_pack(a2.x, a2.y, hi, lo);
    *(unsigned*)&Ah[0][m_][k_] = hi;
    *(unsigned*)&Al[0][m_][k_] = lo;
  }
  f32x8r b0r = loadraw8(B + (size_t)akb * N + c0, N);
  f32x8r b1r = loadraw8(B + (size_t)akb * N + c0 + 16, N);
  __syncthreads();
  f32x4 acc0 = {0.f,0.f,0.f,0.f}, acc1 = {0.f,0.f,0.f,0.f};
  int cur = 0;
  for (int k0 = 0; k0 < K; k0 += 32) {
    int kp = (k0 + 32 < K) ? k0 + 32 : 0;
    float2 a2n = *(const float2*)(ar + kp);
    f32x8r b0n = loadraw8(B + (size_t)(kp + akb) * N + c0, N);
    f32x8r b1n = loadraw8(B + (size_t)(kp + akb) * N + c0 + 16, N);
    bfrag2 bf0 = cvt_bf2(b0r), bf1 = cvt_bf2(b1r);
    bf16x8 ah = *(const bf16x8*)&Ah[cur][arow][akb];
    bf16x8 al = *(const bf16x8*)&Al[cur][arow][akb];
    acc0 = mfma_sp(ah, al, bf0, acc0);
    acc1 = mfma_sp(ah, al, bf1, acc1);
    unsigned hi, lo; split_pack(a2n.x, a2n.y, hi, lo);
    *(unsigned*)&Ah[cur ^ 1][m_][k_] = hi;
    *(unsigned*)&Al[cur ^ 1][m_][k_] = lo;
    __syncthreads();
    b0r = b0n; b1r = b1n; cur ^= 1;
  }
  int r0 = (lane >> 4) << 2;
#pragma unroll
  for (int ri = 0; ri < 4; ri++) {
    int row = bm + r0 + ri;
    size_t o0 = (size_t)row * N + c0;
    float v0 = acc0[ri], v1 = acc1[ri];
    if (resid) { v0 += resid[o0]; v1 += resid[o0 + 16]; }
    C[o0] = v0; C[o0 + 16] = v1;
    if (C2) { C2[o0] = v0; C2[o0 + 16] = v1; }
  }
}

// ---------------- per-head rmsnorm + RoPE ----------------
__global__ __launch_bounds__(64) void qknorm_rope_k(float* __restrict__ qb,
    float* __restrict__ kb, const float* __restrict__ qw, const float* __restrict__ kw,
    const float* __restrict__ fcos, const float* __restrict__ fsin) {
  int t = blockIdx.x, hid = blockIdx.y, lane = threadIdx.x;
  float* p; const float* w;
  if (hid < NHEADS) { p = qb + (size_t)t * (NHEADS*HDIM) + hid * HDIM; w = qw; }
  else              { p = kb + (size_t)t * (NKVH*HDIM) + (hid - NHEADS) * HDIM; w = kw; }
  float v = p[lane];
  float ss = v * v;
  for (int off = 32; off; off >>= 1) ss += __shfl_xor(ss, off);
  float vn = v * rsqrtf(ss * (1.f / HDIM) + EPS) * w[lane];
  int pi = lane >> 1;
  float c = fcos[t * (HDIM/2) + pi], s = fsin[t * (HDIM/2) + pi];
  float other = __shfl_xor(vn, 1);
  float o = (lane & 1) ? (other * s + vn * c) : (vn * c - other * s);
  p[lane] = o;
}

// ---------------- causal flash attention, bf16 MFMA, GQA 4:1 ----------------
__global__ __launch_bounds__(256) void attn_mfma(const float* __restrict__ qb,
    const float* __restrict__ kb, const float* __restrict__ vb, float* __restrict__ ob) {
  int h = blockIdx.y;
  int qbase = blockIdx.x << 6;
  int kvh = h >> 2;
  int tid = threadIdx.x, wv = tid >> 6, lane = tid & 63;
  __shared__ short Kt[64][72];
  __shared__ short Vt[64][72];
  __shared__ short Pl[4][16][72];
  int arow = lane & 15;
  int akb = (lane >> 4) << 3;
  int kg = lane >> 4;
  int qrow_base = qbase + wv * 16;
  bf16x8 qf[2];
  {
    const float* qp = qb + (size_t)(qrow_base + arow) * (NHEADS*HDIM) + h * HDIM;
#pragma unroll
    for (int c = 0; c < 2; c++) {
      int d0 = akb + c * 32;
      union { bf16x8 v; unsigned u[4]; } r;
#pragma unroll
      for (int j = 0; j < 4; j++) r.u[j] = pk2bf(qp[d0 + 2*j], qp[d0 + 2*j + 1]);
      qf[c] = r.v;
    }
  }
  f32x4 accO[4];
  float m_[4], l_[4];
#pragma unroll
  for (int n = 0; n < 4; n++) { accO[n] = (f32x4){0.f,0.f,0.f,0.f}; m_[n] = -1e30f; l_[n] = 0.f; }
  int ntiles = (qbase >> 6) + 1;
  for (int ti = 0; ti < ntiles; ti++) {
    int ts = ti << 6;
#pragma unroll
    for (int i = 0; i < 16; i++) {
      int flat = tid + i * 256;
      int kk = flat >> 6, dd = flat & 63;
      size_t src = (size_t)(ts + kk) * (NKVH*HDIM) + kvh * HDIM + dd;
      Kt[kk][dd] = (short)rne1(kb[src]);
      Vt[dd][kk] = (short)rne1(vb[src]);
    }
    __syncthreads();
    f32x4 accS[4];
#pragma unroll
    for (int n = 0; n < 4; n++) accS[n] = (f32x4){0.f,0.f,0.f,0.f};
#pragma unroll
    for (int c = 0; c < 2; c++) {
#pragma unroll
      for (int n = 0; n < 4; n++) {
        bf16x8 bf = *(const bf16x8*)&Kt[n*16 + arow][c*32 + akb];
        accS[n] = mfma16(qf[c], bf, accS[n]);
      }
    }
#pragma unroll
    for (int ri = 0; ri < 4; ri++) {
      int qrow = qrow_base + kg*4 + ri;
      float mx = -1e30f;
#pragma unroll
      for (int n = 0; n < 4; n++) {
        int key = ts + n*16 + arow;
        float s = (key <= qrow) ? accS[n][ri] * 0.125f : -1e30f;
        accS[n][ri] = s;
        mx = fmaxf(mx, s);
      }
      for (int off = 1; off < 16; off <<= 1) mx = fmaxf(mx, __shfl_xor(mx, off));
      float mn = fmaxf(m_[ri], mx);
      float a = __expf(m_[ri] - mn);
      float sum = 0.f;
#pragma unroll
      for (int n = 0; n < 4; n++) {
        float p = __expf(accS[n][ri] - mn);
        accS[n][ri] = p;
        sum += p;
      }
      for (int off = 1; off < 16; off <<= 1) sum += __shfl_xor(sum, off);
      l_[ri] = l_[ri] * a + sum;
      m_[ri] = mn;
#pragma unroll
      for (int n = 0; n < 4; n++) accO[n][ri] *= a;
    }
#pragma unroll
    for (int ri = 0; ri < 4; ri++)
#pragma unroll
      for (int n = 0; n < 4; n++)
        Pl[wv][kg*4 + ri][n*16 + arow] = (short)rne1(accS[n][ri]);
#pragma unroll
    for (int c = 0; c < 2; c++) {
      bf16x8 pf = *(const bf16x8*)&Pl[wv][arow][c*32 + akb];
#pragma unroll
      for (int n = 0; n < 4; n++) {
        bf16x8 vf = *(const bf16x8*)&Vt[n*16 + arow][c*32 + akb];
        accO[n] = mfma16(pf, vf, accO[n]);
      }
    }
    __syncthreads();
  }
#pragma unroll
  for (int ri = 0; ri < 4; ri++) {
    int qrow = qrow_base + kg*4 + ri;
    float inv = 1.f / l_[ri];
#pragma unroll
    for (int n = 0; n < 4; n++)
      ob[(size_t)qrow * (NHEADS*HDIM) + h * HDIM + n*16 + arow] = accO[n][ri] * inv;
  }
}

// ---------------- gate: softmax -> top-6 (low-index tie-break) ----------------
__global__ __launch_bounds__(64) void gate_topk_k(const float* __restrict__ z,
    const float* __restrict__ gw, int* __restrict__ sel, float* __restrict__ topw,
    int* __restrict__ counts) {
  int t = blockIdx.x, lane = threadIdx.x;
  const float* zr = z + (size_t)t * D_MODEL;
  float acc = 0.f;
  for (int d = 0; d < D_MODEL; d += 4) {
    float4 zv = *(const float4*)(zr + d);
    acc += zv.x * gw[(size_t)(d + 0) * NEXP + lane];
    acc += zv.y * gw[(size_t)(d + 1) * NEXP + lane];
    acc += zv.z * gw[(size_t)(d + 2) * NEXP + lane];
    acc += zv.w * gw[(size_t)(d + 3) * NEXP + lane];
  }
  float m = acc;
  for (int off = 32; off; off >>= 1) m = fmaxf(m, __shfl_xor(m, off));
  float p = __expf(acc - m);
  float s = p;
  for (int off = 32; off; off >>= 1) s += __shfl_xor(s, off);
  p /= s;
  float rem = p, wsum = 0.f;
  float wvv[TOPK]; int wi[TOPK];
  for (int i = 0; i < TOPK; i++) {
    float v = rem; int idx = lane;
    for (int off = 32; off; off >>= 1) {
      float v2 = __shfl_xor(v, off);
      int i2 = __shfl_xor(idx, off);
      if (v2 > v || (v2 == v && i2 < idx)) { v = v2; idx = i2; }
    }
    wvv[i] = v; wi[i] = idx; wsum += v;
    if (lane == idx) rem = -1.f;
  }
  if (lane < TOPK) {
    sel[t * TOPK + lane] = wi[lane];
    topw[t * TOPK + lane] = wvv[lane] / wsum;
  }
  if (lane == 0)
    for (int i = 0; i < TOPK; i++) atomicAdd(&counts[wi[i]], 1);
}

// ---------------- scan + flattened (expert, mtile) work list (+shared tiles) -------
__global__ void scan_k(const int* __restrict__ counts, int* __restrict__ offs,
                       int* __restrict__ cursor, int* __restrict__ tile2e,
                       int* __restrict__ tile2mt, int* __restrict__ ntiles) {
  int lane = threadIdx.x;
  int c = counts[lane];
  int x = c;
  for (int off = 1; off < 64; off <<= 1) {
    int y = __shfl_up(x, off);
    if (lane >= off) x += y;
  }
  offs[lane] = x - c;
  cursor[lane] = x - c;
  int nt = (c + 127) >> 7;
  int y = nt;
  for (int off = 1; off < 64; off <<= 1) {
    int t2 = __shfl_up(y, off);
    if (lane >= off) y += t2;
  }
  int tbase = y - nt;
  for (int i = 0; i < nt; i++) { tile2e[tbase + i] = lane; tile2mt[tbase + i] = i; }
  if (lane == 63) {
    // append 8 shared-expert tiles (e = NEXP, 1024 tokens / 128)
    for (int i = 0; i < 8; i++) { tile2e[y + i] = NEXP; tile2mt[y + i] = i; }
    ntiles[0] = y + 8;
  }
}

__global__ void scatter_k(const int* __restrict__ sel, const float* __restrict__ topw,
    int* __restrict__ cursor, int* __restrict__ tok, float* __restrict__ wt) {
  int t = blockIdx.x * 256 + threadIdx.x;
  if (t >= SEQ) return;
  for (int i = 0; i < TOPK; i++) {
    int e = sel[t * TOPK + i];
    int pos = atomicAdd(&cursor[e], 1);
    tok[pos] = t;
    wt[pos] = topw[t * TOPK + i];
  }
}

// ---------------- MoE phase A (bf16, pipelined, shared-expert fused) ----------------
// grid = (HEXP/64, MAXTILES); one 128-row x 64-col tile per block.
__global__ __launch_bounds__(256) void moe_up4(const ushort* __restrict__ zb,
    const float* __restrict__ w1, const float* __restrict__ w3, size_t wstride,
    const float* __restrict__ sw1, const float* __restrict__ sw3,
    ushort* __restrict__ g, ushort* __restrict__ sg,
    const int* __restrict__ tok_list, const float* __restrict__ wt_list,
    const int* __restrict__ counts, const int* __restrict__ offs,
    const int* __restrict__ tile2e, const int* __restrict__ tile2mt,
    const int* __restrict__ ntiles) {
  int gt = blockIdx.y;
  if (gt >= ntiles[0]) return;
  int e = tile2e[gt];
  int mt = tile2mt[gt] << 7;
  bool sh = (e == NEXP);
  int cnt = sh ? SEQ : counts[e];
  int off = sh ? 0 : offs[e];
  const float* w1p = sh ? sw1 : w1 + (size_t)e * wstride;
  const float* w3p = sh ? sw3 : w3 + (size_t)e * wstride;
  ushort* gout = sh ? sg : g;
  __shared__ ushort Ah[2][128][40];
  __shared__ int toks[128];
  int tid = threadIdx.x, wv = tid >> 6, lane = tid & 63;
  int arow = lane & 15, akb = (lane >> 4) << 3, kg = lane >> 4;
  int c0 = (blockIdx.x << 6) + wv * 16 + arow;
  if (tid < 128) {
    int r = mt + tid; if (r >= cnt) r = cnt - 1;
    toks[tid] = sh ? r : tok_list[off + r];
  }
  __syncthreads();
  int row0 = tid >> 2, q8 = (tid & 3) * 8;
  int row1 = row0 + 64;
  {
    uint4 a0 = *(const uint4*)(zb + (size_t)toks[row0] * D_MODEL + q8);
    uint4 a1v = *(const uint4*)(zb + (size_t)toks[row1] * D_MODEL + q8);
    *(uint4*)&Ah[0][row0][q8] = a0;
    *(uint4*)&Ah[0][row1][q8] = a1v;
  }
  f32x8r b1r = loadraw8(w1p + (size_t)akb * HEXP + c0, HEXP);
  f32x8r b3r = loadraw8(w3p + (size_t)akb * HEXP + c0, HEXP);
  __syncthreads();
  f32x4 a1[8], a3[8];
#pragma unroll
  for (int f = 0; f < 8; f++) { a1[f] = (f32x4){0.f,0.f,0.f,0.f}; a3[f] = (f32x4){0.f,0.f,0.f,0.f}; }
  int cur = 0;
  for (int k0 = 0; k0 < D_MODEL; k0 += 32) {
    int kp = (k0 + 32 < D_MODEL) ? k0 + 32 : 0;
    uint4 an0 = *(const uint4*)(zb + (size_t)toks[row0] * D_MODEL + kp + q8);
    uint4 an1 = *(const uint4*)(zb + (size_t)toks[row1] * D_MODEL + kp + q8);
    f32x8r b1n = loadraw8(w1p + (size_t)(kp + akb) * HEXP + c0, HEXP);
    f32x8r b3n = loadraw8(w3p + (size_t)(kp + akb) * HEXP + c0, HEXP);
    bf16x8 b1 = cvt_bf(b1r), b3 = cvt_bf(b3r);
#pragma unroll
    for (int f = 0; f < 8; f++) {
      bf16x8 ah = *(const bf16x8*)&Ah[cur][f*16 + arow][akb];
      a1[f] = mfma16(ah, b1, a1[f]);
      a3[f] = mfma16(ah, b3, a3[f]);
    }
    *(uint4*)&Ah[cur ^ 1][row0][q8] = an0;
    *(uint4*)&Ah[cur ^ 1][row1][q8] = an1;
    __syncthreads();
    b1r = b1n; b3r = b3n; cur ^= 1;
  }
#pragma unroll
  for (int f = 0; f < 8; f++)
#pragma unroll
    for (int ri = 0; ri < 4; ri++) {
      int r = mt + f*16 + kg*4 + ri;
      if (r < cnt) {
        float wt = sh ? 1.0f : wt_list[off + r];
        float h1 = a1[f][ri], h3 = a3[f][ri];
        float gv = h1 / (1.f + __expf(-h1)) * h3 * wt;
        gout[(size_t)(off + r) * HEXP + c0] = (ushort)rne1(gv);
      }
    }
}

// ---------------- MoE phase B (bf16, pipelined, shared fused): out += g @ w2 -------
// grid = (D_MODEL/128, MAXTILES).
__global__ __launch_bounds__(256) void moe_down4(const ushort* __restrict__ g,
    const ushort* __restrict__ sg, const float* __restrict__ w2, size_t wstride,
    const float* __restrict__ sw2, float* __restrict__ out,
    const int* __restrict__ tok_list, const int* __restrict__ counts,
    const int* __restrict__ offs, const int* __restrict__ tile2e,
    const int* __restrict__ tile2mt, const int* __restrict__ ntiles) {
  int gt = blockIdx.y;
  if (gt >= ntiles[0]) return;
  int e = tile2e[gt];
  int mt = tile2mt[gt] << 7;
  bool sh = (e == NEXP);
  int cnt = sh ? SEQ : counts[e];
  int off = sh ? 0 : offs[e];
  const float* w2p = sh ? sw2 : w2 + (size_t)e * wstride;
  const ushort* gin = sh ? sg : g;
  __shared__ ushort Ah[2][128][40];
  __shared__ int ridx[128];
  int tid = threadIdx.x, wv = tid >> 6, lane = tid & 63;
  int arow = lane & 15, akb = (lane >> 4) << 3, kg = lane >> 4;
  int c0 = (blockIdx.x << 7) + wv * 32 + arow;
  if (tid < 128) {
    int r = mt + tid; if (r >= cnt) r = cnt - 1;
    ridx[tid] = off + r;
  }
  __syncthreads();
  int row0 = tid >> 2, q8 = (tid & 3) * 8;
  int row1 = row0 + 64;
  {
    uint4 a0 = *(const uint4*)(gin + (size_t)ridx[row0] * HEXP + q8);
    uint4 a1v = *(const uint4*)(gin + (size_t)ridx[row1] * HEXP + q8);
    *(uint4*)&Ah[0][row0][q8] = a0;
    *(uint4*)&Ah[0][row1][q8] = a1v;
  }
  f32x8r b0r = loadraw8(w2p + (size_t)akb * D_MODEL + c0, D_MODEL);
  f32x8r b1r = loadraw8(w2p + (size_t)akb * D_MODEL + c0 + 16, D_MODEL);
  __syncthreads();
  f32x4 ac0[8], ac1[8];
#pragma unroll
  for (int f = 0; f < 8; f++) { ac0[f] = (f32x4){0.f,0.f,0.f,0.f}; ac1[f] = (f32x4){0.f,0.f,0.f,0.f}; }
  int cur = 0;
  for (int k0 = 0; k0 < HEXP; k0 += 32) {
    int kp = (k0 + 32 < HEXP) ? k0 + 32 : 0;
    uint4 an0 = *(const uint4*)(gin + (size_t)ridx[row0] * HEXP + kp + q8);
    uint4 an1 = *(const uint4*)(gin + (size_t)ridx[row1] * HEXP + kp + q8);
    f32x8r b0n = loadraw8(w2p + (size_t)(kp + akb) * D_MODEL + c0, D_MODEL);
    f32x8r b1n = loadraw8(w2p + (size_t)(kp + akb) * D_MODEL + c0 + 16, D_MODEL);
    bf16x8 b0 = cvt_bf(b0r), b1 = cvt_bf(b1r);
#pragma unroll
    for (int f = 0; f < 8; f++) {
      bf16x8 ah = *(const bf16x8*)&Ah[cur][f*16 + arow][akb];
      ac0[f] = mfma16(ah, b0, ac0[f]);
      ac1[f] = mfma16(ah, b1, ac1[f]);
    }
    *(uint4*)&Ah[cur ^ 1][row0][q8] = an0;
    *(uint4*)&Ah[cur ^ 1][row1][q8] = an1;
    __syncthreads();
    b0r = b0n; b1r = b1n; cur ^= 1;
  }
#pragma unroll
  for (int f = 0; f < 8; f++)
#pragma unroll
    for (int ri = 0; ri < 4; ri++) {
      int r = mt + f*16 + kg*4 + ri;
      if (r < cnt) {
        int tok = sh ? r : tok_list[off + r];
        float* op = out + (size_t)tok * D_MODEL + c0;
        atomicAdd(op, ac0[f][ri]);
        atomicAdd(op + 16, ac1[f][ri]);
      }
    }
}

// ---------------- host ----------------
extern "C" void kernel_launch(void* const* d_in, const int* in_sizes, int n_in,
                              void* d_out, int out_size, void* d_ws, size_t ws_size,
                              hipStream_t stream) {
  const float* x     = (const float*)d_in[0];
  const float* fcos  = (const float*)d_in[1];
  const float* fsin  = (const float*)d_in[2];
  const float* anw   = (const float*)d_in[3];
  const float* fnw   = (const float*)d_in[4];
  const float* wq    = (const float*)d_in[5];
  const float* wk    = (const float*)d_in[6];
  const float* wvv   = (const float*)d_in[7];
  const float* wo    = (const float*)d_in[8];
  const float* qnw   = (const float*)d_in[9];
  const float* knw   = (const float*)d_in[10];
  const float* gatew = (const float*)d_in[11];
  const float* w1e   = (const float*)d_in[12];
  const float* w3e   = (const float*)d_in[13];
  const float* w2e   = (const float*)d_in[14];
  const float* sw1   = (const float*)d_in[15];
  const float* sw3   = (const float*)d_in[16];
  const float* sw2   = (const float*)d_in[17];
  float* out = (float*)d_out;

  char* ws = (char*)d_ws;
  const size_t MB = 1ull << 20;
  float*  hx    = (float*)(ws);             // 4MB (attn-norm out, then attn out)
  float*  h     = (float*)(ws + 4*MB);      // 4MB residual after attention
  float*  z     = (float*)(ws + 8*MB);      // 4MB ffn-norm out (f32, for gate)
  float*  qbuf  = (float*)(ws + 12*MB);     // 4MB   (dead after attention)
  float*  kbuf  = (float*)(ws + 16*MB);     // 1MB
  float*  vbuf  = (float*)(ws + 17*MB);     // 1MB
  ushort* zb    = (ushort*)(ws + 12*MB);    // 2MB bf16 z (overlaps dead qbuf)
  ushort* gb    = (ushort*)(ws + 14*MB);    // 6.3MB bf16 expert activations
  ushort* s_gb  = (ushort*)(ws + 20*MB + 512*1024); // 1MB shared-expert act
  char*   misc  = ws + 22*MB;
  int*   sel      = (int*)(misc);
  float* topw     = (float*)(misc + 24576);
  int*   counts   = (int*)(misc + 49152);
  int*   offs     = (int*)(misc + 49408);
  int*   cursor   = (int*)(misc + 49664);
  int*   ntiles   = (int*)(misc + 50432);
  int*   tile2e   = (int*)(misc + 50688);
  int*   tile2mt  = (int*)(misc + 51200);
  int*   tok_list = (int*)(misc + 51712);
  float* wt_list  = (float*)(misc + 76288);

  // 1. attn rmsnorm
  rmsnorm_k<<<SEQ, 256, 0, stream>>>(x, anw, hx, nullptr);
  // 2. QKV projections (split-bf16 MFMA, pipelined)
  mfma_gemm_k<<<dim3(8, 64), 256, 0, stream>>>(hx, wq, qbuf, nullptr, nullptr, 1024, 1024);
  mfma_gemm_k<<<dim3(2, 64), 256, 0, stream>>>(hx, wk, kbuf, nullptr, nullptr, 256, 1024);
  mfma_gemm_k<<<dim3(2, 64), 256, 0, stream>>>(hx, wvv, vbuf, nullptr, nullptr, 256, 1024);
  // 3. q/k rmsnorm + rope
  qknorm_rope_k<<<dim3(SEQ, NHEADS + NKVH), 64, 0, stream>>>(qbuf, kbuf, qnw, knw, fcos, fsin);
  // 4. causal flash attention (bf16 MFMA) -> hx
  attn_mfma<<<dim3(SEQ / 64, NHEADS), 256, 0, stream>>>(qbuf, kbuf, vbuf, hx);
  // 5. o @ wo + x -> h (and d_out = h)
  mfma_gemm_k<<<dim3(8, 64), 256, 0, stream>>>(hx, wo, h, out, x, 1024, 1024);
  // 6. ffn rmsnorm -> z (f32) + zb (bf16)
  rmsnorm_k<<<SEQ, 256, 0, stream>>>(h, fnw, z, zb);
  // 7. gate + top-k + bucketing + flattened tile list (incl. shared tiles)
  hipMemsetAsync(counts, 0, 256, stream);
  gate_topk_k<<<SEQ, 64, 0, stream>>>(z, gatew, sel, topw, counts);
  scan_k<<<1, 64, 0, stream>>>(counts, offs, cursor, tile2e, tile2mt, ntiles);
  scatter_k<<<SEQ / 256, 256, 0, stream>>>(sel, topw, cursor, tok_list, wt_list);
  // 8. MoE phase A (experts + shared expert in one dispatch)
  moe_up4<<<dim3(HEXP / 64, MAXTILES), 256, 0, stream>>>(zb, w1e, w3e,
      (size_t)D_MODEL * HEXP, sw1, sw3, gb, s_gb, tok_list, wt_list,
      counts, offs, tile2e, tile2mt, ntiles);
  // 9. MoE phase B (experts + shared expert in one dispatch)
  moe_down4<<<dim3(D_MODEL / 128, MAXTILES), 256, 0, stream>>>(gb, s_gb, w2e,
      (size_t)HEXP * D_MODEL, sw2, out, tok_list, counts, offs,
      tile2e, tile2mt, ntiles);
  (void)in_sizes; (void)n_in; (void)out_size; (void)ws_size;
}

// Round 7
// 413.324 us; speedup vs baseline: 9.6818x; 1.0288x over previous
//
#include <hip/hip_runtime.h>
#include <hip/hip_bf16.h>
#include <math.h>

#define D_MODEL 1024
#define SEQ     1024
#define NHEADS  16
#define NKVH    4
#define HDIM    64
#define NEXP    64
#define TOPK    6
#define HEXP    512
#define EPS     1e-5f
#define MAXTILES 120   // 112 expert tiles max + 8 shared-expert tiles

typedef __attribute__((ext_vector_type(8))) short bf16x8;
typedef __attribute__((ext_vector_type(4))) float f32x4;

struct bfrag2 { bf16x8 hi, lo; };
struct f32x8r { float v[8]; };

__device__ __forceinline__ unsigned rne1(float a) {
  union { float f; unsigned u; } x; x.f = a;
  return (x.u + 0x7fffu + ((x.u >> 16) & 1u)) >> 16;
}
__device__ __forceinline__ float frombf(unsigned h) {
  union { float f; unsigned u; } x; x.u = h << 16; return x.f;
}
__device__ __forceinline__ void split_pack(float a, float b, unsigned& hi, unsigned& lo) {
  unsigned ha = rne1(a), hb = rne1(b);
  hi = ha | (hb << 16);
  lo = rne1(a - frombf(ha)) | (rne1(b - frombf(hb)) << 16);
}
__device__ __forceinline__ unsigned pk2bf(float a, float b) {
  return rne1(a) | (rne1(b) << 16);
}

__device__ __forceinline__ f32x4 mfma16(bf16x8 a, bf16x8 b, f32x4 c) {
  return __builtin_amdgcn_mfma_f32_16x16x32_bf16(a, b, c, 0, 0, 0);
}
__device__ __forceinline__ f32x4 mfma_sp(bf16x8 ah, bf16x8 al, const bfrag2& b, f32x4 c) {
  c = mfma16(ah, b.hi, c);
  c = mfma16(ah, b.lo, c);
  c = mfma16(al, b.hi, c);
  return c;
}

__device__ __forceinline__ f32x8r loadraw8(const float* __restrict__ p, int ld) {
  f32x8r r;
#pragma unroll
  for (int i = 0; i < 8; i++) r.v[i] = p[(size_t)ld * i];
  return r;
}
__device__ __forceinline__ bf16x8 cvt_bf(const f32x8r& f) {
  union { bf16x8 v; unsigned u[4]; } r;
  r.u[0] = pk2bf(f.v[0], f.v[1]); r.u[1] = pk2bf(f.v[2], f.v[3]);
  r.u[2] = pk2bf(f.v[4], f.v[5]); r.u[3] = pk2bf(f.v[6], f.v[7]);
  return r.v;
}
__device__ __forceinline__ bfrag2 cvt_bf2(const f32x8r& f) {
  union { bf16x8 v; unsigned u[4]; } H, L;
  split_pack(f.v[0], f.v[1], H.u[0], L.u[0]);
  split_pack(f.v[2], f.v[3], H.u[1], L.u[1]);
  split_pack(f.v[4], f.v[5], H.u[2], L.u[2]);
  split_pack(f.v[6], f.v[7], H.u[3], L.u[3]);
  bfrag2 r; r.hi = H.v; r.lo = L.v; return r;
}

// ---------------- rmsnorm over D=1024 (+ optional bf16 copy) ----------------
__global__ __launch_bounds__(256) void rmsnorm_k(const float* __restrict__ x,
    const float* __restrict__ w, float* __restrict__ out, ushort* __restrict__ outb) {
  int t = blockIdx.x;
  const float4* xr = (const float4*)(x + (size_t)t * D_MODEL);
  float4 v = xr[threadIdx.x];
  float ss = v.x*v.x + v.y*v.y + v.z*v.z + v.w*v.w;
  for (int off = 32; off; off >>= 1) ss += __shfl_xor(ss, off);
  __shared__ float red[4];
  if ((threadIdx.x & 63) == 0) red[threadIdx.x >> 6] = ss;
  __syncthreads();
  float tot = red[0] + red[1] + red[2] + red[3];
  float inv = rsqrtf(tot * (1.f / D_MODEL) + EPS);
  float4 wv = ((const float4*)w)[threadIdx.x];
  float4 o;
  o.x = v.x * inv * wv.x; o.y = v.y * inv * wv.y;
  o.z = v.z * inv * wv.z; o.w = v.w * inv * wv.w;
  ((float4*)(out + (size_t)t * D_MODEL))[threadIdx.x] = o;
  if (outb) {
    uint2 b;
    b.x = pk2bf(o.x, o.y); b.y = pk2bf(o.z, o.w);
    *(uint2*)(outb + (size_t)t * D_MODEL + threadIdx.x * 4) = b;
  }
}

// ---------------- dense split-bf16 MFMA GEMM, depth-2 pipeline ----------------
// BM=16, BN=128, 4 waves. grid = (N/128, M/16). K >= 64, K % 64 == 0.
__global__ __launch_bounds__(256) void mfma_gemm_k(const float* __restrict__ A,
    const float* __restrict__ B, float* __restrict__ C, float* __restrict__ C2,
    const float* __restrict__ resid, int N, int K) {
  __shared__ short Ah[2][16][40];
  __shared__ short Al[2][16][40];
  int bm = blockIdx.y << 4, bn = blockIdx.x << 7;
  int tid = threadIdx.x, wv = tid >> 6, lane = tid & 63;
  int m_ = tid >> 4, k_ = (tid & 15) << 1;
  int arow = lane & 15, akb = (lane >> 4) << 3;
  int c0 = bn + wv * 32 + arow;
  const float* ar = A + (size_t)(bm + m_) * K + k_;
  // prologue: A(0)->LDS[0]; aO=A(1); bE=B(0); bO=B(1)
  {
    float2 a0 = *(const float2*)ar;
    unsigned hi, lo; split_pack(a0.x, a0.y, hi, lo);
    *(unsigned*)&Ah[0][m_][k_] = hi;
    *(unsigned*)&Al[0][m_][k_] = lo;
  }
  float2 aO = *(const float2*)(ar + 32);
  float2 aE;
  f32x8r bE0 = loadraw8(B + (size_t)akb * N + c0, N);
  f32x8r bE1 = loadraw8(B + (size_t)akb * N + c0 + 16, N);
  f32x8r bO0 = loadraw8(B + (size_t)(32 + akb) * N + c0, N);
  f32x8r bO1 = loadraw8(B + (size_t)(32 + akb) * N + c0 + 16, N);
  __syncthreads();
  f32x4 acc0 = {0.f,0.f,0.f,0.f}, acc1 = {0.f,0.f,0.f,0.f};
  for (int k0 = 0; k0 < K; k0 += 64) {
    { // even step: consume bE (B(i)), MFMA LDS[0], write aO=A(i+1)->LDS[1], load i+2
      int kp = (k0 + 64 < K) ? k0 + 64 : 0;
      f32x8r n0 = loadraw8(B + (size_t)(kp + akb) * N + c0, N);
      f32x8r n1 = loadraw8(B + (size_t)(kp + akb) * N + c0 + 16, N);
      float2 an = *(const float2*)(ar + kp);
      bfrag2 f0 = cvt_bf2(bE0), f1 = cvt_bf2(bE1);
      bf16x8 ah = *(const bf16x8*)&Ah[0][arow][akb];
      bf16x8 al = *(const bf16x8*)&Al[0][arow][akb];
      acc0 = mfma_sp(ah, al, f0, acc0);
      acc1 = mfma_sp(ah, al, f1, acc1);
      unsigned hi, lo; split_pack(aO.x, aO.y, hi, lo);
      *(unsigned*)&Ah[1][m_][k_] = hi;
      *(unsigned*)&Al[1][m_][k_] = lo;
      __syncthreads();
      bE0 = n0; bE1 = n1; aE = an;
    }
    { // odd step: consume bO (B(i+1)), MFMA LDS[1], write aE=A(i+2)->LDS[0], load i+3
      int kp = (k0 + 96 < K) ? k0 + 96 : 0;
      f32x8r n0 = loadraw8(B + (size_t)(kp + akb) * N + c0, N);
      f32x8r n1 = loadraw8(B + (size_t)(kp + akb) * N + c0 + 16, N);
      float2 an = *(const float2*)(ar + kp);
      bfrag2 f0 = cvt_bf2(bO0), f1 = cvt_bf2(bO1);
      bf16x8 ah = *(const bf16x8*)&Ah[1][arow][akb];
      bf16x8 al = *(const bf16x8*)&Al[1][arow][akb];
      acc0 = mfma_sp(ah, al, f0, acc0);
      acc1 = mfma_sp(ah, al, f1, acc1);
      unsigned hi, lo; split_pack(aE.x, aE.y, hi, lo);
      *(unsigned*)&Ah[0][m_][k_] = hi;
      *(unsigned*)&Al[0][m_][k_] = lo;
      __syncthreads();
      bO0 = n0; bO1 = n1; aO = an;
    }
  }
  int r0 = (lane >> 4) << 2;
#pragma unroll
  for (int ri = 0; ri < 4; ri++) {
    int row = bm + r0 + ri;
    size_t o0 = (size_t)row * N + c0;
    float v0 = acc0[ri], v1 = acc1[ri];
    if (resid) { v0 += resid[o0]; v1 += resid[o0 + 16]; }
    C[o0] = v0; C[o0 + 16] = v1;
    if (C2) { C2[o0] = v0; C2[o0 + 16] = v1; }
  }
}

// ---------------- per-head rmsnorm + RoPE ----------------
__global__ __launch_bounds__(64) void qknorm_rope_k(float* __restrict__ qb,
    float* __restrict__ kb, const float* __restrict__ qw, const float* __restrict__ kw,
    const float* __restrict__ fcos, const float* __restrict__ fsin) {
  int t = blockIdx.x, hid = blockIdx.y, lane = threadIdx.x;
  float* p; const float* w;
  if (hid < NHEADS) { p = qb + (size_t)t * (NHEADS*HDIM) + hid * HDIM; w = qw; }
  else              { p = kb + (size_t)t * (NKVH*HDIM) + (hid - NHEADS) * HDIM; w = kw; }
  float v = p[lane];
  float ss = v * v;
  for (int off = 32; off; off >>= 1) ss += __shfl_xor(ss, off);
  float vn = v * rsqrtf(ss * (1.f / HDIM) + EPS) * w[lane];
  int pi = lane >> 1;
  float c = fcos[t * (HDIM/2) + pi], s = fsin[t * (HDIM/2) + pi];
  float other = __shfl_xor(vn, 1);
  float o = (lane & 1) ? (other * s + vn * c) : (vn * c - other * s);
  p[lane] = o;
}

// ---------------- causal flash attention, bf16 MFMA, GQA 4:1 ----------------
__global__ __launch_bounds__(256) void attn_mfma(const float* __restrict__ qb,
    const float* __restrict__ kb, const float* __restrict__ vb, float* __restrict__ ob) {
  int h = blockIdx.y;
  int qbase = blockIdx.x << 6;
  int kvh = h >> 2;
  int tid = threadIdx.x, wv = tid >> 6, lane = tid & 63;
  __shared__ short Kt[64][72];
  __shared__ short Vt[64][72];
  __shared__ short Pl[4][16][72];
  int arow = lane & 15;
  int akb = (lane >> 4) << 3;
  int kg = lane >> 4;
  int qrow_base = qbase + wv * 16;
  bf16x8 qf[2];
  {
    const float* qp = qb + (size_t)(qrow_base + arow) * (NHEADS*HDIM) + h * HDIM;
#pragma unroll
    for (int c = 0; c < 2; c++) {
      int d0 = akb + c * 32;
      union { bf16x8 v; unsigned u[4]; } r;
#pragma unroll
      for (int j = 0; j < 4; j++) r.u[j] = pk2bf(qp[d0 + 2*j], qp[d0 + 2*j + 1]);
      qf[c] = r.v;
    }
  }
  f32x4 accO[4];
  float m_[4], l_[4];
#pragma unroll
  for (int n = 0; n < 4; n++) { accO[n] = (f32x4){0.f,0.f,0.f,0.f}; m_[n] = -1e30f; l_[n] = 0.f; }
  int ntiles = (qbase >> 6) + 1;
  for (int ti = 0; ti < ntiles; ti++) {
    int ts = ti << 6;
#pragma unroll
    for (int i = 0; i < 16; i++) {
      int flat = tid + i * 256;
      int kk = flat >> 6, dd = flat & 63;
      size_t src = (size_t)(ts + kk) * (NKVH*HDIM) + kvh * HDIM + dd;
      Kt[kk][dd] = (short)rne1(kb[src]);
      Vt[dd][kk] = (short)rne1(vb[src]);
    }
    __syncthreads();
    f32x4 accS[4];
#pragma unroll
    for (int n = 0; n < 4; n++) accS[n] = (f32x4){0.f,0.f,0.f,0.f};
#pragma unroll
    for (int c = 0; c < 2; c++) {
#pragma unroll
      for (int n = 0; n < 4; n++) {
        bf16x8 bf = *(const bf16x8*)&Kt[n*16 + arow][c*32 + akb];
        accS[n] = mfma16(qf[c], bf, accS[n]);
      }
    }
#pragma unroll
    for (int ri = 0; ri < 4; ri++) {
      int qrow = qrow_base + kg*4 + ri;
      float mx = -1e30f;
#pragma unroll
      for (int n = 0; n < 4; n++) {
        int key = ts + n*16 + arow;
        float s = (key <= qrow) ? accS[n][ri] * 0.125f : -1e30f;
        accS[n][ri] = s;
        mx = fmaxf(mx, s);
      }
      for (int off = 1; off < 16; off <<= 1) mx = fmaxf(mx, __shfl_xor(mx, off));
      float mn = fmaxf(m_[ri], mx);
      float a = __expf(m_[ri] - mn);
      float sum = 0.f;
#pragma unroll
      for (int n = 0; n < 4; n++) {
        float p = __expf(accS[n][ri] - mn);
        accS[n][ri] = p;
        sum += p;
      }
      for (int off = 1; off < 16; off <<= 1) sum += __shfl_xor(sum, off);
      l_[ri] = l_[ri] * a + sum;
      m_[ri] = mn;
#pragma unroll
      for (int n = 0; n < 4; n++) accO[n][ri] *= a;
    }
#pragma unroll
    for (int ri = 0; ri < 4; ri++)
#pragma unroll
      for (int n = 0; n < 4; n++)
        Pl[wv][kg*4 + ri][n*16 + arow] = (short)rne1(accS[n][ri]);
#pragma unroll
    for (int c = 0; c < 2; c++) {
      bf16x8 pf = *(const bf16x8*)&Pl[wv][arow][c*32 + akb];
#pragma unroll
      for (int n = 0; n < 4; n++) {
        bf16x8 vf = *(const bf16x8*)&Vt[n*16 + arow][c*32 + akb];
        accO[n] = mfma16(pf, vf, accO[n]);
      }
    }
    __syncthreads();
  }
#pragma unroll
  for (int ri = 0; ri < 4; ri++) {
    int qrow = qrow_base + kg*4 + ri;
    float inv = 1.f / l_[ri];
#pragma unroll
    for (int n = 0; n < 4; n++)
      ob[(size_t)qrow * (NHEADS*HDIM) + h * HDIM + n*16 + arow] = accO[n][ri] * inv;
  }
}

// ---------------- gate: softmax -> top-6 (low-index tie-break) ----------------
__global__ __launch_bounds__(64) void gate_topk_k(const float* __restrict__ z,
    const float* __restrict__ gw, int* __restrict__ sel, float* __restrict__ topw,
    int* __restrict__ counts) {
  int t = blockIdx.x, lane = threadIdx.x;
  const float* zr = z + (size_t)t * D_MODEL;
  float acc = 0.f;
  for (int d = 0; d < D_MODEL; d += 4) {
    float4 zv = *(const float4*)(zr + d);
    acc += zv.x * gw[(size_t)(d + 0) * NEXP + lane];
    acc += zv.y * gw[(size_t)(d + 1) * NEXP + lane];
    acc += zv.z * gw[(size_t)(d + 2) * NEXP + lane];
    acc += zv.w * gw[(size_t)(d + 3) * NEXP + lane];
  }
  float m = acc;
  for (int off = 32; off; off >>= 1) m = fmaxf(m, __shfl_xor(m, off));
  float p = __expf(acc - m);
  float s = p;
  for (int off = 32; off; off >>= 1) s += __shfl_xor(s, off);
  p /= s;
  float rem = p, wsum = 0.f;
  float wvv[TOPK]; int wi[TOPK];
  for (int i = 0; i < TOPK; i++) {
    float v = rem; int idx = lane;
    for (int off = 32; off; off >>= 1) {
      float v2 = __shfl_xor(v, off);
      int i2 = __shfl_xor(idx, off);
      if (v2 > v || (v2 == v && i2 < idx)) { v = v2; idx = i2; }
    }
    wvv[i] = v; wi[i] = idx; wsum += v;
    if (lane == idx) rem = -1.f;
  }
  if (lane < TOPK) {
    sel[t * TOPK + lane] = wi[lane];
    topw[t * TOPK + lane] = wvv[lane] / wsum;
  }
  if (lane == 0)
    for (int i = 0; i < TOPK; i++) atomicAdd(&counts[wi[i]], 1);
}

// ---------------- scan + flattened (expert, mtile) work list (+shared tiles) -------
__global__ void scan_k(const int* __restrict__ counts, int* __restrict__ offs,
                       int* __restrict__ cursor, int* __restrict__ tile2e,
                       int* __restrict__ tile2mt, int* __restrict__ ntiles) {
  int lane = threadIdx.x;
  int c = counts[lane];
  int x = c;
  for (int off = 1; off < 64; off <<= 1) {
    int y = __shfl_up(x, off);
    if (lane >= off) x += y;
  }
  offs[lane] = x - c;
  cursor[lane] = x - c;
  int nt = (c + 127) >> 7;
  int y = nt;
  for (int off = 1; off < 64; off <<= 1) {
    int t2 = __shfl_up(y, off);
    if (lane >= off) y += t2;
  }
  int tbase = y - nt;
  for (int i = 0; i < nt; i++) { tile2e[tbase + i] = lane; tile2mt[tbase + i] = i; }
  if (lane == 63) {
    for (int i = 0; i < 8; i++) { tile2e[y + i] = NEXP; tile2mt[y + i] = i; }
    ntiles[0] = y + 8;
  }
}

__global__ void scatter_k(const int* __restrict__ sel, const float* __restrict__ topw,
    int* __restrict__ cursor, int* __restrict__ tok, float* __restrict__ wt) {
  int t = blockIdx.x * 256 + threadIdx.x;
  if (t >= SEQ) return;
  for (int i = 0; i < TOPK; i++) {
    int e = sel[t * TOPK + i];
    int pos = atomicAdd(&cursor[e], 1);
    tok[pos] = t;
    wt[pos] = topw[t * TOPK + i];
  }
}

// ---------------- MoE phase A (bf16, depth-2 pipeline, shared-expert fused) --------
// grid = (HEXP/64, MAXTILES); one 128-row x 64-col tile per block. K=1024.
__global__ __launch_bounds__(256) void moe_up5(const ushort* __restrict__ zb,
    const float* __restrict__ w1, const float* __restrict__ w3, size_t wstride,
    const float* __restrict__ sw1, const float* __restrict__ sw3,
    ushort* __restrict__ g, ushort* __restrict__ sg,
    const int* __restrict__ tok_list, const float* __restrict__ wt_list,
    const int* __restrict__ counts, const int* __restrict__ offs,
    const int* __restrict__ tile2e, const int* __restrict__ tile2mt,
    const int* __restrict__ ntiles) {
  int gt = blockIdx.y;
  if (gt >= ntiles[0]) return;
  int e = tile2e[gt];
  int mt = tile2mt[gt] << 7;
  bool sh = (e == NEXP);
  int cnt = sh ? SEQ : counts[e];
  int off = sh ? 0 : offs[e];
  const float* w1p = sh ? sw1 : w1 + (size_t)e * wstride;
  const float* w3p = sh ? sw3 : w3 + (size_t)e * wstride;
  ushort* gout = sh ? sg : g;
  __shared__ ushort Ah[2][128][40];
  __shared__ int toks[128];
  int tid = threadIdx.x, wv = tid >> 6, lane = tid & 63;
  int arow = lane & 15, akb = (lane >> 4) << 3, kg = lane >> 4;
  int c0 = (blockIdx.x << 6) + wv * 16 + arow;
  if (tid < 128) {
    int r = mt + tid; if (r >= cnt) r = cnt - 1;
    toks[tid] = sh ? r : tok_list[off + r];
  }
  __syncthreads();
  int row0 = tid >> 2, q8 = (tid & 3) * 8;
  int row1 = row0 + 64;
  const ushort* zr0 = zb + (size_t)toks[row0] * D_MODEL + q8;
  const ushort* zr1 = zb + (size_t)toks[row1] * D_MODEL + q8;
  // prologue: A(0)->LDS[0]; aO=A(1); bE=B(0); bO=B(1)
  {
    uint4 t0 = *(const uint4*)zr0;
    uint4 t1 = *(const uint4*)zr1;
    *(uint4*)&Ah[0][row0][q8] = t0;
    *(uint4*)&Ah[0][row1][q8] = t1;
  }
  uint4 aO0 = *(const uint4*)(zr0 + 32);
  uint4 aO1 = *(const uint4*)(zr1 + 32);
  uint4 aE0, aE1;
  f32x8r bE1 = loadraw8(w1p + (size_t)akb * HEXP + c0, HEXP);
  f32x8r bE3 = loadraw8(w3p + (size_t)akb * HEXP + c0, HEXP);
  f32x8r bO1 = loadraw8(w1p + (size_t)(32 + akb) * HEXP + c0, HEXP);
  f32x8r bO3 = loadraw8(w3p + (size_t)(32 + akb) * HEXP + c0, HEXP);
  __syncthreads();
  f32x4 a1[8], a3[8];
#pragma unroll
  for (int f = 0; f < 8; f++) { a1[f] = (f32x4){0.f,0.f,0.f,0.f}; a3[f] = (f32x4){0.f,0.f,0.f,0.f}; }
  for (int k0 = 0; k0 < D_MODEL; k0 += 64) {
    { // even step
      int kp = (k0 + 64 < D_MODEL) ? k0 + 64 : 0;
      f32x8r n1 = loadraw8(w1p + (size_t)(kp + akb) * HEXP + c0, HEXP);
      f32x8r n3 = loadraw8(w3p + (size_t)(kp + akb) * HEXP + c0, HEXP);
      uint4 an0 = *(const uint4*)(zr0 + kp);
      uint4 an1 = *(const uint4*)(zr1 + kp);
      bf16x8 b1 = cvt_bf(bE1), b3 = cvt_bf(bE3);
#pragma unroll
      for (int f = 0; f < 8; f++) {
        bf16x8 ah = *(const bf16x8*)&Ah[0][f*16 + arow][akb];
        a1[f] = mfma16(ah, b1, a1[f]);
        a3[f] = mfma16(ah, b3, a3[f]);
      }
      *(uint4*)&Ah[1][row0][q8] = aO0;
      *(uint4*)&Ah[1][row1][q8] = aO1;
      __syncthreads();
      bE1 = n1; bE3 = n3; aE0 = an0; aE1 = an1;
    }
    { // odd step
      int kp = (k0 + 96 < D_MODEL) ? k0 + 96 : 0;
      f32x8r n1 = loadraw8(w1p + (size_t)(kp + akb) * HEXP + c0, HEXP);
      f32x8r n3 = loadraw8(w3p + (size_t)(kp + akb) * HEXP + c0, HEXP);
      uint4 an0 = *(const uint4*)(zr0 + kp);
      uint4 an1 = *(const uint4*)(zr1 + kp);
      bf16x8 b1 = cvt_bf(bO1), b3 = cvt_bf(bO3);
#pragma unroll
      for (int f = 0; f < 8; f++) {
        bf16x8 ah = *(const bf16x8*)&Ah[1][f*16 + arow][akb];
        a1[f] = mfma16(ah, b1, a1[f]);
        a3[f] = mfma16(ah, b3, a3[f]);
      }
      *(uint4*)&Ah[0][row0][q8] = aE0;
      *(uint4*)&Ah[0][row1][q8] = aE1;
      __syncthreads();
      bO1 = n1; bO3 = n3; aO0 = an0; aO1 = an1;
    }
  }
#pragma unroll
  for (int f = 0; f < 8; f++)
#pragma unroll
    for (int ri = 0; ri < 4; ri++) {
      int r = mt + f*16 + kg*4 + ri;
      if (r < cnt) {
        float wt = sh ? 1.0f : wt_list[off + r];
        float h1 = a1[f][ri], h3 = a3[f][ri];
        float gv = h1 / (1.f + __expf(-h1)) * h3 * wt;
        gout[(size_t)(off + r) * HEXP + c0] = (ushort)rne1(gv);
      }
    }
}

// ---------------- MoE phase B (bf16, depth-2 pipeline, shared fused) ---------------
// grid = (D_MODEL/128, MAXTILES). K=512.
__global__ __launch_bounds__(256) void moe_down5(const ushort* __restrict__ g,
    const ushort* __restrict__ sg, const float* __restrict__ w2, size_t wstride,
    const float* __restrict__ sw2, float* __restrict__ out,
    const int* __restrict__ tok_list, const int* __restrict__ counts,
    const int* __restrict__ offs, const int* __restrict__ tile2e,
    const int* __restrict__ tile2mt, const int* __restrict__ ntiles) {
  int gt = blockIdx.y;
  if (gt >= ntiles[0]) return;
  int e = tile2e[gt];
  int mt = tile2mt[gt] << 7;
  bool sh = (e == NEXP);
  int cnt = sh ? SEQ : counts[e];
  int off = sh ? 0 : offs[e];
  const float* w2p = sh ? sw2 : w2 + (size_t)e * wstride;
  const ushort* gin = sh ? sg : g;
  __shared__ ushort Ah[2][128][40];
  int tid = threadIdx.x, wv = tid >> 6, lane = tid & 63;
  int arow = lane & 15, akb = (lane >> 4) << 3, kg = lane >> 4;
  int c0 = (blockIdx.x << 7) + wv * 32 + arow;
  int row0 = tid >> 2, q8 = (tid & 3) * 8;
  int row1 = row0 + 64;
  int rr0 = mt + row0; if (rr0 >= cnt) rr0 = cnt - 1;
  int rr1 = mt + row1; if (rr1 >= cnt) rr1 = cnt - 1;
  const ushort* gr0 = gin + (size_t)(off + rr0) * HEXP + q8;
  const ushort* gr1 = gin + (size_t)(off + rr1) * HEXP + q8;
  // prologue
  {
    uint4 t0 = *(const uint4*)gr0;
    uint4 t1 = *(const uint4*)gr1;
    *(uint4*)&Ah[0][row0][q8] = t0;
    *(uint4*)&Ah[0][row1][q8] = t1;
  }
  uint4 aO0 = *(const uint4*)(gr0 + 32);
  uint4 aO1 = *(const uint4*)(gr1 + 32);
  uint4 aE0, aE1;
  f32x8r bEa = loadraw8(w2p + (size_t)akb * D_MODEL + c0, D_MODEL);
  f32x8r bEb = loadraw8(w2p + (size_t)akb * D_MODEL + c0 + 16, D_MODEL);
  f32x8r bOa = loadraw8(w2p + (size_t)(32 + akb) * D_MODEL + c0, D_MODEL);
  f32x8r bOb = loadraw8(w2p + (size_t)(32 + akb) * D_MODEL + c0 + 16, D_MODEL);
  __syncthreads();
  f32x4 ac0[8], ac1[8];
#pragma unroll
  for (int f = 0; f < 8; f++) { ac0[f] = (f32x4){0.f,0.f,0.f,0.f}; ac1[f] = (f32x4){0.f,0.f,0.f,0.f}; }
  for (int k0 = 0; k0 < HEXP; k0 += 64) {
    { // even step
      int kp = (k0 + 64 < HEXP) ? k0 + 64 : 0;
      f32x8r na = loadraw8(w2p + (size_t)(kp + akb) * D_MODEL + c0, D_MODEL);
      f32x8r nb = loadraw8(w2p + (size_t)(kp + akb) * D_MODEL + c0 + 16, D_MODEL);
      uint4 an0 = *(const uint4*)(gr0 + kp);
      uint4 an1 = *(const uint4*)(gr1 + kp);
      bf16x8 b0 = cvt_bf(bEa), b1 = cvt_bf(bEb);
#pragma unroll
      for (int f = 0; f < 8; f++) {
        bf16x8 ah = *(const bf16x8*)&Ah[0][f*16 + arow][akb];
        ac0[f] = mfma16(ah, b0, ac0[f]);
        ac1[f] = mfma16(ah, b1, ac1[f]);
      }
      *(uint4*)&Ah[1][row0][q8] = aO0;
      *(uint4*)&Ah[1][row1][q8] = aO1;
      __syncthreads();
      bEa = na; bEb = nb; aE0 = an0; aE1 = an1;
    }
    { // odd step
      int kp = (k0 + 96 < HEXP) ? k0 + 96 : 0;
      f32x8r na = loadraw8(w2p + (size_t)(kp + akb) * D_MODEL + c0, D_MODEL);
      f32x8r nb = loadraw8(w2p + (size_t)(kp + akb) * D_MODEL + c0 + 16, D_MODEL);
      uint4 an0 = *(const uint4*)(gr0 + kp);
      uint4 an1 = *(const uint4*)(gr1 + kp);
      bf16x8 b0 = cvt_bf(bOa), b1 = cvt_bf(bOb);
#pragma unroll
      for (int f = 0; f < 8; f++) {
        bf16x8 ah = *(const bf16x8*)&Ah[1][f*16 + arow][akb];
        ac0[f] = mfma16(ah, b0, ac0[f]);
        ac1[f] = mfma16(ah, b1, ac1[f]);
      }
      *(uint4*)&Ah[0][row0][q8] = aE0;
      *(uint4*)&Ah[0][row1][q8] = aE1;
      __syncthreads();
      bOa = na; bOb = nb; aO0 = an0; aO1 = an1;
    }
  }
#pragma unroll
  for (int f = 0; f < 8; f++)
#pragma unroll
    for (int ri = 0; ri < 4; ri++) {
      int r = mt + f*16 + kg*4 + ri;
      if (r < cnt) {
        int tok = sh ? r : tok_list[off + r];
        float* op = out + (size_t)tok * D_MODEL + c0;
        atomicAdd(op, ac0[f][ri]);
        atomicAdd(op + 16, ac1[f][ri]);
      }
    }
}

// ---------------- host ----------------
extern "C" void kernel_launch(void* const* d_in, const int* in_sizes, int n_in,
                              void* d_out, int out_size, void* d_ws, size_t ws_size,
                              hipStream_t stream) {
  const float* x     = (const float*)d_in[0];
  const float* fcos  = (const float*)d_in[1];
  const float* fsin  = (const float*)d_in[2];
  const float* anw   = (const float*)d_in[3];
  const float* fnw   = (const float*)d_in[4];
  const float* wq    = (const float*)d_in[5];
  const float* wk    = (const float*)d_in[6];
  const float* wvv   = (const float*)d_in[7];
  const float* wo    = (const float*)d_in[8];
  const float* qnw   = (const float*)d_in[9];
  const float* knw   = (const float*)d_in[10];
  const float* gatew = (const float*)d_in[11];
  const float* w1e   = (const float*)d_in[12];
  const float* w3e   = (const float*)d_in[13];
  const float* w2e   = (const float*)d_in[14];
  const float* sw1   = (const float*)d_in[15];
  const float* sw3   = (const float*)d_in[16];
  const float* sw2   = (const float*)d_in[17];
  float* out = (float*)d_out;

  char* ws = (char*)d_ws;
  const size_t MB = 1ull << 20;
  float*  hx    = (float*)(ws);             // 4MB (attn-norm out, then attn out)
  float*  h     = (float*)(ws + 4*MB);      // 4MB residual after attention
  float*  z     = (float*)(ws + 8*MB);      // 4MB ffn-norm out (f32, for gate)
  float*  qbuf  = (float*)(ws + 12*MB);     // 4MB   (dead after attention)
  float*  kbuf  = (float*)(ws + 16*MB);     // 1MB
  float*  vbuf  = (float*)(ws + 17*MB);     // 1MB
  ushort* zb    = (ushort*)(ws + 12*MB);    // 2MB bf16 z (overlaps dead qbuf)
  ushort* gb    = (ushort*)(ws + 14*MB);    // 6.3MB bf16 expert activations
  ushort* s_gb  = (ushort*)(ws + 20*MB + 512*1024); // 1MB shared-expert act
  char*   misc  = ws + 22*MB;
  int*   sel      = (int*)(misc);
  float* topw     = (float*)(misc + 24576);
  int*   counts   = (int*)(misc + 49152);
  int*   offs     = (int*)(misc + 49408);
  int*   cursor   = (int*)(misc + 49664);
  int*   ntiles   = (int*)(misc + 50432);
  int*   tile2e   = (int*)(misc + 50688);
  int*   tile2mt  = (int*)(misc + 51200);
  int*   tok_list = (int*)(misc + 51712);
  float* wt_list  = (float*)(misc + 76288);

  // 1. attn rmsnorm
  rmsnorm_k<<<SEQ, 256, 0, stream>>>(x, anw, hx, nullptr);
  // 2. QKV projections (split-bf16 MFMA, depth-2)
  mfma_gemm_k<<<dim3(8, 64), 256, 0, stream>>>(hx, wq, qbuf, nullptr, nullptr, 1024, 1024);
  mfma_gemm_k<<<dim3(2, 64), 256, 0, stream>>>(hx, wk, kbuf, nullptr, nullptr, 256, 1024);
  mfma_gemm_k<<<dim3(2, 64), 256, 0, stream>>>(hx, wvv, vbuf, nullptr, nullptr, 256, 1024);
  // 3. q/k rmsnorm + rope
  qknorm_rope_k<<<dim3(SEQ, NHEADS + NKVH), 64, 0, stream>>>(qbuf, kbuf, qnw, knw, fcos, fsin);
  // 4. causal flash attention (bf16 MFMA) -> hx
  attn_mfma<<<dim3(SEQ / 64, NHEADS), 256, 0, stream>>>(qbuf, kbuf, vbuf, hx);
  // 5. o @ wo + x -> h (and d_out = h)
  mfma_gemm_k<<<dim3(8, 64), 256, 0, stream>>>(hx, wo, h, out, x, 1024, 1024);
  // 6. ffn rmsnorm -> z (f32) + zb (bf16)
  rmsnorm_k<<<SEQ, 256, 0, stream>>>(h, fnw, z, zb);
  // 7. gate + top-k + bucketing + flattened tile list (incl. shared tiles)
  hipMemsetAsync(counts, 0, 256, stream);
  gate_topk_k<<<SEQ, 64, 0, stream>>>(z, gatew, sel, topw, counts);
  scan_k<<<1, 64, 0, stream>>>(counts, offs, cursor, tile2e, tile2mt, ntiles);
  scatter_k<<<SEQ / 256, 256, 0, stream>>>(sel, topw, cursor, tok_list, wt_list);
  // 8. MoE phase A (experts + shared expert in one dispatch)
  moe_up5<<<dim3(HEXP / 64, MAXTILES), 256, 0, stream>>>(zb, w1e, w3e,
      (size_t)D_MODEL * HEXP, sw1, sw3, gb, s_gb, tok_list, wt_list,
      counts, offs, tile2e, tile2mt, ntiles);
  // 9. MoE phase B (experts + shared expert in one dispatch)
  moe_down5<<<dim3(D_MODEL / 128, MAXTILES), 256, 0, stream>>>(gb, s_gb, w2e,
      (size_t)HEXP * D_MODEL, sw2, out, tok_list, counts, offs,
      tile2e, tile2mt, ntiles);
  (void)in_sizes; (void)n_in; (void)out_size; (void)ws_size;
}

// Round 8
// 382.117 us; speedup vs baseline: 10.4725x; 1.0817x over previous
//
#include <hip/hip_runtime.h>
#include <hip/hip_bf16.h>
#include <math.h>

#define D_MODEL 1024
#define SEQ     1024
#define NHEADS  16
#define NKVH    4
#define HDIM    64
#define NEXP    64
#define TOPK    6
#define HEXP    512
#define EPS     1e-5f
#define MAXTILES 120   // 112 expert tiles max + 8 shared-expert tiles

typedef __attribute__((ext_vector_type(8))) short bf16x8;
typedef __attribute__((ext_vector_type(4))) float f32x4;

struct bfrag2 { bf16x8 hi, lo; };
struct f32x8r { float v[8]; };

__device__ __forceinline__ unsigned rne1(float a) {
  union { float f; unsigned u; } x; x.f = a;
  return (x.u + 0x7fffu + ((x.u >> 16) & 1u)) >> 16;
}
__device__ __forceinline__ float frombf(unsigned h) {
  union { float f; unsigned u; } x; x.u = h << 16; return x.f;
}
__device__ __forceinline__ void split_pack(float a, float b, unsigned& hi, unsigned& lo) {
  unsigned ha = rne1(a), hb = rne1(b);
  hi = ha | (hb << 16);
  lo = rne1(a - frombf(ha)) | (rne1(b - frombf(hb)) << 16);
}
__device__ __forceinline__ unsigned pk2bf(float a, float b) {
  return rne1(a) | (rne1(b) << 16);
}

__device__ __forceinline__ f32x4 mfma16(bf16x8 a, bf16x8 b, f32x4 c) {
  return __builtin_amdgcn_mfma_f32_16x16x32_bf16(a, b, c, 0, 0, 0);
}
__device__ __forceinline__ f32x4 mfma_sp(bf16x8 ah, bf16x8 al, const bfrag2& b, f32x4 c) {
  c = mfma16(ah, b.hi, c);
  c = mfma16(ah, b.lo, c);
  c = mfma16(al, b.hi, c);
  return c;
}

// barrier WITHOUT the compiler's vmcnt(0) drain: LDS ordered, global loads stay in flight
__device__ __forceinline__ void barrier_nv() {
  asm volatile("s_waitcnt lgkmcnt(0)" ::: "memory");
  __builtin_amdgcn_s_barrier();
}

__device__ __forceinline__ f32x8r loadraw8(const float* __restrict__ p, int ld) {
  f32x8r r;
#pragma unroll
  for (int i = 0; i < 8; i++) r.v[i] = p[(size_t)ld * i];
  return r;
}
__device__ __forceinline__ bfrag2 cvt_bf2(const f32x8r& f) {
  union { bf16x8 v; unsigned u[4]; } H, L;
  split_pack(f.v[0], f.v[1], H.u[0], L.u[0]);
  split_pack(f.v[2], f.v[3], H.u[1], L.u[1]);
  split_pack(f.v[4], f.v[5], H.u[2], L.u[2]);
  split_pack(f.v[6], f.v[7], H.u[3], L.u[3]);
  bfrag2 r; r.hi = H.v; r.lo = L.v; return r;
}

// B-fragment read from LDS [32][RL] ushort, conflict-free for RL=74/138
template<int RL>
__device__ __forceinline__ bf16x8 bfrag_lds(const ushort* __restrict__ B, int akb, int c) {
  union { bf16x8 v; ushort s[8]; } r;
#pragma unroll
  for (int j = 0; j < 8; j++) r.s[j] = B[(akb + j) * RL + c];
  return r.v;
}

// ---------------- rmsnorm over D=1024 (+ optional bf16 copy) ----------------
__global__ __launch_bounds__(256) void rmsnorm_k(const float* __restrict__ x,
    const float* __restrict__ w, float* __restrict__ out, ushort* __restrict__ outb) {
  int t = blockIdx.x;
  const float4* xr = (const float4*)(x + (size_t)t * D_MODEL);
  float4 v = xr[threadIdx.x];
  float ss = v.x*v.x + v.y*v.y + v.z*v.z + v.w*v.w;
  for (int off = 32; off; off >>= 1) ss += __shfl_xor(ss, off);
  __shared__ float red[4];
  if ((threadIdx.x & 63) == 0) red[threadIdx.x >> 6] = ss;
  __syncthreads();
  float tot = red[0] + red[1] + red[2] + red[3];
  float inv = rsqrtf(tot * (1.f / D_MODEL) + EPS);
  float4 wv = ((const float4*)w)[threadIdx.x];
  float4 o;
  o.x = v.x * inv * wv.x; o.y = v.y * inv * wv.y;
  o.z = v.z * inv * wv.z; o.w = v.w * inv * wv.w;
  ((float4*)(out + (size_t)t * D_MODEL))[threadIdx.x] = o;
  if (outb) {
    uint2 b;
    b.x = pk2bf(o.x, o.y); b.y = pk2bf(o.z, o.w);
    *(uint2*)(outb + (size_t)t * D_MODEL + threadIdx.x * 4) = b;
  }
}

// ---------------- dense split-bf16 MFMA GEMM, depth-2 pipeline, relaxed barrier ----
__global__ __launch_bounds__(256) void mfma_gemm_k(const float* __restrict__ A,
    const float* __restrict__ B, float* __restrict__ C, float* __restrict__ C2,
    const float* __restrict__ resid, int N, int K) {
  __shared__ short Ah[2][16][40];
  __shared__ short Al[2][16][40];
  int bm = blockIdx.y << 4, bn = blockIdx.x << 7;
  int tid = threadIdx.x, wv = tid >> 6, lane = tid & 63;
  int m_ = tid >> 4, k_ = (tid & 15) << 1;
  int arow = lane & 15, akb = (lane >> 4) << 3;
  int c0 = bn + wv * 32 + arow;
  const float* ar = A + (size_t)(bm + m_) * K + k_;
  {
    float2 a0 = *(const float2*)ar;
    unsigned hi, lo; split_pack(a0.x, a0.y, hi, lo);
    *(unsigned*)&Ah[0][m_][k_] = hi;
    *(unsigned*)&Al[0][m_][k_] = lo;
  }
  float2 aO = *(const float2*)(ar + 32);
  float2 aE;
  f32x8r bE0 = loadraw8(B + (size_t)akb * N + c0, N);
  f32x8r bE1 = loadraw8(B + (size_t)akb * N + c0 + 16, N);
  f32x8r bO0 = loadraw8(B + (size_t)(32 + akb) * N + c0, N);
  f32x8r bO1 = loadraw8(B + (size_t)(32 + akb) * N + c0 + 16, N);
  __syncthreads();
  f32x4 acc0 = {0.f,0.f,0.f,0.f}, acc1 = {0.f,0.f,0.f,0.f};
  for (int k0 = 0; k0 < K; k0 += 64) {
    { // even
      int kp = (k0 + 64 < K) ? k0 + 64 : 0;
      f32x8r n0 = loadraw8(B + (size_t)(kp + akb) * N + c0, N);
      f32x8r n1 = loadraw8(B + (size_t)(kp + akb) * N + c0 + 16, N);
      float2 an = *(const float2*)(ar + kp);
      bfrag2 f0 = cvt_bf2(bE0), f1 = cvt_bf2(bE1);
      bf16x8 ah = *(const bf16x8*)&Ah[0][arow][akb];
      bf16x8 al = *(const bf16x8*)&Al[0][arow][akb];
      acc0 = mfma_sp(ah, al, f0, acc0);
      acc1 = mfma_sp(ah, al, f1, acc1);
      unsigned hi, lo; split_pack(aO.x, aO.y, hi, lo);
      *(unsigned*)&Ah[1][m_][k_] = hi;
      *(unsigned*)&Al[1][m_][k_] = lo;
      barrier_nv();
      bE0 = n0; bE1 = n1; aE = an;
    }
    { // odd
      int kp = (k0 + 96 < K) ? k0 + 96 : 0;
      f32x8r n0 = loadraw8(B + (size_t)(kp + akb) * N + c0, N);
      f32x8r n1 = loadraw8(B + (size_t)(kp + akb) * N + c0 + 16, N);
      float2 an = *(const float2*)(ar + kp);
      bfrag2 f0 = cvt_bf2(bO0), f1 = cvt_bf2(bO1);
      bf16x8 ah = *(const bf16x8*)&Ah[1][arow][akb];
      bf16x8 al = *(const bf16x8*)&Al[1][arow][akb];
      acc0 = mfma_sp(ah, al, f0, acc0);
      acc1 = mfma_sp(ah, al, f1, acc1);
      unsigned hi, lo; split_pack(aE.x, aE.y, hi, lo);
      *(unsigned*)&Ah[0][m_][k_] = hi;
      *(unsigned*)&Al[0][m_][k_] = lo;
      barrier_nv();
      bO0 = n0; bO1 = n1; aO = an;
    }
  }
  int r0 = (lane >> 4) << 2;
#pragma unroll
  for (int ri = 0; ri < 4; ri++) {
    int row = bm + r0 + ri;
    size_t o0 = (size_t)row * N + c0;
    float v0 = acc0[ri], v1 = acc1[ri];
    if (resid) { v0 += resid[o0]; v1 += resid[o0 + 16]; }
    C[o0] = v0; C[o0 + 16] = v1;
    if (C2) { C2[o0] = v0; C2[o0 + 16] = v1; }
  }
}

// ---------------- per-head rmsnorm + RoPE ----------------
__global__ __launch_bounds__(64) void qknorm_rope_k(float* __restrict__ qb,
    float* __restrict__ kb, const float* __restrict__ qw, const float* __restrict__ kw,
    const float* __restrict__ fcos, const float* __restrict__ fsin) {
  int t = blockIdx.x, hid = blockIdx.y, lane = threadIdx.x;
  float* p; const float* w;
  if (hid < NHEADS) { p = qb + (size_t)t * (NHEADS*HDIM) + hid * HDIM; w = qw; }
  else              { p = kb + (size_t)t * (NKVH*HDIM) + (hid - NHEADS) * HDIM; w = kw; }
  float v = p[lane];
  float ss = v * v;
  for (int off = 32; off; off >>= 1) ss += __shfl_xor(ss, off);
  float vn = v * rsqrtf(ss * (1.f / HDIM) + EPS) * w[lane];
  int pi = lane >> 1;
  float c = fcos[t * (HDIM/2) + pi], s = fsin[t * (HDIM/2) + pi];
  float other = __shfl_xor(vn, 1);
  float o = (lane & 1) ? (other * s + vn * c) : (vn * c - other * s);
  p[lane] = o;
}

// ---------------- causal flash attention, bf16 MFMA, GQA 4:1 ----------------
__global__ __launch_bounds__(256) void attn_mfma(const float* __restrict__ qb,
    const float* __restrict__ kb, const float* __restrict__ vb, float* __restrict__ ob) {
  int h = blockIdx.y;
  int qbase = blockIdx.x << 6;
  int kvh = h >> 2;
  int tid = threadIdx.x, wv = tid >> 6, lane = tid & 63;
  __shared__ short Kt[64][72];
  __shared__ short Vt[64][72];
  __shared__ short Pl[4][16][72];
  int arow = lane & 15;
  int akb = (lane >> 4) << 3;
  int kg = lane >> 4;
  int qrow_base = qbase + wv * 16;
  bf16x8 qf[2];
  {
    const float* qp = qb + (size_t)(qrow_base + arow) * (NHEADS*HDIM) + h * HDIM;
#pragma unroll
    for (int c = 0; c < 2; c++) {
      int d0 = akb + c * 32;
      union { bf16x8 v; unsigned u[4]; } r;
#pragma unroll
      for (int j = 0; j < 4; j++) r.u[j] = pk2bf(qp[d0 + 2*j], qp[d0 + 2*j + 1]);
      qf[c] = r.v;
    }
  }
  f32x4 accO[4];
  float m_[4], l_[4];
#pragma unroll
  for (int n = 0; n < 4; n++) { accO[n] = (f32x4){0.f,0.f,0.f,0.f}; m_[n] = -1e30f; l_[n] = 0.f; }
  int ntiles = (qbase >> 6) + 1;
  for (int ti = 0; ti < ntiles; ti++) {
    int ts = ti << 6;
#pragma unroll
    for (int i = 0; i < 16; i++) {
      int flat = tid + i * 256;
      int kk = flat >> 6, dd = flat & 63;
      size_t src = (size_t)(ts + kk) * (NKVH*HDIM) + kvh * HDIM + dd;
      Kt[kk][dd] = (short)rne1(kb[src]);
      Vt[dd][kk] = (short)rne1(vb[src]);
    }
    __syncthreads();
    f32x4 accS[4];
#pragma unroll
    for (int n = 0; n < 4; n++) accS[n] = (f32x4){0.f,0.f,0.f,0.f};
#pragma unroll
    for (int c = 0; c < 2; c++) {
#pragma unroll
      for (int n = 0; n < 4; n++) {
        bf16x8 bf = *(const bf16x8*)&Kt[n*16 + arow][c*32 + akb];
        accS[n] = mfma16(qf[c], bf, accS[n]);
      }
    }
#pragma unroll
    for (int ri = 0; ri < 4; ri++) {
      int qrow = qrow_base + kg*4 + ri;
      float mx = -1e30f;
#pragma unroll
      for (int n = 0; n < 4; n++) {
        int key = ts + n*16 + arow;
        float s = (key <= qrow) ? accS[n][ri] * 0.125f : -1e30f;
        accS[n][ri] = s;
        mx = fmaxf(mx, s);
      }
      for (int off = 1; off < 16; off <<= 1) mx = fmaxf(mx, __shfl_xor(mx, off));
      float mn = fmaxf(m_[ri], mx);
      float a = __expf(m_[ri] - mn);
      float sum = 0.f;
#pragma unroll
      for (int n = 0; n < 4; n++) {
        float p = __expf(accS[n][ri] - mn);
        accS[n][ri] = p;
        sum += p;
      }
      for (int off = 1; off < 16; off <<= 1) sum += __shfl_xor(sum, off);
      l_[ri] = l_[ri] * a + sum;
      m_[ri] = mn;
#pragma unroll
      for (int n = 0; n < 4; n++) accO[n][ri] *= a;
    }
#pragma unroll
    for (int ri = 0; ri < 4; ri++)
#pragma unroll
      for (int n = 0; n < 4; n++)
        Pl[wv][kg*4 + ri][n*16 + arow] = (short)rne1(accS[n][ri]);
#pragma unroll
    for (int c = 0; c < 2; c++) {
      bf16x8 pf = *(const bf16x8*)&Pl[wv][arow][c*32 + akb];
#pragma unroll
      for (int n = 0; n < 4; n++) {
        bf16x8 vf = *(const bf16x8*)&Vt[n*16 + arow][c*32 + akb];
        accO[n] = mfma16(pf, vf, accO[n]);
      }
    }
    __syncthreads();
  }
#pragma unroll
  for (int ri = 0; ri < 4; ri++) {
    int qrow = qrow_base + kg*4 + ri;
    float inv = 1.f / l_[ri];
#pragma unroll
    for (int n = 0; n < 4; n++)
      ob[(size_t)qrow * (NHEADS*HDIM) + h * HDIM + n*16 + arow] = accO[n][ri] * inv;
  }
}

// ---------------- gate: softmax -> top-6 (low-index tie-break) ----------------
__global__ __launch_bounds__(64) void gate_topk_k(const float* __restrict__ z,
    const float* __restrict__ gw, int* __restrict__ sel, float* __restrict__ topw,
    int* __restrict__ counts) {
  int t = blockIdx.x, lane = threadIdx.x;
  const float* zr = z + (size_t)t * D_MODEL;
  float acc = 0.f;
  for (int d = 0; d < D_MODEL; d += 4) {
    float4 zv = *(const float4*)(zr + d);
    acc += zv.x * gw[(size_t)(d + 0) * NEXP + lane];
    acc += zv.y * gw[(size_t)(d + 1) * NEXP + lane];
    acc += zv.z * gw[(size_t)(d + 2) * NEXP + lane];
    acc += zv.w * gw[(size_t)(d + 3) * NEXP + lane];
  }
  float m = acc;
  for (int off = 32; off; off >>= 1) m = fmaxf(m, __shfl_xor(m, off));
  float p = __expf(acc - m);
  float s = p;
  for (int off = 32; off; off >>= 1) s += __shfl_xor(s, off);
  p /= s;
  float rem = p, wsum = 0.f;
  float wvv[TOPK]; int wi[TOPK];
  for (int i = 0; i < TOPK; i++) {
    float v = rem; int idx = lane;
    for (int off = 32; off; off >>= 1) {
      float v2 = __shfl_xor(v, off);
      int i2 = __shfl_xor(idx, off);
      if (v2 > v || (v2 == v && i2 < idx)) { v = v2; idx = i2; }
    }
    wvv[i] = v; wi[i] = idx; wsum += v;
    if (lane == idx) rem = -1.f;
  }
  if (lane < TOPK) {
    sel[t * TOPK + lane] = wi[lane];
    topw[t * TOPK + lane] = wvv[lane] / wsum;
  }
  if (lane == 0)
    for (int i = 0; i < TOPK; i++) atomicAdd(&counts[wi[i]], 1);
}

// ---------------- scan + flattened (expert, mtile) work list (+shared tiles) -------
__global__ void scan_k(const int* __restrict__ counts, int* __restrict__ offs,
                       int* __restrict__ cursor, int* __restrict__ tile2e,
                       int* __restrict__ tile2mt, int* __restrict__ ntiles) {
  int lane = threadIdx.x;
  int c = counts[lane];
  int x = c;
  for (int off = 1; off < 64; off <<= 1) {
    int y = __shfl_up(x, off);
    if (lane >= off) x += y;
  }
  offs[lane] = x - c;
  cursor[lane] = x - c;
  int nt = (c + 127) >> 7;
  int y = nt;
  for (int off = 1; off < 64; off <<= 1) {
    int t2 = __shfl_up(y, off);
    if (lane >= off) y += t2;
  }
  int tbase = y - nt;
  for (int i = 0; i < nt; i++) { tile2e[tbase + i] = lane; tile2mt[tbase + i] = i; }
  if (lane == 63) {
    for (int i = 0; i < 8; i++) { tile2e[y + i] = NEXP; tile2mt[y + i] = i; }
    ntiles[0] = y + 8;
  }
}

__global__ void scatter_k(const int* __restrict__ sel, const float* __restrict__ topw,
    int* __restrict__ cursor, int* __restrict__ tok, float* __restrict__ wt) {
  int t = blockIdx.x * 256 + threadIdx.x;
  if (t >= SEQ) return;
  for (int i = 0; i < TOPK; i++) {
    int e = sel[t * TOPK + i];
    int pos = atomicAdd(&cursor[e], 1);
    tok[pos] = t;
    wt[pos] = topw[t * TOPK + i];
  }
}

// ---------------- MoE phase A: coalesced-LDS B, relaxed barrier, dbuf --------------
// grid = (HEXP/64, MAXTILES); one 128-row x 64-col tile per block. K=1024.
__global__ __launch_bounds__(256) void moe_up6(const ushort* __restrict__ zb,
    const float* __restrict__ w1, const float* __restrict__ w3, size_t wstride,
    const float* __restrict__ sw1, const float* __restrict__ sw3,
    ushort* __restrict__ g, ushort* __restrict__ sg,
    const int* __restrict__ tok_list, const float* __restrict__ wt_list,
    const int* __restrict__ counts, const int* __restrict__ offs,
    const int* __restrict__ tile2e, const int* __restrict__ tile2mt,
    const int* __restrict__ ntiles) {
  int gt = blockIdx.y;
  if (gt >= ntiles[0]) return;
  int e = tile2e[gt];
  int mt = tile2mt[gt] << 7;
  bool sh = (e == NEXP);
  int cnt = sh ? SEQ : counts[e];
  int off = sh ? 0 : offs[e];
  const float* w1p = (sh ? sw1 : w1 + (size_t)e * wstride) + (blockIdx.x << 6);
  const float* w3p = (sh ? sw3 : w3 + (size_t)e * wstride) + (blockIdx.x << 6);
  ushort* gout = sh ? sg : g;
  __shared__ ushort Ah[2][128][40];
  __shared__ ushort Bs[2][2][32][74];
  __shared__ int toks[128];
  int tid = threadIdx.x, wv = tid >> 6, lane = tid & 63;
  int arow = lane & 15, akb = (lane >> 4) << 3, kg = lane >> 4;
  int c0l = wv * 16 + arow;
  int c0 = (blockIdx.x << 6) + c0l;
  if (tid < 128) {
    int r = mt + tid; if (r >= cnt) r = cnt - 1;
    toks[tid] = sh ? r : tok_list[off + r];
  }
  __syncthreads();
  int row0 = tid >> 2, q8 = (tid & 3) << 3, row1 = row0 + 64;
  const ushort* zr0 = zb + (size_t)toks[row0] * D_MODEL + q8;
  const ushort* zr1 = zb + (size_t)toks[row1] * D_MODEL + q8;
  int kB = tid >> 4, cB = (tid & 15) << 2;
  const float* w1q = w1p + (size_t)kB * HEXP + cB;
  const float* w3q = w3p + (size_t)kB * HEXP + cB;
  // prologue: raw(0)
  uint4  ra0 = *(const uint4*)zr0;
  uint4  ra1 = *(const uint4*)zr1;
  float4 rb1a = *(const float4*)w1q;
  float4 rb1b = *(const float4*)(w1q + 16 * HEXP);
  float4 rb3a = *(const float4*)w3q;
  float4 rb3b = *(const float4*)(w3q + 16 * HEXP);
  f32x4 a1[8], a3[8];
#pragma unroll
  for (int f = 0; f < 8; f++) { a1[f] = (f32x4){0.f,0.f,0.f,0.f}; a3[f] = (f32x4){0.f,0.f,0.f,0.f}; }
  int cur = 0;
  for (int k0 = 0; k0 < D_MODEL; k0 += 32) {
    int kp = (k0 + 32 < D_MODEL) ? k0 + 32 : 0;
    // issue next-step loads (stay in flight across the relaxed barrier)
    uint4  na0 = *(const uint4*)(zr0 + kp);
    uint4  na1 = *(const uint4*)(zr1 + kp);
    const float* w1n = w1q + (size_t)kp * HEXP;
    const float* w3n = w3q + (size_t)kp * HEXP;
    float4 nb1a = *(const float4*)w1n;
    float4 nb1b = *(const float4*)(w1n + 16 * HEXP);
    float4 nb3a = *(const float4*)w3n;
    float4 nb3b = *(const float4*)(w3n + 16 * HEXP);
    // stage current step to LDS
    *(uint4*)&Ah[cur][row0][q8] = ra0;
    *(uint4*)&Ah[cur][row1][q8] = ra1;
    {
      unsigned* p = (unsigned*)&Bs[cur][0][kB][cB];
      p[0] = pk2bf(rb1a.x, rb1a.y); p[1] = pk2bf(rb1a.z, rb1a.w);
      unsigned* p2 = (unsigned*)&Bs[cur][0][kB + 16][cB];
      p2[0] = pk2bf(rb1b.x, rb1b.y); p2[1] = pk2bf(rb1b.z, rb1b.w);
      unsigned* p3 = (unsigned*)&Bs[cur][1][kB][cB];
      p3[0] = pk2bf(rb3a.x, rb3a.y); p3[1] = pk2bf(rb3a.z, rb3a.w);
      unsigned* p4 = (unsigned*)&Bs[cur][1][kB + 16][cB];
      p4[0] = pk2bf(rb3b.x, rb3b.y); p4[1] = pk2bf(rb3b.z, rb3b.w);
    }
    barrier_nv();
    bf16x8 f1 = bfrag_lds<74>(&Bs[cur][0][0][0], akb, c0l);
    bf16x8 f3 = bfrag_lds<74>(&Bs[cur][1][0][0], akb, c0l);
#pragma unroll
    for (int f = 0; f < 8; f++) {
      bf16x8 ah = *(const bf16x8*)&Ah[cur][f*16 + arow][akb];
      a1[f] = mfma16(ah, f1, a1[f]);
      a3[f] = mfma16(ah, f3, a3[f]);
    }
    ra0 = na0; ra1 = na1;
    rb1a = nb1a; rb1b = nb1b; rb3a = nb3a; rb3b = nb3b;
    cur ^= 1;
  }
#pragma unroll
  for (int f = 0; f < 8; f++)
#pragma unroll
    for (int ri = 0; ri < 4; ri++) {
      int r = mt + f*16 + kg*4 + ri;
      if (r < cnt) {
        float wt = sh ? 1.0f : wt_list[off + r];
        float h1 = a1[f][ri], h3 = a3[f][ri];
        float gv = h1 / (1.f + __expf(-h1)) * h3 * wt;
        gout[(size_t)(off + r) * HEXP + c0] = (ushort)rne1(gv);
      }
    }
}

// ---------------- MoE phase B: coalesced-LDS B, relaxed barrier, dbuf --------------
// grid = (D_MODEL/128, MAXTILES). K=512.
__global__ __launch_bounds__(256) void moe_down6(const ushort* __restrict__ g,
    const ushort* __restrict__ sg, const float* __restrict__ w2, size_t wstride,
    const float* __restrict__ sw2, float* __restrict__ out,
    const int* __restrict__ tok_list, const int* __restrict__ counts,
    const int* __restrict__ offs, const int* __restrict__ tile2e,
    const int* __restrict__ tile2mt, const int* __restrict__ ntiles) {
  int gt = blockIdx.y;
  if (gt >= ntiles[0]) return;
  int e = tile2e[gt];
  int mt = tile2mt[gt] << 7;
  bool sh = (e == NEXP);
  int cnt = sh ? SEQ : counts[e];
  int off = sh ? 0 : offs[e];
  const float* w2p = (sh ? sw2 : w2 + (size_t)e * wstride) + (blockIdx.x << 7);
  const ushort* gin = sh ? sg : g;
  __shared__ ushort Ah[2][128][40];
  __shared__ ushort Bs[2][32][138];
  int tid = threadIdx.x, wv = tid >> 6, lane = tid & 63;
  int arow = lane & 15, akb = (lane >> 4) << 3, kg = lane >> 4;
  int c0l = wv * 32 + arow;
  int c0 = (blockIdx.x << 7) + c0l;
  int row0 = tid >> 2, q8 = (tid & 3) << 3, row1 = row0 + 64;
  int rr0 = mt + row0; if (rr0 >= cnt) rr0 = cnt - 1;
  int rr1 = mt + row1; if (rr1 >= cnt) rr1 = cnt - 1;
  const ushort* gr0 = gin + (size_t)(off + rr0) * HEXP + q8;
  const ushort* gr1 = gin + (size_t)(off + rr1) * HEXP + q8;
  int kB = tid >> 3, cB = (tid & 7) << 4;
  const float* w2q = w2p + (size_t)kB * D_MODEL + cB;
  // prologue
  uint4  ra0 = *(const uint4*)gr0;
  uint4  ra1 = *(const uint4*)gr1;
  float4 rb0 = *(const float4*)(w2q);
  float4 rb1 = *(const float4*)(w2q + 4);
  float4 rb2 = *(const float4*)(w2q + 8);
  float4 rb3 = *(const float4*)(w2q + 12);
  f32x4 ac0[8], ac1[8];
#pragma unroll
  for (int f = 0; f < 8; f++) { ac0[f] = (f32x4){0.f,0.f,0.f,0.f}; ac1[f] = (f32x4){0.f,0.f,0.f,0.f}; }
  int cur = 0;
  for (int k0 = 0; k0 < HEXP; k0 += 32) {
    int kp = (k0 + 32 < HEXP) ? k0 + 32 : 0;
    uint4  na0 = *(const uint4*)(gr0 + kp);
    uint4  na1 = *(const uint4*)(gr1 + kp);
    const float* wn = w2q + (size_t)kp * D_MODEL;
    float4 nb0 = *(const float4*)(wn);
    float4 nb1 = *(const float4*)(wn + 4);
    float4 nb2 = *(const float4*)(wn + 8);
    float4 nb3 = *(const float4*)(wn + 12);
    *(uint4*)&Ah[cur][row0][q8] = ra0;
    *(uint4*)&Ah[cur][row1][q8] = ra1;
    {
      unsigned* p = (unsigned*)&Bs[cur][kB][cB];
      p[0] = pk2bf(rb0.x, rb0.y); p[1] = pk2bf(rb0.z, rb0.w);
      p[2] = pk2bf(rb1.x, rb1.y); p[3] = pk2bf(rb1.z, rb1.w);
      p[4] = pk2bf(rb2.x, rb2.y); p[5] = pk2bf(rb2.z, rb2.w);
      p[6] = pk2bf(rb3.x, rb3.y); p[7] = pk2bf(rb3.z, rb3.w);
    }
    barrier_nv();
    bf16x8 f0 = bfrag_lds<138>(&Bs[cur][0][0], akb, c0l);
    bf16x8 f1 = bfrag_lds<138>(&Bs[cur][0][0], akb, c0l + 16);
#pragma unroll
    for (int f = 0; f < 8; f++) {
      bf16x8 ah = *(const bf16x8*)&Ah[cur][f*16 + arow][akb];
      ac0[f] = mfma16(ah, f0, ac0[f]);
      ac1[f] = mfma16(ah, f1, ac1[f]);
    }
    ra0 = na0; ra1 = na1;
    rb0 = nb0; rb1 = nb1; rb2 = nb2; rb3 = nb3;
    cur ^= 1;
  }
#pragma unroll
  for (int f = 0; f < 8; f++)
#pragma unroll
    for (int ri = 0; ri < 4; ri++) {
      int r = mt + f*16 + kg*4 + ri;
      if (r < cnt) {
        int tok = sh ? r : tok_list[off + r];
        float* op = out + (size_t)tok * D_MODEL + c0;
        atomicAdd(op, ac0[f][ri]);
        atomicAdd(op + 16, ac1[f][ri]);
      }
    }
}

// ---------------- host ----------------
extern "C" void kernel_launch(void* const* d_in, const int* in_sizes, int n_in,
                              void* d_out, int out_size, void* d_ws, size_t ws_size,
                              hipStream_t stream) {
  const float* x     = (const float*)d_in[0];
  const float* fcos  = (const float*)d_in[1];
  const float* fsin  = (const float*)d_in[2];
  const float* anw   = (const float*)d_in[3];
  const float* fnw   = (const float*)d_in[4];
  const float* wq    = (const float*)d_in[5];
  const float* wk    = (const float*)d_in[6];
  const float* wvv   = (const float*)d_in[7];
  const float* wo    = (const float*)d_in[8];
  const float* qnw   = (const float*)d_in[9];
  const float* knw   = (const float*)d_in[10];
  const float* gatew = (const float*)d_in[11];
  const float* w1e   = (const float*)d_in[12];
  const float* w3e   = (const float*)d_in[13];
  const float* w2e   = (const float*)d_in[14];
  const float* sw1   = (const float*)d_in[15];
  const float* sw3   = (const float*)d_in[16];
  const float* sw2   = (const float*)d_in[17];
  float* out = (float*)d_out;

  char* ws = (char*)d_ws;
  const size_t MB = 1ull << 20;
  float*  hx    = (float*)(ws);             // 4MB (attn-norm out, then attn out)
  float*  h     = (float*)(ws + 4*MB);      // 4MB residual after attention
  float*  z     = (float*)(ws + 8*MB);      // 4MB ffn-norm out (f32, for gate)
  float*  qbuf  = (float*)(ws + 12*MB);     // 4MB   (dead after attention)
  float*  kbuf  = (float*)(ws + 16*MB);     // 1MB
  float*  vbuf  = (float*)(ws + 17*MB);     // 1MB
  ushort* zb    = (ushort*)(ws + 12*MB);    // 2MB bf16 z (overlaps dead qbuf)
  ushort* gb    = (ushort*)(ws + 14*MB);    // 6.3MB bf16 expert activations
  ushort* s_gb  = (ushort*)(ws + 20*MB + 512*1024); // 1MB shared-expert act
  char*   misc  = ws + 22*MB;
  int*   sel      = (int*)(misc);
  float* topw     = (float*)(misc + 24576);
  int*   counts   = (int*)(misc + 49152);
  int*   offs     = (int*)(misc + 49408);
  int*   cursor   = (int*)(misc + 49664);
  int*   ntiles   = (int*)(misc + 50432);
  int*   tile2e   = (int*)(misc + 50688);
  int*   tile2mt  = (int*)(misc + 51200);
  int*   tok_list = (int*)(misc + 51712);
  float* wt_list  = (float*)(misc + 76288);

  // 1. attn rmsnorm
  rmsnorm_k<<<SEQ, 256, 0, stream>>>(x, anw, hx, nullptr);
  // 2. QKV projections (split-bf16 MFMA, relaxed-barrier pipeline)
  mfma_gemm_k<<<dim3(8, 64), 256, 0, stream>>>(hx, wq, qbuf, nullptr, nullptr, 1024, 1024);
  mfma_gemm_k<<<dim3(2, 64), 256, 0, stream>>>(hx, wk, kbuf, nullptr, nullptr, 256, 1024);
  mfma_gemm_k<<<dim3(2, 64), 256, 0, stream>>>(hx, wvv, vbuf, nullptr, nullptr, 256, 1024);
  // 3. q/k rmsnorm + rope
  qknorm_rope_k<<<dim3(SEQ, NHEADS + NKVH), 64, 0, stream>>>(qbuf, kbuf, qnw, knw, fcos, fsin);
  // 4. causal flash attention (bf16 MFMA) -> hx
  attn_mfma<<<dim3(SEQ / 64, NHEADS), 256, 0, stream>>>(qbuf, kbuf, vbuf, hx);
  // 5. o @ wo + x -> h (and d_out = h)
  mfma_gemm_k<<<dim3(8, 64), 256, 0, stream>>>(hx, wo, h, out, x, 1024, 1024);
  // 6. ffn rmsnorm -> z (f32) + zb (bf16)
  rmsnorm_k<<<SEQ, 256, 0, stream>>>(h, fnw, z, zb);
  // 7. gate + top-k + bucketing + flattened tile list (incl. shared tiles)
  hipMemsetAsync(counts, 0, 256, stream);
  gate_topk_k<<<SEQ, 64, 0, stream>>>(z, gatew, sel, topw, counts);
  scan_k<<<1, 64, 0, stream>>>(counts, offs, cursor, tile2e, tile2mt, ntiles);
  scatter_k<<<SEQ / 256, 256, 0, stream>>>(sel, topw, cursor, tok_list, wt_list);
  // 8. MoE phase A (experts + shared expert in one dispatch)
  moe_up6<<<dim3(HEXP / 64, MAXTILES), 256, 0, stream>>>(zb, w1e, w3e,
      (size_t)D_MODEL * HEXP, sw1, sw3, gb, s_gb, tok_list, wt_list,
      counts, offs, tile2e, tile2mt, ntiles);
  // 9. MoE phase B (experts + shared expert in one dispatch)
  moe_down6<<<dim3(D_MODEL / 128, MAXTILES), 256, 0, stream>>>(gb, s_gb, w2e,
      (size_t)HEXP * D_MODEL, sw2, out, tok_list, counts, offs,
      tile2e, tile2mt, ntiles);
  (void)in_sizes; (void)n_in; (void)out_size; (void)ws_size;
}